// Round 6
// baseline (1895.730 us; speedup 1.0000x reference)
//
#include <hip/hip_runtime.h>

typedef unsigned short ushort;
typedef unsigned int uint;
typedef __bf16 bf16x8 __attribute__((ext_vector_type(8)));
typedef unsigned short ushort8v __attribute__((ext_vector_type(8)));
typedef float f32x4 __attribute__((ext_vector_type(4)));

__device__ __forceinline__ float b2f(ushort u) {
    unsigned int x = ((unsigned int)u) << 16;
    float f;
    __builtin_memcpy(&f, &x, 4);
    return f;
}
__device__ __forceinline__ ushort f2bf(float f) {
    unsigned int x;
    __builtin_memcpy(&x, &f, 4);
    unsigned int r = x + 0x7fffu + ((x >> 16) & 1u);
    return (ushort)(r >> 16);
}
__device__ __forceinline__ float u2f_lo(uint u) {
    uint x = u << 16;
    float f;
    __builtin_memcpy(&f, &x, 4);
    return f;
}
__device__ __forceinline__ float u2f_hi(uint u) {
    uint x = u & 0xffff0000u;
    float f;
    __builtin_memcpy(&f, &x, 4);
    return f;
}
__device__ __forceinline__ uint packbf(float a, float b) {
    return (uint)f2bf(a) | ((uint)f2bf(b) << 16);
}
__device__ __forceinline__ ushort to_bf(float f) { return f2bf(f); }
__device__ __forceinline__ ushort to_bf(ushort u) { return u; }

#define NPIX 16384  // H*W = 128*128
#define PSTRIDE 136 // padded plane row stride (ushorts); 68 uints

// ---------------------------------------------------------------------------
// stage one 128x128 bf16 plane into padded LDS; zero only the 784 border
// dwords (interior is fully overwritten). Interior origin at [2][2].
// ---------------------------------------------------------------------------
__device__ __forceinline__ void stage_plane(ushort* pl, const ushort* __restrict__ src, int tid) {
    uint* plu = (uint*)pl;
    for (int i = tid; i < 784; i += 256) {
        int idx;
        if (i < 136) idx = i;                       // rows 0-1
        else if (i < 272) idx = 8840 + (i - 136);   // rows 130-131
        else {
            int j = i - 272;
            int r = (j >> 2) + 2;                   // rows 2..129
            int cs = j & 3;
            idx = r * 68 + (cs == 0 ? 0 : 64 + cs); // uint 0 (left pad), 65-67 (right pad)
        }
        plu[idx] = 0u;
    }
    for (int i = tid; i < 2048; i += 256) {
        int row = i >> 4, xg = (i & 15) << 3;
        uint4 v = *(const uint4*)&src[row * 128 + xg];
        uint* dst = (uint*)&pl[(row + 2) * PSTRIDE + xg + 2];
        dst[0] = v.x; dst[1] = v.y; dst[2] = v.z; dst[3] = v.w;
    }
    __syncthreads();
}

// unpack 12 consecutive bf16 at rowp (16B-aligned) into f32
__device__ __forceinline__ void unpack12(const ushort* rowp, float* cc) {
    const uint* rp = (const uint*)rowp;
    uint4 u = *(const uint4*)rp;
    uint2 v = *(const uint2*)(rp + 4);
    cc[0] = u2f_lo(u.x); cc[1] = u2f_hi(u.x);
    cc[2] = u2f_lo(u.y); cc[3] = u2f_hi(u.y);
    cc[4] = u2f_lo(u.z); cc[5] = u2f_hi(u.z);
    cc[6] = u2f_lo(u.w); cc[7] = u2f_hi(u.w);
    cc[8] = u2f_lo(v.x); cc[9] = u2f_hi(v.x);
    cc[10] = u2f_lo(v.y); cc[11] = u2f_hi(v.y);
}

// ---------------------------------------------------------------------------
// K0: convert fp32 weights to bf16 once (qkv_w, pin_w, pout_w).
// ---------------------------------------------------------------------------
__global__ __launch_bounds__(256) void wcvt(const float* __restrict__ s0, ushort* __restrict__ d0, int n0,
                                            const float* __restrict__ s1, ushort* __restrict__ d1, int n1,
                                            const float* __restrict__ s2, ushort* __restrict__ d2, int n2) {
    int i = blockIdx.x * 256 + threadIdx.x;
    if (i < n0) d0[i] = f2bf(s0[i]);
    else if (i < n0 + n1) d1[i - n0] = f2bf(s1[i - n0]);
    else if (i < n0 + n1 + n2) d2[i - n0 - n1] = f2bf(s2[i - n0 - n1]);
}

// ---------------------------------------------------------------------------
// K1/K5: fused LayerNorm(C=128) + 1x1 conv via MFMA (unchanged).
// ---------------------------------------------------------------------------
template <int O, typename TIN>
__global__ __launch_bounds__(256) void ln_gemm_mfma(const TIN* __restrict__ xin,
                                                    const ushort* __restrict__ Wb,
                                                    const float* __restrict__ gamma,
                                                    const float* __restrict__ beta,
                                                    ushort* __restrict__ out) {
    __shared__ ushort xs[64][136];
    __shared__ float red[2][4][64];
    __shared__ float mu[64], rs[64];
    __shared__ float gl[128], bl[128];

    const int blk = blockIdx.x;
    const int b = blk >> 8;
    const int pix0 = (blk & 255) * 64;
    const int tid = threadIdx.x;

    const TIN* xb = xin + (size_t)b * 128 * NPIX + pix0;
    for (int i = tid; i < 1024; i += 256) {
        int p = i & 63, cg = i >> 6;
        const TIN* src = xb + (size_t)(cg * 8) * NPIX + p;
        ushort8v u;
#pragma unroll
        for (int j = 0; j < 8; j++) u[j] = to_bf(src[(size_t)j * NPIX]);
        *(ushort8v*)&xs[p][cg * 8] = u;
    }
    if (tid < 128) {
        gl[tid] = gamma[tid];
        bl[tid] = beta[tid];
    }
    __syncthreads();

    {
        const int p = tid & 63, part = tid >> 6;
        float s = 0.f, ss = 0.f;
#pragma unroll
        for (int q = 0; q < 4; q++) {
            ushort8v u = *(const ushort8v*)&xs[p][part * 32 + q * 8];
#pragma unroll
            for (int j = 0; j < 8; j++) {
                float v = b2f(u[j]);
                s += v;
                ss += v * v;
            }
        }
        red[0][part][p] = s;
        red[1][part][p] = ss;
    }
    __syncthreads();
    if (tid < 64) {
        float s = red[0][0][tid] + red[0][1][tid] + red[0][2][tid] + red[0][3][tid];
        float ss = red[1][0][tid] + red[1][1][tid] + red[1][2][tid] + red[1][3][tid];
        float m = s * (1.f / 128.f);
        float var = ss * (1.f / 128.f) - m * m;
        mu[tid] = m;
        rs[tid] = rsqrtf(var + 1e-5f);
    }
    __syncthreads();
    {
        const int p = tid & 63, part = tid >> 6;
        const float mp = mu[p], rp = rs[p];
#pragma unroll
        for (int q = 0; q < 4; q++) {
            int c0 = part * 32 + q * 8;
            ushort8v u = *(const ushort8v*)&xs[p][c0];
            ushort8v o;
#pragma unroll
            for (int j = 0; j < 8; j++) {
                float v = b2f(u[j]);
                o[j] = f2bf((v - mp) * rp * gl[c0 + j] + bl[c0 + j]);
            }
            *(ushort8v*)&xs[p][c0] = o;
        }
    }
    __syncthreads();

    const int wv = tid >> 6, lane = tid & 63;
    const int lr = lane & 15, lg = lane >> 4;

    bf16x8 bfr[4][4];
#pragma unroll
    for (int t = 0; t < 4; t++)
#pragma unroll
        for (int kc = 0; kc < 4; kc++)
            bfr[t][kc] = __builtin_bit_cast(bf16x8, *(const ushort8v*)&xs[t * 16 + lr][kc * 32 + lg * 8]);

    constexpr int MT = O / 64;
#pragma unroll 1
    for (int mt = 0; mt < MT; mt++) {
        const int o0 = (wv * MT + mt) * 16;
        bf16x8 afr[4];
#pragma unroll
        for (int kc = 0; kc < 4; kc++)
            afr[kc] = __builtin_bit_cast(bf16x8,
                *(const ushort8v*)&Wb[(size_t)(o0 + lr) * 128 + kc * 32 + lg * 8]);
        f32x4 acc[4] = {{0.f, 0.f, 0.f, 0.f}, {0.f, 0.f, 0.f, 0.f}, {0.f, 0.f, 0.f, 0.f}, {0.f, 0.f, 0.f, 0.f}};
#pragma unroll
        for (int kc = 0; kc < 4; kc++)
#pragma unroll
            for (int t = 0; t < 4; t++)
                acc[t] = __builtin_amdgcn_mfma_f32_16x16x32_bf16(afr[kc], bfr[t][kc], acc[t], 0, 0, 0);
#pragma unroll
        for (int t = 0; t < 4; t++)
#pragma unroll
            for (int r = 0; r < 4; r++) {
                int o = o0 + lg * 4 + r;
                out[((size_t)b * O + o) * NPIX + pix0 + t * 16 + lr] = f2bf(acc[t][r]);
            }
    }
}

// ---------------------------------------------------------------------------
// K2: 3x3 depthwise conv, one (b,c) plane per block. 8 px/thread/iter.
// ---------------------------------------------------------------------------
__global__ __launch_bounds__(256) void dwconv3_lds(const ushort* __restrict__ in,
                                                   const float* __restrict__ wdw,
                                                   ushort* __restrict__ out) {
    __shared__ ushort pl[132 * PSTRIDE];
    const int c = blockIdx.x;
    const size_t plane = ((size_t)blockIdx.y * gridDim.x + c) * NPIX;
    const int tid = threadIdx.x;

    float w[9];
#pragma unroll
    for (int j = 0; j < 9; j++) w[j] = wdw[c * 9 + j];

    stage_plane(pl, in + plane, tid);

    const int x = (tid & 15) * 8;
    const int ybase = tid >> 4;
#pragma unroll 1
    for (int k = 0; k < 8; k++) {
        const int y = k * 16 + ybase;
        float a[8];
#pragma unroll
        for (int p = 0; p < 8; p++) a[p] = 0.f;
#pragma unroll
        for (int ky = 0; ky < 3; ky++) {
            float cc[12];
            unpack12(&pl[(y + ky + 1) * PSTRIDE + x], cc);
#pragma unroll
            for (int kx = 0; kx < 3; kx++) {
                float wv = w[ky * 3 + kx];
#pragma unroll
                for (int p = 0; p < 8; p++) a[p] += cc[p + kx + 1] * wv;
            }
        }
        const int px0 = (y << 7) + x;
        uint4 o;
        o.x = packbf(a[0], a[1]);
        o.y = packbf(a[2], a[3]);
        o.z = packbf(a[4], a[5]);
        o.w = packbf(a[6], a[7]);
        *(uint4*)&out[plane + px0] = o;
    }
}

// ---------------------------------------------------------------------------
// K6/K7/gating fused: x3=dw3(t), x5=dw5(t), g=gelu(t*c1) (sigmoid approx),
// write g*x3 -> gated[b][c], g*x5 -> gated[b][256+c]. 8 px/thread/iter.
// ---------------------------------------------------------------------------
__global__ __launch_bounds__(256) void dw_gated(const ushort* __restrict__ t,
                                                const float* __restrict__ w3_,
                                                const float* __restrict__ w5_,
                                                const float* __restrict__ c1w,
                                                ushort* __restrict__ gated) {
    __shared__ ushort pl[132 * PSTRIDE];
    const int c = blockIdx.x;
    const int b = blockIdx.y;
    const int tid = threadIdx.x;

    float w3[9], w5[25];
#pragma unroll
    for (int j = 0; j < 9; j++) w3[j] = w3_[c * 9 + j];
#pragma unroll
    for (int j = 0; j < 25; j++) w5[j] = w5_[c * 25 + j];
    const float c1v = c1w[c];

    stage_plane(pl, t + ((size_t)b * 256 + c) * NPIX, tid);

    ushort* g3 = gated + ((size_t)b * 512 + c) * NPIX;
    ushort* g5 = g3 + (size_t)256 * NPIX;

    const int x = (tid & 15) * 8;
    const int ybase = tid >> 4;
#pragma unroll 1
    for (int k = 0; k < 8; k++) {
        const int y = k * 16 + ybase;
        float a5[8], a3[8], tc[8];
#pragma unroll
        for (int p = 0; p < 8; p++) { a5[p] = 0.f; a3[p] = 0.f; }
#pragma unroll
        for (int ky = 0; ky < 5; ky++) {
            float cc[12];
            unpack12(&pl[(y + ky) * PSTRIDE + x], cc);
#pragma unroll
            for (int kx = 0; kx < 5; kx++) {
                float wv = w5[ky * 5 + kx];
#pragma unroll
                for (int p = 0; p < 8; p++) a5[p] += cc[p + kx] * wv;
            }
            if (ky >= 1 && ky <= 3) {
#pragma unroll
                for (int kx = 0; kx < 3; kx++) {
                    float wv = w3[(ky - 1) * 3 + kx];
#pragma unroll
                    for (int p = 0; p < 8; p++) a3[p] += cc[p + kx + 1] * wv;
                }
            }
            if (ky == 2) {
#pragma unroll
                for (int p = 0; p < 8; p++) tc[p] = cc[p + 2];
            }
        }
        const int px0 = (y << 7) + x;
        uint4 o3, o5;
        float g[8];
#pragma unroll
        for (int p = 0; p < 8; p++) {
            float x1 = tc[p] * c1v;
            // gelu(x) ~= x * sigmoid(1.702 x); |err| <= ~0.02, well under tolerance
            g[p] = x1 * __builtin_amdgcn_rcpf(1.f + __expf(-1.702f * x1));
        }
        o3.x = packbf(g[0] * a3[0], g[1] * a3[1]);
        o3.y = packbf(g[2] * a3[2], g[3] * a3[3]);
        o3.z = packbf(g[4] * a3[4], g[5] * a3[5]);
        o3.w = packbf(g[6] * a3[6], g[7] * a3[7]);
        o5.x = packbf(g[0] * a5[0], g[1] * a5[1]);
        o5.y = packbf(g[2] * a5[2], g[3] * a5[3]);
        o5.z = packbf(g[4] * a5[4], g[5] * a5[5]);
        o5.w = packbf(g[6] * a5[6], g[7] * a5[7]);
        *(uint4*)&g3[px0] = o3;
        *(uint4*)&g5[px0] = o5;
    }
}

// ---------------------------------------------------------------------------
// K3a: L2 norms of q and k rows (vectorized loads).
// ---------------------------------------------------------------------------
__global__ __launch_bounds__(256) void l2norms(const ushort* __restrict__ qkv,
                                               float* __restrict__ norms) {
    int blk = blockIdx.x;
    int qk = blk & 1, d = (blk >> 1) & 15, h = (blk >> 5) & 7, b = blk >> 8;
    int ch = qk * 128 + h * 16 + d;
    const ushort8v* row = (const ushort8v*)(qkv + ((size_t)b * 384 + ch) * NPIX);
    float s = 0.f;
    for (int i = threadIdx.x; i < 2048; i += 256) {
        ushort8v u = row[i];
#pragma unroll
        for (int j = 0; j < 8; j++) {
            float v = b2f(u[j]);
            s += v * v;
        }
    }
    for (int off = 32; off; off >>= 1) s += __shfl_down(s, off, 64);
    __shared__ float red[4];
    if ((threadIdx.x & 63) == 0) red[threadIdx.x >> 6] = s;
    __syncthreads();
    if (threadIdx.x == 0) {
        float t = red[0] + red[1] + red[2] + red[3];
        norms[blk] = fmaxf(sqrtf(t), 1e-12f);
    }
}

// ---------------------------------------------------------------------------
// K3b: partial q·k^T dot products. 512 blocks = (b,h,seg of 2048 pixels).
// ---------------------------------------------------------------------------
__global__ __launch_bounds__(256) void qk_partial(const ushort* __restrict__ qkv,
                                                  float* __restrict__ Spart) {
    __shared__ float qs[16][260], ks[16][260];
    int blk = blockIdx.x;
    int seg = blk & 7, h = (blk >> 3) & 7, b = blk >> 6;
    int bh = b * 8 + h;
    int n0 = seg * 2048;
    int tid = threadIdx.x;
    int d = tid >> 4, e = tid & 15;
    float acc = 0.f;
    for (int c0 = 0; c0 < 2048; c0 += 256) {
        __syncthreads();
        for (int i = tid; i < 16 * 256; i += 256) {
            int r = i >> 8, col = i & 255;
            qs[r][col] = b2f(qkv[((size_t)b * 384 + h * 16 + r) * NPIX + n0 + c0 + col]);
            ks[r][col] = b2f(qkv[((size_t)b * 384 + 128 + h * 16 + r) * NPIX + n0 + c0 + col]);
        }
        __syncthreads();
        for (int nn = 0; nn < 256; nn += 4) {
            float4 qv = *(const float4*)&qs[d][nn];
            float4 kv = *(const float4*)&ks[e][nn];
            acc += qv.x * kv.x + qv.y * kv.y + qv.z * kv.z + qv.w * kv.w;
        }
    }
    Spart[((size_t)seg * 64 + bh) * 256 + tid] = acc;
}

// ---------------------------------------------------------------------------
// K3c: softmax + fold attn into attn_proj -> M bf16.
// ---------------------------------------------------------------------------
__global__ __launch_bounds__(256) void softmax_M(const float* __restrict__ Spart,
                                                 const float* __restrict__ norms,
                                                 const float* __restrict__ temp,
                                                 const float* __restrict__ attn_proj,
                                                 ushort* __restrict__ M) {
    int bh = blockIdx.x;
    int b = bh >> 3, h = bh & 7;
    int tid = threadIdx.x;
    int d = tid >> 4, e = tid & 15;
    float s = 0.f;
#pragma unroll
    for (int sg = 0; sg < 8; sg++) s += Spart[((size_t)sg * 64 + bh) * 256 + tid];
    float nq = norms[((b * 8 + h) * 16 + d) * 2 + 0];
    float nk = norms[((b * 8 + h) * 16 + e) * 2 + 1];
    float logit = s / (nq * nk) * temp[h];
    float m = logit;
    for (int off = 8; off; off >>= 1) m = fmaxf(m, __shfl_xor(m, off, 64));
    float ex = expf(logit - m);
    float sum = ex;
    for (int off = 8; off; off >>= 1) sum += __shfl_xor(sum, off, 64);
    float attn = ex / sum;
    __shared__ float A[16][17];
    A[d][e] = attn;
    __syncthreads();
    for (int i = tid; i < 128 * 16; i += 256) {
        int o = i >> 4, ee = i & 15;
        float acc = 0.f;
#pragma unroll
        for (int dd = 0; dd < 16; dd++) acc += attn_proj[o * 128 + h * 16 + dd] * A[dd][ee];
        M[((size_t)b * 128 + o) * 128 + h * 16 + ee] = f2bf(acc);
    }
}

// ---------------------------------------------------------------------------
// K4: x2 = x + M_b @ v via MFMA (unchanged).
// ---------------------------------------------------------------------------
__global__ __launch_bounds__(256) void mv_res_mfma(const ushort* __restrict__ qkv,
                                                   const ushort* __restrict__ Mb16,
                                                   const float* __restrict__ x,
                                                   ushort* __restrict__ x2) {
    __shared__ ushort vs[64][136];
    const int blk = blockIdx.x;
    const int b = blk >> 8;
    const int pix0 = (blk & 255) * 64;
    const int tid = threadIdx.x;

    const ushort* vb = qkv + ((size_t)b * 384 + 256) * NPIX + pix0;
    for (int i = tid; i < 1024; i += 256) {
        int p = i & 63, cg = i >> 6;
        const ushort* src = vb + (size_t)(cg * 8) * NPIX + p;
        ushort8v u;
#pragma unroll
        for (int j = 0; j < 8; j++) u[j] = src[(size_t)j * NPIX];
        *(ushort8v*)&vs[p][cg * 8] = u;
    }
    __syncthreads();

    const int wv = tid >> 6, lane = tid & 63;
    const int lr = lane & 15, lg = lane >> 4;

    bf16x8 bfr[4][4];
#pragma unroll
    for (int t = 0; t < 4; t++)
#pragma unroll
        for (int kc = 0; kc < 4; kc++)
            bfr[t][kc] = __builtin_bit_cast(bf16x8, *(const ushort8v*)&vs[t * 16 + lr][kc * 32 + lg * 8]);

    const ushort* Mb = Mb16 + (size_t)b * 128 * 128;
#pragma unroll 1
    for (int mt = 0; mt < 2; mt++) {
        const int o0 = (wv * 2 + mt) * 16;
        bf16x8 afr[4];
#pragma unroll
        for (int kc = 0; kc < 4; kc++)
            afr[kc] = __builtin_bit_cast(bf16x8,
                *(const ushort8v*)&Mb[(size_t)(o0 + lr) * 128 + kc * 32 + lg * 8]);
        f32x4 acc[4] = {{0.f, 0.f, 0.f, 0.f}, {0.f, 0.f, 0.f, 0.f}, {0.f, 0.f, 0.f, 0.f}, {0.f, 0.f, 0.f, 0.f}};
#pragma unroll
        for (int kc = 0; kc < 4; kc++)
#pragma unroll
            for (int t = 0; t < 4; t++)
                acc[t] = __builtin_amdgcn_mfma_f32_16x16x32_bf16(afr[kc], bfr[t][kc], acc[t], 0, 0, 0);
#pragma unroll
        for (int t = 0; t < 4; t++)
#pragma unroll
            for (int r = 0; r < 4; r++) {
                int o = o0 + lg * 4 + r;
                size_t off = ((size_t)b * 128 + o) * NPIX + pix0 + t * 16 + lr;
                x2[off] = f2bf(x[off] + acc[t][r]);
            }
    }
}

// ---------------------------------------------------------------------------
// K8: out = x2 + pout[128,512] @ gated via MFMA (unchanged).
// ---------------------------------------------------------------------------
__global__ __launch_bounds__(256) void gdfn_mfma(const ushort* __restrict__ gated,
                                                 const ushort* __restrict__ x2,
                                                 const ushort* __restrict__ pout_b,
                                                 float* __restrict__ out) {
    __shared__ ushort gs[64][72];

    const int blk = blockIdx.x;
    const int b = blk >> 8;
    const int pix0 = (blk & 255) * 64;
    const int tid = threadIdx.x;
    const int wv = tid >> 6, lane = tid & 63;
    const int lr = lane & 15, lg = lane >> 4;

    f32x4 acc[2][4];
#pragma unroll
    for (int mt = 0; mt < 2; mt++)
#pragma unroll
        for (int tt = 0; tt < 4; tt++) acc[mt][tt] = (f32x4){0.f, 0.f, 0.f, 0.f};

#pragma unroll 1
    for (int kb = 0; kb < 8; kb++) {
        __syncthreads();
        for (int i = tid; i < 512; i += 256) {
            int p = i & 63, kg = i >> 6;
            const ushort* src = gated + ((size_t)b * 512 + kb * 64 + kg * 8) * NPIX + pix0 + p;
            ushort8v u;
#pragma unroll
            for (int j = 0; j < 8; j++) u[j] = src[(size_t)j * NPIX];
            *(ushort8v*)&gs[p][kg * 8] = u;
        }
        __syncthreads();

        bf16x8 bfrg[4][2];
#pragma unroll
        for (int tt = 0; tt < 4; tt++)
#pragma unroll
            for (int kc = 0; kc < 2; kc++)
                bfrg[tt][kc] = __builtin_bit_cast(bf16x8, *(const ushort8v*)&gs[tt * 16 + lr][kc * 32 + lg * 8]);

#pragma unroll
        for (int mt = 0; mt < 2; mt++) {
            const int o0 = (wv * 2 + mt) * 16;
            bf16x8 afr[2];
#pragma unroll
            for (int kc = 0; kc < 2; kc++)
                afr[kc] = __builtin_bit_cast(bf16x8,
                    *(const ushort8v*)&pout_b[(size_t)(o0 + lr) * 512 + kb * 64 + kc * 32 + lg * 8]);
#pragma unroll
            for (int kc = 0; kc < 2; kc++)
#pragma unroll
                for (int tt = 0; tt < 4; tt++)
                    acc[mt][tt] = __builtin_amdgcn_mfma_f32_16x16x32_bf16(afr[kc], bfrg[tt][kc], acc[mt][tt], 0, 0, 0);
        }
    }

#pragma unroll
    for (int mt = 0; mt < 2; mt++)
#pragma unroll
        for (int tt = 0; tt < 4; tt++)
#pragma unroll
            for (int r = 0; r < 4; r++) {
                int o = (wv * 2 + mt) * 16 + lg * 4 + r;
                size_t off = ((size_t)b * 128 + o) * NPIX + pix0 + tt * 16 + lr;
                out[off] = b2f(x2[off]) + acc[mt][tt][r];
            }
}

// ---------------------------------------------------------------------------
extern "C" void kernel_launch(void* const* d_in, const int* in_sizes, int n_in,
                              void* d_out, int out_size, void* d_ws, size_t ws_size,
                              hipStream_t stream) {
    const float* x = (const float*)d_in[0];
    const float* ln1_w = (const float*)d_in[1];
    const float* ln1_b = (const float*)d_in[2];
    const float* qkv_w = (const float*)d_in[3];
    const float* qkv_dw = (const float*)d_in[4];
    const float* temperature = (const float*)d_in[5];
    const float* attn_proj = (const float*)d_in[6];
    const float* ln2_w = (const float*)d_in[7];
    const float* ln2_b = (const float*)d_in[8];
    const float* pin_w = (const float*)d_in[9];
    const float* c1_w = (const float*)d_in[10];
    const float* c3_w = (const float*)d_in[11];
    const float* c5_w = (const float*)d_in[12];
    const float* pout_w = (const float*)d_in[13];
    float* out = (float*)d_out;

    char* ws = (char*)d_ws;
    // norms/Spart live in the qkv_pre region (dead between dwconv3 and ln_gemm<256>)
    float*  norms   = (float*)(ws + 0);             //      8,192
    float*  Spart   = (float*)(ws + 8192);          //    524,288
    ushort* qkv_pre = (ushort*)(ws + 0);            // 100,663,296 (dead after dwconv3)
    ushort* qkv     = (ushort*)(ws + 100663296);    // 100,663,296 (dead after mv_res)
    ushort* x2      = (ushort*)(ws + 201326592);    //  33,554,432 (lives to end)
    ushort* t       = (ushort*)(ws + 0);            //  67,108,864 (reuses qkv_pre)
    ushort* gated   = (ushort*)(ws + 67108864);     // 134,217,728 (reuses qkv region)
    ushort* Mb16    = (ushort*)(ws + 235151360);    //    262,144
    ushort* qkv_wb  = (ushort*)(ws + 235413504);    //     98,304
    ushort* pin_wb  = (ushort*)(ws + 235511808);    //     65,536
    ushort* pout_wb = (ushort*)(ws + 235577344);    //    131,072  (end ~235.7 MB)

    // K0: weight conversion (f32 -> bf16)
    wcvt<<<576, 256, 0, stream>>>(qkv_w, qkv_wb, 49152, pin_w, pin_wb, 32768, pout_w, pout_wb, 65536);
    // K1: qkv_pre = qkv_w @ LN1(x)
    ln_gemm_mfma<384, float><<<2048, 256, 0, stream>>>(x, qkv_wb, ln1_w, ln1_b, qkv_pre);
    // K2: qkv = dwconv3x3(qkv_pre), plane-per-block LDS
    dwconv3_lds<<<dim3(384, 8), 256, 0, stream>>>(qkv_pre, qkv_dw, qkv);
    // K3: tiny attention folded into per-batch projection matrix M
    l2norms<<<2048, 256, 0, stream>>>(qkv, norms);
    qk_partial<<<512, 256, 0, stream>>>(qkv, Spart);
    softmax_M<<<64, 256, 0, stream>>>(Spart, norms, temperature, attn_proj, Mb16);
    // K4: x2 = x + M_b @ v
    mv_res_mfma<<<2048, 256, 0, stream>>>(qkv, Mb16, x, x2);
    // K5: t = pin_w @ LN2(x2)
    ln_gemm_mfma<256, ushort><<<2048, 256, 0, stream>>>(x2, pin_wb, ln2_w, ln2_b, t);
    // K6/K7 fused + gating: gated = [gelu(t*c1)*dw3(t) ; gelu(t*c1)*dw5(t)]
    dw_gated<<<dim3(256, 8), 256, 0, stream>>>(t, c3_w, c5_w, c1_w, gated);
    // K8: out = x2 + pout @ gated
    gdfn_mfma<<<2048, 256, 0, stream>>>(gated, x2, pout_wb, out);
}

// Round 7
// 337.915 us; speedup vs baseline: 5.6101x; 5.6101x over previous
//
#include <hip/hip_runtime.h>

typedef unsigned short ushort;
typedef unsigned int uint;
typedef __bf16 bf16x8 __attribute__((ext_vector_type(8)));
typedef unsigned short ushort8v __attribute__((ext_vector_type(8)));
typedef float f32x4 __attribute__((ext_vector_type(4)));

__device__ __forceinline__ float b2f(ushort u) {
    unsigned int x = ((unsigned int)u) << 16;
    float f;
    __builtin_memcpy(&f, &x, 4);
    return f;
}
__device__ __forceinline__ ushort f2bf(float f) {
    unsigned int x;
    __builtin_memcpy(&x, &f, 4);
    unsigned int r = x + 0x7fffu + ((x >> 16) & 1u);
    return (ushort)(r >> 16);
}
__device__ __forceinline__ float u2f_lo(uint u) {
    uint x = u << 16;
    float f;
    __builtin_memcpy(&f, &x, 4);
    return f;
}
__device__ __forceinline__ float u2f_hi(uint u) {
    uint x = u & 0xffff0000u;
    float f;
    __builtin_memcpy(&f, &x, 4);
    return f;
}
__device__ __forceinline__ uint packbf(float a, float b) {
    return (uint)f2bf(a) | ((uint)f2bf(b) << 16);
}
__device__ __forceinline__ ushort to_bf(float f) { return f2bf(f); }
__device__ __forceinline__ ushort to_bf(ushort u) { return u; }

#define NPIX 16384  // H*W = 128*128
#define PSTRIDE 136 // padded plane row stride (ushorts); 68 uints

// ---------------------------------------------------------------------------
// stage one 128x128 bf16 plane into padded LDS; zero only the 784 border
// dwords (interior is fully overwritten). Interior origin at [2][2].
// ---------------------------------------------------------------------------
__device__ __forceinline__ void stage_plane(ushort* pl, const ushort* __restrict__ src, int tid) {
    uint* plu = (uint*)pl;
    for (int i = tid; i < 784; i += 256) {
        int idx;
        if (i < 136) idx = i;                       // rows 0-1
        else if (i < 272) idx = 8840 + (i - 136);   // rows 130-131
        else {
            int j = i - 272;
            int r = (j >> 2) + 2;                   // rows 2..129
            int cs = j & 3;
            idx = r * 68 + (cs == 0 ? 0 : 64 + cs); // uint 0 (left pad), 65-67 (right pad)
        }
        plu[idx] = 0u;
    }
    for (int i = tid; i < 2048; i += 256) {
        int row = i >> 4, xg = (i & 15) << 3;
        uint4 v = *(const uint4*)&src[row * 128 + xg];
        uint* dst = (uint*)&pl[(row + 2) * PSTRIDE + xg + 2];
        dst[0] = v.x; dst[1] = v.y; dst[2] = v.z; dst[3] = v.w;
    }
    __syncthreads();
}

// unpack 12 consecutive bf16 at rowp (16B-aligned) into f32
__device__ __forceinline__ void unpack12(const ushort* rowp, float* cc) {
    const uint* rp = (const uint*)rowp;
    uint4 u = *(const uint4*)rp;
    uint2 v = *(const uint2*)(rp + 4);
    cc[0] = u2f_lo(u.x); cc[1] = u2f_hi(u.x);
    cc[2] = u2f_lo(u.y); cc[3] = u2f_hi(u.y);
    cc[4] = u2f_lo(u.z); cc[5] = u2f_hi(u.z);
    cc[6] = u2f_lo(u.w); cc[7] = u2f_hi(u.w);
    cc[8] = u2f_lo(v.x); cc[9] = u2f_hi(v.x);
    cc[10] = u2f_lo(v.y); cc[11] = u2f_hi(v.y);
}

// ---------------------------------------------------------------------------
// K0: convert fp32 weights to bf16 once (qkv_w, pin_w, pout_w).
// ---------------------------------------------------------------------------
__global__ __launch_bounds__(256) void wcvt(const float* __restrict__ s0, ushort* __restrict__ d0, int n0,
                                            const float* __restrict__ s1, ushort* __restrict__ d1, int n1,
                                            const float* __restrict__ s2, ushort* __restrict__ d2, int n2) {
    int i = blockIdx.x * 256 + threadIdx.x;
    if (i < n0) d0[i] = f2bf(s0[i]);
    else if (i < n0 + n1) d1[i - n0] = f2bf(s1[i - n0]);
    else if (i < n0 + n1 + n2) d2[i - n0 - n1] = f2bf(s2[i - n0 - n1]);
}

// ---------------------------------------------------------------------------
// K1/K5: fused LayerNorm(C=128) + 1x1 conv via MFMA (unchanged).
// ---------------------------------------------------------------------------
template <int O, typename TIN>
__global__ __launch_bounds__(256) void ln_gemm_mfma(const TIN* __restrict__ xin,
                                                    const ushort* __restrict__ Wb,
                                                    const float* __restrict__ gamma,
                                                    const float* __restrict__ beta,
                                                    ushort* __restrict__ out) {
    __shared__ ushort xs[64][136];
    __shared__ float red[2][4][64];
    __shared__ float mu[64], rs[64];
    __shared__ float gl[128], bl[128];

    const int blk = blockIdx.x;
    const int b = blk >> 8;
    const int pix0 = (blk & 255) * 64;
    const int tid = threadIdx.x;

    const TIN* xb = xin + (size_t)b * 128 * NPIX + pix0;
    for (int i = tid; i < 1024; i += 256) {
        int p = i & 63, cg = i >> 6;
        const TIN* src = xb + (size_t)(cg * 8) * NPIX + p;
        ushort8v u;
#pragma unroll
        for (int j = 0; j < 8; j++) u[j] = to_bf(src[(size_t)j * NPIX]);
        *(ushort8v*)&xs[p][cg * 8] = u;
    }
    if (tid < 128) {
        gl[tid] = gamma[tid];
        bl[tid] = beta[tid];
    }
    __syncthreads();

    {
        const int p = tid & 63, part = tid >> 6;
        float s = 0.f, ss = 0.f;
#pragma unroll
        for (int q = 0; q < 4; q++) {
            ushort8v u = *(const ushort8v*)&xs[p][part * 32 + q * 8];
#pragma unroll
            for (int j = 0; j < 8; j++) {
                float v = b2f(u[j]);
                s += v;
                ss += v * v;
            }
        }
        red[0][part][p] = s;
        red[1][part][p] = ss;
    }
    __syncthreads();
    if (tid < 64) {
        float s = red[0][0][tid] + red[0][1][tid] + red[0][2][tid] + red[0][3][tid];
        float ss = red[1][0][tid] + red[1][1][tid] + red[1][2][tid] + red[1][3][tid];
        float m = s * (1.f / 128.f);
        float var = ss * (1.f / 128.f) - m * m;
        mu[tid] = m;
        rs[tid] = rsqrtf(var + 1e-5f);
    }
    __syncthreads();
    {
        const int p = tid & 63, part = tid >> 6;
        const float mp = mu[p], rp = rs[p];
#pragma unroll
        for (int q = 0; q < 4; q++) {
            int c0 = part * 32 + q * 8;
            ushort8v u = *(const ushort8v*)&xs[p][c0];
            ushort8v o;
#pragma unroll
            for (int j = 0; j < 8; j++) {
                float v = b2f(u[j]);
                o[j] = f2bf((v - mp) * rp * gl[c0 + j] + bl[c0 + j]);
            }
            *(ushort8v*)&xs[p][c0] = o;
        }
    }
    __syncthreads();

    const int wv = tid >> 6, lane = tid & 63;
    const int lr = lane & 15, lg = lane >> 4;

    bf16x8 bfr[4][4];
#pragma unroll
    for (int t = 0; t < 4; t++)
#pragma unroll
        for (int kc = 0; kc < 4; kc++)
            bfr[t][kc] = __builtin_bit_cast(bf16x8, *(const ushort8v*)&xs[t * 16 + lr][kc * 32 + lg * 8]);

    constexpr int MT = O / 64;
#pragma unroll 1
    for (int mt = 0; mt < MT; mt++) {
        const int o0 = (wv * MT + mt) * 16;
        bf16x8 afr[4];
#pragma unroll
        for (int kc = 0; kc < 4; kc++)
            afr[kc] = __builtin_bit_cast(bf16x8,
                *(const ushort8v*)&Wb[(size_t)(o0 + lr) * 128 + kc * 32 + lg * 8]);
        f32x4 acc[4] = {{0.f, 0.f, 0.f, 0.f}, {0.f, 0.f, 0.f, 0.f}, {0.f, 0.f, 0.f, 0.f}, {0.f, 0.f, 0.f, 0.f}};
#pragma unroll
        for (int kc = 0; kc < 4; kc++)
#pragma unroll
            for (int t = 0; t < 4; t++)
                acc[t] = __builtin_amdgcn_mfma_f32_16x16x32_bf16(afr[kc], bfr[t][kc], acc[t], 0, 0, 0);
#pragma unroll
        for (int t = 0; t < 4; t++)
#pragma unroll
            for (int r = 0; r < 4; r++) {
                int o = o0 + lg * 4 + r;
                out[((size_t)b * O + o) * NPIX + pix0 + t * 16 + lr] = f2bf(acc[t][r]);
            }
    }
}

// ---------------------------------------------------------------------------
// K2: 3x3 depthwise conv, one (b,c) plane per block. 8 px/thread/iter.
// ---------------------------------------------------------------------------
__global__ __launch_bounds__(256) void dwconv3_lds(const ushort* __restrict__ in,
                                                   const float* __restrict__ wdw,
                                                   ushort* __restrict__ out) {
    __shared__ ushort pl[132 * PSTRIDE];
    const int c = blockIdx.x;
    const size_t plane = ((size_t)blockIdx.y * gridDim.x + c) * NPIX;
    const int tid = threadIdx.x;

    float w[9];
#pragma unroll
    for (int j = 0; j < 9; j++) w[j] = wdw[c * 9 + j];

    stage_plane(pl, in + plane, tid);

    const int x = (tid & 15) * 8;
    const int ybase = tid >> 4;
#pragma unroll 1
    for (int k = 0; k < 8; k++) {
        const int y = k * 16 + ybase;
        float a[8];
#pragma unroll
        for (int p = 0; p < 8; p++) a[p] = 0.f;
#pragma unroll
        for (int ky = 0; ky < 3; ky++) {
            float cc[12];
            unpack12(&pl[(y + ky + 1) * PSTRIDE + x], cc);
#pragma unroll
            for (int kx = 0; kx < 3; kx++) {
                float wv = w[ky * 3 + kx];
#pragma unroll
                for (int p = 0; p < 8; p++) a[p] += cc[p + kx + 1] * wv;
            }
        }
        const int px0 = (y << 7) + x;
        uint4 o;
        o.x = packbf(a[0], a[1]);
        o.y = packbf(a[2], a[3]);
        o.z = packbf(a[4], a[5]);
        o.w = packbf(a[6], a[7]);
        *(uint4*)&out[plane + px0] = o;
    }
}

// ---------------------------------------------------------------------------
// K6/K7/gating fused: x3=dw3(t), x5=dw5(t), g=gelu(t*c1) (sigmoid approx),
// write g*x3 -> gated[b][c], g*x5 -> gated[b][256+c]. 8 px/thread/iter.
// ---------------------------------------------------------------------------
__global__ __launch_bounds__(256) void dw_gated(const ushort* __restrict__ t,
                                                const float* __restrict__ w3_,
                                                const float* __restrict__ w5_,
                                                const float* __restrict__ c1w,
                                                ushort* __restrict__ gated) {
    __shared__ ushort pl[132 * PSTRIDE];
    const int c = blockIdx.x;
    const int b = blockIdx.y;
    const int tid = threadIdx.x;

    float w3[9], w5[25];
#pragma unroll
    for (int j = 0; j < 9; j++) w3[j] = w3_[c * 9 + j];
#pragma unroll
    for (int j = 0; j < 25; j++) w5[j] = w5_[c * 25 + j];
    const float c1v = c1w[c];

    stage_plane(pl, t + ((size_t)b * 256 + c) * NPIX, tid);

    ushort* g3 = gated + ((size_t)b * 512 + c) * NPIX;
    ushort* g5 = g3 + (size_t)256 * NPIX;

    const int x = (tid & 15) * 8;
    const int ybase = tid >> 4;
#pragma unroll 1
    for (int k = 0; k < 8; k++) {
        const int y = k * 16 + ybase;
        float a5[8], a3[8], tc[8];
#pragma unroll
        for (int p = 0; p < 8; p++) { a5[p] = 0.f; a3[p] = 0.f; }
#pragma unroll
        for (int ky = 0; ky < 5; ky++) {
            float cc[12];
            unpack12(&pl[(y + ky) * PSTRIDE + x], cc);
#pragma unroll
            for (int kx = 0; kx < 5; kx++) {
                float wv = w5[ky * 5 + kx];
#pragma unroll
                for (int p = 0; p < 8; p++) a5[p] += cc[p + kx] * wv;
            }
            if (ky >= 1 && ky <= 3) {
#pragma unroll
                for (int kx = 0; kx < 3; kx++) {
                    float wv = w3[(ky - 1) * 3 + kx];
#pragma unroll
                    for (int p = 0; p < 8; p++) a3[p] += cc[p + kx + 1] * wv;
                }
            }
            if (ky == 2) {
#pragma unroll
                for (int p = 0; p < 8; p++) tc[p] = cc[p + 2];
            }
        }
        const int px0 = (y << 7) + x;
        uint4 o3, o5;
        float g[8];
#pragma unroll
        for (int p = 0; p < 8; p++) {
            float x1 = tc[p] * c1v;
            // gelu(x) ~= x * sigmoid(1.702 x); |err| <= ~0.02, well under tolerance
            g[p] = x1 * __builtin_amdgcn_rcpf(1.f + __expf(-1.702f * x1));
        }
        o3.x = packbf(g[0] * a3[0], g[1] * a3[1]);
        o3.y = packbf(g[2] * a3[2], g[3] * a3[3]);
        o3.z = packbf(g[4] * a3[4], g[5] * a3[5]);
        o3.w = packbf(g[6] * a3[6], g[7] * a3[7]);
        o5.x = packbf(g[0] * a5[0], g[1] * a5[1]);
        o5.y = packbf(g[2] * a5[2], g[3] * a5[3]);
        o5.z = packbf(g[4] * a5[4], g[5] * a5[5]);
        o5.w = packbf(g[6] * a5[6], g[7] * a5[7]);
        *(uint4*)&g3[px0] = o3;
        *(uint4*)&g5[px0] = o5;
    }
}

// ---------------------------------------------------------------------------
// K3 (NEW, all-in-one): per (b,h): S = q k^T (16x16, K=16384) via MFMA,
// row norms via diag(q q^T), diag(k k^T) (2 extra MFMAs, zero extra loads),
// then softmax and fold into attn_proj -> M. Replaces l2norms + qk_partial +
// softmax_M. grid = 64 (b,h), 4 waves each owning a 4096-px K-range.
// ---------------------------------------------------------------------------
__global__ __launch_bounds__(256) void attn_M(const ushort* __restrict__ qkv,
                                              const float* __restrict__ temp,
                                              const float* __restrict__ attn_proj,
                                              ushort* __restrict__ M) {
    __shared__ float Sp[4][16][16];
    __shared__ float QSS[4][16], KSS[4][16];
    __shared__ float A[16][17];

    const int bh = blockIdx.x, b = bh >> 3, h = bh & 7;
    const int tid = threadIdx.x;
    const int w = tid >> 6, lane = tid & 63;
    const int lr = lane & 15, lg = lane >> 4;

    // A-frag: q row lr, k-slice cols; B-frag: B[n][e]=k[e][n] -> same pattern.
    const ushort* qrow = qkv + ((size_t)b * 384 + h * 16 + lr) * NPIX + w * 4096 + lg * 8;
    const ushort* krow = qkv + ((size_t)b * 384 + 128 + h * 16 + lr) * NPIX + w * 4096 + lg * 8;

    f32x4 acc = {0.f, 0.f, 0.f, 0.f};
    f32x4 accq = {0.f, 0.f, 0.f, 0.f};
    f32x4 acck = {0.f, 0.f, 0.f, 0.f};
#pragma unroll 2
    for (int it = 0; it < 128; it++) {
        bf16x8 qf = __builtin_bit_cast(bf16x8, *(const ushort8v*)(qrow + it * 32));
        bf16x8 kf = __builtin_bit_cast(bf16x8, *(const ushort8v*)(krow + it * 32));
        acc = __builtin_amdgcn_mfma_f32_16x16x32_bf16(qf, kf, acc, 0, 0, 0);
        accq = __builtin_amdgcn_mfma_f32_16x16x32_bf16(qf, qf, accq, 0, 0, 0);
        acck = __builtin_amdgcn_mfma_f32_16x16x32_bf16(kf, kf, acck, 0, 0, 0);
    }
    // C layout: col=lane&15, row=(lane>>4)*4+r  (m89)
#pragma unroll
    for (int r = 0; r < 4; r++) Sp[w][lg * 4 + r][lr] = acc[r];
    if (lg == (lr >> 2)) {  // lane holding diagonal element (row==col==lr)
        QSS[w][lr] = accq[lr & 3];
        KSS[w][lr] = acck[lr & 3];
    }
    __syncthreads();

    // one thread per (d,e)
    const int d = tid >> 4, e = tid & 15;
    float S = Sp[0][d][e] + Sp[1][d][e] + Sp[2][d][e] + Sp[3][d][e];
    float nq = fmaxf(sqrtf(QSS[0][d] + QSS[1][d] + QSS[2][d] + QSS[3][d]), 1e-12f);
    float nk = fmaxf(sqrtf(KSS[0][e] + KSS[1][e] + KSS[2][e] + KSS[3][e]), 1e-12f);
    float logit = S / (nq * nk) * temp[h];
    float m = logit;
    for (int off = 8; off; off >>= 1) m = fmaxf(m, __shfl_xor(m, off, 64));
    float ex = expf(logit - m);
    float sum = ex;
    for (int off = 8; off; off >>= 1) sum += __shfl_xor(sum, off, 64);
    A[d][e] = ex / sum;
    __syncthreads();

    // fold: M[b][o][h*16+e] = sum_d attn_proj[o][h*16+d] * A[d][e]
    for (int i = tid; i < 2048; i += 256) {
        int o = i >> 4, ee = i & 15;
        float acc2 = 0.f;
#pragma unroll
        for (int dd = 0; dd < 16; dd++) acc2 += attn_proj[o * 128 + h * 16 + dd] * A[dd][ee];
        M[((size_t)b * 128 + o) * 128 + h * 16 + ee] = f2bf(acc2);
    }
}

// ---------------------------------------------------------------------------
// K4: x2 = x + M_b @ v via MFMA (unchanged).
// ---------------------------------------------------------------------------
__global__ __launch_bounds__(256) void mv_res_mfma(const ushort* __restrict__ qkv,
                                                   const ushort* __restrict__ Mb16,
                                                   const float* __restrict__ x,
                                                   ushort* __restrict__ x2) {
    __shared__ ushort vs[64][136];
    const int blk = blockIdx.x;
    const int b = blk >> 8;
    const int pix0 = (blk & 255) * 64;
    const int tid = threadIdx.x;

    const ushort* vb = qkv + ((size_t)b * 384 + 256) * NPIX + pix0;
    for (int i = tid; i < 1024; i += 256) {
        int p = i & 63, cg = i >> 6;
        const ushort* src = vb + (size_t)(cg * 8) * NPIX + p;
        ushort8v u;
#pragma unroll
        for (int j = 0; j < 8; j++) u[j] = src[(size_t)j * NPIX];
        *(ushort8v*)&vs[p][cg * 8] = u;
    }
    __syncthreads();

    const int wv = tid >> 6, lane = tid & 63;
    const int lr = lane & 15, lg = lane >> 4;

    bf16x8 bfr[4][4];
#pragma unroll
    for (int t = 0; t < 4; t++)
#pragma unroll
        for (int kc = 0; kc < 4; kc++)
            bfr[t][kc] = __builtin_bit_cast(bf16x8, *(const ushort8v*)&vs[t * 16 + lr][kc * 32 + lg * 8]);

    const ushort* Mb = Mb16 + (size_t)b * 128 * 128;
#pragma unroll 1
    for (int mt = 0; mt < 2; mt++) {
        const int o0 = (wv * 2 + mt) * 16;
        bf16x8 afr[4];
#pragma unroll
        for (int kc = 0; kc < 4; kc++)
            afr[kc] = __builtin_bit_cast(bf16x8,
                *(const ushort8v*)&Mb[(size_t)(o0 + lr) * 128 + kc * 32 + lg * 8]);
        f32x4 acc[4] = {{0.f, 0.f, 0.f, 0.f}, {0.f, 0.f, 0.f, 0.f}, {0.f, 0.f, 0.f, 0.f}, {0.f, 0.f, 0.f, 0.f}};
#pragma unroll
        for (int kc = 0; kc < 4; kc++)
#pragma unroll
            for (int t = 0; t < 4; t++)
                acc[t] = __builtin_amdgcn_mfma_f32_16x16x32_bf16(afr[kc], bfr[t][kc], acc[t], 0, 0, 0);
#pragma unroll
        for (int t = 0; t < 4; t++)
#pragma unroll
            for (int r = 0; r < 4; r++) {
                int o = o0 + lg * 4 + r;
                size_t off = ((size_t)b * 128 + o) * NPIX + pix0 + t * 16 + lr;
                x2[off] = f2bf(x[off] + acc[t][r]);
            }
    }
}

// ---------------------------------------------------------------------------
// K8: out = x2 + pout[128,512] @ gated via MFMA (unchanged).
// ---------------------------------------------------------------------------
__global__ __launch_bounds__(256) void gdfn_mfma(const ushort* __restrict__ gated,
                                                 const ushort* __restrict__ x2,
                                                 const ushort* __restrict__ pout_b,
                                                 float* __restrict__ out) {
    __shared__ ushort gs[64][72];

    const int blk = blockIdx.x;
    const int b = blk >> 8;
    const int pix0 = (blk & 255) * 64;
    const int tid = threadIdx.x;
    const int wv = tid >> 6, lane = tid & 63;
    const int lr = lane & 15, lg = lane >> 4;

    f32x4 acc[2][4];
#pragma unroll
    for (int mt = 0; mt < 2; mt++)
#pragma unroll
        for (int tt = 0; tt < 4; tt++) acc[mt][tt] = (f32x4){0.f, 0.f, 0.f, 0.f};

#pragma unroll 1
    for (int kb = 0; kb < 8; kb++) {
        __syncthreads();
        for (int i = tid; i < 512; i += 256) {
            int p = i & 63, kg = i >> 6;
            const ushort* src = gated + ((size_t)b * 512 + kb * 64 + kg * 8) * NPIX + pix0 + p;
            ushort8v u;
#pragma unroll
            for (int j = 0; j < 8; j++) u[j] = src[(size_t)j * NPIX];
            *(ushort8v*)&gs[p][kg * 8] = u;
        }
        __syncthreads();

        bf16x8 bfrg[4][2];
#pragma unroll
        for (int tt = 0; tt < 4; tt++)
#pragma unroll
            for (int kc = 0; kc < 2; kc++)
                bfrg[tt][kc] = __builtin_bit_cast(bf16x8, *(const ushort8v*)&gs[tt * 16 + lr][kc * 32 + lg * 8]);

#pragma unroll
        for (int mt = 0; mt < 2; mt++) {
            const int o0 = (wv * 2 + mt) * 16;
            bf16x8 afr[2];
#pragma unroll
            for (int kc = 0; kc < 2; kc++)
                afr[kc] = __builtin_bit_cast(bf16x8,
                    *(const ushort8v*)&pout_b[(size_t)(o0 + lr) * 512 + kb * 64 + kc * 32 + lg * 8]);
#pragma unroll
            for (int kc = 0; kc < 2; kc++)
#pragma unroll
                for (int tt = 0; tt < 4; tt++)
                    acc[mt][tt] = __builtin_amdgcn_mfma_f32_16x16x32_bf16(afr[kc], bfrg[tt][kc], acc[mt][tt], 0, 0, 0);
        }
    }

#pragma unroll
    for (int mt = 0; mt < 2; mt++)
#pragma unroll
        for (int tt = 0; tt < 4; tt++)
#pragma unroll
            for (int r = 0; r < 4; r++) {
                int o = (wv * 2 + mt) * 16 + lg * 4 + r;
                size_t off = ((size_t)b * 128 + o) * NPIX + pix0 + tt * 16 + lr;
                out[off] = b2f(x2[off]) + acc[mt][tt][r];
            }
}

// ---------------------------------------------------------------------------
extern "C" void kernel_launch(void* const* d_in, const int* in_sizes, int n_in,
                              void* d_out, int out_size, void* d_ws, size_t ws_size,
                              hipStream_t stream) {
    const float* x = (const float*)d_in[0];
    const float* ln1_w = (const float*)d_in[1];
    const float* ln1_b = (const float*)d_in[2];
    const float* qkv_w = (const float*)d_in[3];
    const float* qkv_dw = (const float*)d_in[4];
    const float* temperature = (const float*)d_in[5];
    const float* attn_proj = (const float*)d_in[6];
    const float* ln2_w = (const float*)d_in[7];
    const float* ln2_b = (const float*)d_in[8];
    const float* pin_w = (const float*)d_in[9];
    const float* c1_w = (const float*)d_in[10];
    const float* c3_w = (const float*)d_in[11];
    const float* c5_w = (const float*)d_in[12];
    const float* pout_w = (const float*)d_in[13];
    float* out = (float*)d_out;

    char* ws = (char*)d_ws;
    ushort* qkv_pre = (ushort*)(ws + 0);            // 100,663,296 (dead after dwconv3)
    ushort* qkv     = (ushort*)(ws + 100663296);    // 100,663,296 (dead after mv_res)
    ushort* x2      = (ushort*)(ws + 201326592);    //  33,554,432 (lives to end)
    ushort* t       = (ushort*)(ws + 0);            //  67,108,864 (reuses qkv_pre)
    ushort* gated   = (ushort*)(ws + 67108864);     // 134,217,728 (reuses qkv region)
    ushort* Mb16    = (ushort*)(ws + 235151360);    //    262,144
    ushort* qkv_wb  = (ushort*)(ws + 235413504);    //     98,304
    ushort* pin_wb  = (ushort*)(ws + 235511808);    //     65,536
    ushort* pout_wb = (ushort*)(ws + 235577344);    //    131,072  (end ~235.7 MB)

    // K0: weight conversion (f32 -> bf16)
    wcvt<<<576, 256, 0, stream>>>(qkv_w, qkv_wb, 49152, pin_w, pin_wb, 32768, pout_w, pout_wb, 65536);
    // K1: qkv_pre = qkv_w @ LN1(x)
    ln_gemm_mfma<384, float><<<2048, 256, 0, stream>>>(x, qkv_wb, ln1_w, ln1_b, qkv_pre);
    // K2: qkv = dwconv3x3(qkv_pre), plane-per-block LDS
    dwconv3_lds<<<dim3(384, 8), 256, 0, stream>>>(qkv_pre, qkv_dw, qkv);
    // K3: attention (norms + QK^T + softmax + attn_proj fold) in ONE kernel
    attn_M<<<64, 256, 0, stream>>>(qkv, temperature, attn_proj, Mb16);
    // K4: x2 = x + M_b @ v
    mv_res_mfma<<<2048, 256, 0, stream>>>(qkv, Mb16, x, x2);
    // K5: t = pin_w @ LN2(x2)
    ln_gemm_mfma<256, ushort><<<2048, 256, 0, stream>>>(x2, pin_wb, ln2_w, ln2_b, t);
    // K6/K7 fused + gating: gated = [gelu(t*c1)*dw3(t) ; gelu(t*c1)*dw5(t)]
    dw_gated<<<dim3(256, 8), 256, 0, stream>>>(t, c3_w, c5_w, c1_w, gated);
    // K8: out = x2 + pout @ gated
    gdfn_mfma<<<2048, 256, 0, stream>>>(gated, x2, pout_wb, out);
}

// Round 8
// 324.799 us; speedup vs baseline: 5.8366x; 1.0404x over previous
//
#include <hip/hip_runtime.h>
#include <type_traits>

typedef unsigned short ushort;
typedef unsigned int uint;
typedef __bf16 bf16x8 __attribute__((ext_vector_type(8)));
typedef unsigned short ushort8v __attribute__((ext_vector_type(8)));
typedef float f32x4 __attribute__((ext_vector_type(4)));

__device__ __forceinline__ float b2f(ushort u) {
    unsigned int x = ((unsigned int)u) << 16;
    float f;
    __builtin_memcpy(&f, &x, 4);
    return f;
}
__device__ __forceinline__ ushort f2bf(float f) {
    unsigned int x;
    __builtin_memcpy(&x, &f, 4);
    unsigned int r = x + 0x7fffu + ((x >> 16) & 1u);
    return (ushort)(r >> 16);
}
__device__ __forceinline__ float u2f_lo(uint u) {
    uint x = u << 16;
    float f;
    __builtin_memcpy(&f, &x, 4);
    return f;
}
__device__ __forceinline__ float u2f_hi(uint u) {
    uint x = u & 0xffff0000u;
    float f;
    __builtin_memcpy(&f, &x, 4);
    return f;
}
__device__ __forceinline__ uint packbf(float a, float b) {
    return (uint)f2bf(a) | ((uint)f2bf(b) << 16);
}

#define NPIX 16384  // H*W = 128*128
#define PSTRIDE 136 // padded plane row stride (ushorts); 68 uints

// Tiled intermediate layout: [b][tile(256)][ch(CH)][64 px]
__device__ __forceinline__ size_t tadr(int b, int CH, int tile, int ch, int off) {
    return (((size_t)b * 256 + tile) * CH + ch) * 64 + off;
}

// ---------------------------------------------------------------------------
// stage one 128x128 plane (channel c of tiled tensor) into padded LDS.
// ---------------------------------------------------------------------------
__device__ __forceinline__ void stage_plane(ushort* pl, const ushort* __restrict__ src,
                                            int b, int c, int CH, int tid) {
    uint* plu = (uint*)pl;
    for (int i = tid; i < 784; i += 256) {
        int idx;
        if (i < 136) idx = i;                       // rows 0-1
        else if (i < 272) idx = 8840 + (i - 136);   // rows 130-131
        else {
            int j = i - 272;
            int r = (j >> 2) + 2;                   // rows 2..129
            int cs = j & 3;
            idx = r * 68 + (cs == 0 ? 0 : 64 + cs); // uint 0 (left pad), 65-67 (right pad)
        }
        plu[idx] = 0u;
    }
    for (int i = tid; i < 2048; i += 256) {
        int row = i >> 4, xg = (i & 15) << 3;
        int px0 = row * 128 + xg;
        uint4 v = *(const uint4*)&src[tadr(b, CH, px0 >> 6, c, px0 & 63)];
        uint* dst = (uint*)&pl[(row + 2) * PSTRIDE + xg + 2];
        dst[0] = v.x; dst[1] = v.y; dst[2] = v.z; dst[3] = v.w;
    }
    __syncthreads();
}

// unpack 12 consecutive bf16 at rowp (16B-aligned) into f32
__device__ __forceinline__ void unpack12(const ushort* rowp, float* cc) {
    const uint* rp = (const uint*)rowp;
    uint4 u = *(const uint4*)rp;
    uint2 v = *(const uint2*)(rp + 4);
    cc[0] = u2f_lo(u.x); cc[1] = u2f_hi(u.x);
    cc[2] = u2f_lo(u.y); cc[3] = u2f_hi(u.y);
    cc[4] = u2f_lo(u.z); cc[5] = u2f_hi(u.z);
    cc[6] = u2f_lo(u.w); cc[7] = u2f_hi(u.w);
    cc[8] = u2f_lo(v.x); cc[9] = u2f_hi(v.x);
    cc[10] = u2f_lo(v.y); cc[11] = u2f_hi(v.y);
}

// ---------------------------------------------------------------------------
// K0: convert fp32 weights to bf16 once (qkv_w, pin_w, pout_w).
// ---------------------------------------------------------------------------
__global__ __launch_bounds__(256) void wcvt(const float* __restrict__ s0, ushort* __restrict__ d0, int n0,
                                            const float* __restrict__ s1, ushort* __restrict__ d1, int n1,
                                            const float* __restrict__ s2, ushort* __restrict__ d2, int n2) {
    int i = blockIdx.x * 256 + threadIdx.x;
    if (i < n0) d0[i] = f2bf(s0[i]);
    else if (i < n0 + n1) d1[i - n0] = f2bf(s1[i - n0]);
    else if (i < n0 + n1 + n2) d2[i - n0 - n1] = f2bf(s2[i - n0 - n1]);
}

// ---------------------------------------------------------------------------
// K1/K5: fused LayerNorm(C=128) + 1x1 conv via MFMA.
// TIN=float -> planar NCHW input (model x); TIN=ushort -> tiled input (x2).
// Output tiled [b][tile][O][64].
// ---------------------------------------------------------------------------
template <int O, typename TIN>
__global__ __launch_bounds__(256) void ln_gemm_mfma(const TIN* __restrict__ xin,
                                                    const ushort* __restrict__ Wb,
                                                    const float* __restrict__ gamma,
                                                    const float* __restrict__ beta,
                                                    ushort* __restrict__ out) {
    __shared__ ushort xs[64][136];
    __shared__ float red[2][4][64];
    __shared__ float mu[64], rs[64];
    __shared__ float gl[128], bl[128];

    const int blk = blockIdx.x;
    const int b = blk >> 8;
    const int tile = blk & 255;
    const int tid = threadIdx.x;

    if constexpr (std::is_same<TIN, float>::value) {
        const float* xb = xin + (size_t)b * 128 * NPIX + tile * 64;
        for (int i = tid; i < 1024; i += 256) {
            int p = i & 63, cg = i >> 6;
            const float* src = xb + (size_t)(cg * 8) * NPIX + p;
            ushort8v u;
#pragma unroll
            for (int j = 0; j < 8; j++) u[j] = f2bf(src[(size_t)j * NPIX]);
            *(ushort8v*)&xs[p][cg * 8] = u;
        }
    } else {
        const ushort* xb = xin + tadr(b, 128, tile, 0, 0);
        for (int i = tid; i < 1024; i += 256) {
            int p = i & 63, cg = i >> 6;
            ushort8v u;
#pragma unroll
            for (int j = 0; j < 8; j++) u[j] = xb[(cg * 8 + j) * 64 + p];
            *(ushort8v*)&xs[p][cg * 8] = u;
        }
    }
    if (tid < 128) {
        gl[tid] = gamma[tid];
        bl[tid] = beta[tid];
    }
    __syncthreads();

    {
        const int p = tid & 63, part = tid >> 6;
        float s = 0.f, ss = 0.f;
#pragma unroll
        for (int q = 0; q < 4; q++) {
            ushort8v u = *(const ushort8v*)&xs[p][part * 32 + q * 8];
#pragma unroll
            for (int j = 0; j < 8; j++) {
                float v = b2f(u[j]);
                s += v;
                ss += v * v;
            }
        }
        red[0][part][p] = s;
        red[1][part][p] = ss;
    }
    __syncthreads();
    if (tid < 64) {
        float s = red[0][0][tid] + red[0][1][tid] + red[0][2][tid] + red[0][3][tid];
        float ss = red[1][0][tid] + red[1][1][tid] + red[1][2][tid] + red[1][3][tid];
        float m = s * (1.f / 128.f);
        float var = ss * (1.f / 128.f) - m * m;
        mu[tid] = m;
        rs[tid] = rsqrtf(var + 1e-5f);
    }
    __syncthreads();
    {
        const int p = tid & 63, part = tid >> 6;
        const float mp = mu[p], rp = rs[p];
#pragma unroll
        for (int q = 0; q < 4; q++) {
            int c0 = part * 32 + q * 8;
            ushort8v u = *(const ushort8v*)&xs[p][c0];
            ushort8v o;
#pragma unroll
            for (int j = 0; j < 8; j++) {
                float v = b2f(u[j]);
                o[j] = f2bf((v - mp) * rp * gl[c0 + j] + bl[c0 + j]);
            }
            *(ushort8v*)&xs[p][c0] = o;
        }
    }
    __syncthreads();

    const int wv = tid >> 6, lane = tid & 63;
    const int lr = lane & 15, lg = lane >> 4;

    bf16x8 bfr[4][4];
#pragma unroll
    for (int t = 0; t < 4; t++)
#pragma unroll
        for (int kc = 0; kc < 4; kc++)
            bfr[t][kc] = __builtin_bit_cast(bf16x8, *(const ushort8v*)&xs[t * 16 + lr][kc * 32 + lg * 8]);

    constexpr int MT = O / 64;
#pragma unroll 1
    for (int mt = 0; mt < MT; mt++) {
        const int o0 = (wv * MT + mt) * 16;
        bf16x8 afr[4];
#pragma unroll
        for (int kc = 0; kc < 4; kc++)
            afr[kc] = __builtin_bit_cast(bf16x8,
                *(const ushort8v*)&Wb[(size_t)(o0 + lr) * 128 + kc * 32 + lg * 8]);
        f32x4 acc[4] = {{0.f, 0.f, 0.f, 0.f}, {0.f, 0.f, 0.f, 0.f}, {0.f, 0.f, 0.f, 0.f}, {0.f, 0.f, 0.f, 0.f}};
#pragma unroll
        for (int kc = 0; kc < 4; kc++)
#pragma unroll
            for (int t = 0; t < 4; t++)
                acc[t] = __builtin_amdgcn_mfma_f32_16x16x32_bf16(afr[kc], bfr[t][kc], acc[t], 0, 0, 0);
#pragma unroll
        for (int t = 0; t < 4; t++)
#pragma unroll
            for (int r = 0; r < 4; r++) {
                int o = o0 + lg * 4 + r;
                out[tadr(b, O, tile, o, t * 16 + lr)] = f2bf(acc[t][r]);
            }
    }
}

// ---------------------------------------------------------------------------
// K2: 3x3 depthwise conv, one (b,c) plane per block; tiled in/out.
// ---------------------------------------------------------------------------
__global__ __launch_bounds__(256) void dwconv3_lds(const ushort* __restrict__ in,
                                                   const float* __restrict__ wdw,
                                                   ushort* __restrict__ out, int CH) {
    __shared__ ushort pl[132 * PSTRIDE];
    const int c = blockIdx.x;
    const int b = blockIdx.y;
    const int tid = threadIdx.x;

    float w[9];
#pragma unroll
    for (int j = 0; j < 9; j++) w[j] = wdw[c * 9 + j];

    stage_plane(pl, in, b, c, CH, tid);

    const int x = (tid & 15) * 8;
    const int ybase = tid >> 4;
#pragma unroll 1
    for (int k = 0; k < 8; k++) {
        const int y = k * 16 + ybase;
        float a[8];
#pragma unroll
        for (int p = 0; p < 8; p++) a[p] = 0.f;
#pragma unroll
        for (int ky = 0; ky < 3; ky++) {
            float cc[12];
            unpack12(&pl[(y + ky + 1) * PSTRIDE + x], cc);
#pragma unroll
            for (int kx = 0; kx < 3; kx++) {
                float wv = w[ky * 3 + kx];
#pragma unroll
                for (int p = 0; p < 8; p++) a[p] += cc[p + kx + 1] * wv;
            }
        }
        const int px0 = (y << 7) + x;
        uint4 o;
        o.x = packbf(a[0], a[1]);
        o.y = packbf(a[2], a[3]);
        o.z = packbf(a[4], a[5]);
        o.w = packbf(a[6], a[7]);
        *(uint4*)&out[tadr(b, CH, px0 >> 6, c, px0 & 63)] = o;
    }
}

// ---------------------------------------------------------------------------
// K6/K7/gating fused: x3=dw3(t), x5=dw5(t), g=gelu(t*c1) (sigmoid approx),
// write g*x3 -> gated ch c, g*x5 -> gated ch 256+c. Tiled in/out.
// ---------------------------------------------------------------------------
__global__ __launch_bounds__(256) void dw_gated(const ushort* __restrict__ t,
                                                const float* __restrict__ w3_,
                                                const float* __restrict__ w5_,
                                                const float* __restrict__ c1w,
                                                ushort* __restrict__ gated) {
    __shared__ ushort pl[132 * PSTRIDE];
    const int c = blockIdx.x;
    const int b = blockIdx.y;
    const int tid = threadIdx.x;

    float w3[9], w5[25];
#pragma unroll
    for (int j = 0; j < 9; j++) w3[j] = w3_[c * 9 + j];
#pragma unroll
    for (int j = 0; j < 25; j++) w5[j] = w5_[c * 25 + j];
    const float c1v = c1w[c];

    stage_plane(pl, t, b, c, 256, tid);

    const int x = (tid & 15) * 8;
    const int ybase = tid >> 4;
#pragma unroll 1
    for (int k = 0; k < 8; k++) {
        const int y = k * 16 + ybase;
        float a5[8], a3[8], tc[8];
#pragma unroll
        for (int p = 0; p < 8; p++) { a5[p] = 0.f; a3[p] = 0.f; }
#pragma unroll
        for (int ky = 0; ky < 5; ky++) {
            float cc[12];
            unpack12(&pl[(y + ky) * PSTRIDE + x], cc);
#pragma unroll
            for (int kx = 0; kx < 5; kx++) {
                float wv = w5[ky * 5 + kx];
#pragma unroll
                for (int p = 0; p < 8; p++) a5[p] += cc[p + kx] * wv;
            }
            if (ky >= 1 && ky <= 3) {
#pragma unroll
                for (int kx = 0; kx < 3; kx++) {
                    float wv = w3[(ky - 1) * 3 + kx];
#pragma unroll
                    for (int p = 0; p < 8; p++) a3[p] += cc[p + kx + 1] * wv;
                }
            }
            if (ky == 2) {
#pragma unroll
                for (int p = 0; p < 8; p++) tc[p] = cc[p + 2];
            }
        }
        const int px0 = (y << 7) + x;
        uint4 o3, o5;
        float g[8];
#pragma unroll
        for (int p = 0; p < 8; p++) {
            float x1 = tc[p] * c1v;
            g[p] = x1 * __builtin_amdgcn_rcpf(1.f + __expf(-1.702f * x1));
        }
        o3.x = packbf(g[0] * a3[0], g[1] * a3[1]);
        o3.y = packbf(g[2] * a3[2], g[3] * a3[3]);
        o3.z = packbf(g[4] * a3[4], g[5] * a3[5]);
        o3.w = packbf(g[6] * a3[6], g[7] * a3[7]);
        o5.x = packbf(g[0] * a5[0], g[1] * a5[1]);
        o5.y = packbf(g[2] * a5[2], g[3] * a5[3]);
        o5.z = packbf(g[4] * a5[4], g[5] * a5[5]);
        o5.w = packbf(g[6] * a5[6], g[7] * a5[7]);
        *(uint4*)&gated[tadr(b, 512, px0 >> 6, c, px0 & 63)] = o3;
        *(uint4*)&gated[tadr(b, 512, px0 >> 6, 256 + c, px0 & 63)] = o5;
    }
}

// ---------------------------------------------------------------------------
// K3: per (b,h): S = q k^T + row norms via MFMA, softmax, attn_proj fold -> M.
// qkv is tiled [b][tile][384][64].
// ---------------------------------------------------------------------------
__global__ __launch_bounds__(256) void attn_M(const ushort* __restrict__ qkv,
                                              const float* __restrict__ temp,
                                              const float* __restrict__ attn_proj,
                                              ushort* __restrict__ M) {
    __shared__ float Sp[4][16][16];
    __shared__ float QSS[4][16], KSS[4][16];
    __shared__ float A[16][17];

    const int bh = blockIdx.x, b = bh >> 3, h = bh & 7;
    const int tid = threadIdx.x;
    const int w = tid >> 6, lane = tid & 63;
    const int lr = lane & 15, lg = lane >> 4;

    // wave w owns px range [w*4096, (w+1)*4096) = tiles w*64..w*64+63
    const size_t qbase = (((size_t)b * 256 + w * 64) * 384 + h * 16 + lr) * 64 + lg * 8;
    const size_t kbase = qbase + (size_t)128 * 64;

    f32x4 acc = {0.f, 0.f, 0.f, 0.f};
    f32x4 accq = {0.f, 0.f, 0.f, 0.f};
    f32x4 acck = {0.f, 0.f, 0.f, 0.f};
#pragma unroll 2
    for (int it = 0; it < 128; it++) {
        size_t off = (size_t)(it >> 1) * (384 * 64) + (it & 1) * 32;
        bf16x8 qf = __builtin_bit_cast(bf16x8, *(const ushort8v*)(qkv + qbase + off));
        bf16x8 kf = __builtin_bit_cast(bf16x8, *(const ushort8v*)(qkv + kbase + off));
        acc = __builtin_amdgcn_mfma_f32_16x16x32_bf16(qf, kf, acc, 0, 0, 0);
        accq = __builtin_amdgcn_mfma_f32_16x16x32_bf16(qf, qf, accq, 0, 0, 0);
        acck = __builtin_amdgcn_mfma_f32_16x16x32_bf16(kf, kf, acck, 0, 0, 0);
    }
#pragma unroll
    for (int r = 0; r < 4; r++) Sp[w][lg * 4 + r][lr] = acc[r];
    if (lg == (lr >> 2)) {
        QSS[w][lr] = accq[lr & 3];
        KSS[w][lr] = acck[lr & 3];
    }
    __syncthreads();

    const int d = tid >> 4, e = tid & 15;
    float S = Sp[0][d][e] + Sp[1][d][e] + Sp[2][d][e] + Sp[3][d][e];
    float nq = fmaxf(sqrtf(QSS[0][d] + QSS[1][d] + QSS[2][d] + QSS[3][d]), 1e-12f);
    float nk = fmaxf(sqrtf(KSS[0][e] + KSS[1][e] + KSS[2][e] + KSS[3][e]), 1e-12f);
    float logit = S / (nq * nk) * temp[h];
    float m = logit;
    for (int off = 8; off; off >>= 1) m = fmaxf(m, __shfl_xor(m, off, 64));
    float ex = expf(logit - m);
    float sum = ex;
    for (int off = 8; off; off >>= 1) sum += __shfl_xor(sum, off, 64);
    A[d][e] = ex / sum;
    __syncthreads();

    for (int i = tid; i < 2048; i += 256) {
        int o = i >> 4, ee = i & 15;
        float acc2 = 0.f;
#pragma unroll
        for (int dd = 0; dd < 16; dd++) acc2 += attn_proj[o * 128 + h * 16 + dd] * A[dd][ee];
        M[((size_t)b * 128 + o) * 128 + h * 16 + ee] = f2bf(acc2);
    }
}

// ---------------------------------------------------------------------------
// K4: x2 = x + M_b @ v via MFMA. v from tiled qkv; x planar f32; x2 tiled.
// ---------------------------------------------------------------------------
__global__ __launch_bounds__(256) void mv_res_mfma(const ushort* __restrict__ qkv,
                                                   const ushort* __restrict__ Mb16,
                                                   const float* __restrict__ x,
                                                   ushort* __restrict__ x2) {
    __shared__ ushort vs[64][136];
    const int blk = blockIdx.x;
    const int b = blk >> 8;
    const int tile = blk & 255;
    const int tid = threadIdx.x;

    const ushort* vb = qkv + tadr(b, 384, tile, 256, 0);
    for (int i = tid; i < 1024; i += 256) {
        int p = i & 63, cg = i >> 6;
        ushort8v u;
#pragma unroll
        for (int j = 0; j < 8; j++) u[j] = vb[(cg * 8 + j) * 64 + p];
        *(ushort8v*)&vs[p][cg * 8] = u;
    }
    __syncthreads();

    const int wv = tid >> 6, lane = tid & 63;
    const int lr = lane & 15, lg = lane >> 4;

    bf16x8 bfr[4][4];
#pragma unroll
    for (int t = 0; t < 4; t++)
#pragma unroll
        for (int kc = 0; kc < 4; kc++)
            bfr[t][kc] = __builtin_bit_cast(bf16x8, *(const ushort8v*)&vs[t * 16 + lr][kc * 32 + lg * 8]);

    const ushort* Mb = Mb16 + (size_t)b * 128 * 128;
#pragma unroll 1
    for (int mt = 0; mt < 2; mt++) {
        const int o0 = (wv * 2 + mt) * 16;
        bf16x8 afr[4];
#pragma unroll
        for (int kc = 0; kc < 4; kc++)
            afr[kc] = __builtin_bit_cast(bf16x8,
                *(const ushort8v*)&Mb[(size_t)(o0 + lr) * 128 + kc * 32 + lg * 8]);
        f32x4 acc[4] = {{0.f, 0.f, 0.f, 0.f}, {0.f, 0.f, 0.f, 0.f}, {0.f, 0.f, 0.f, 0.f}, {0.f, 0.f, 0.f, 0.f}};
#pragma unroll
        for (int kc = 0; kc < 4; kc++)
#pragma unroll
            for (int t = 0; t < 4; t++)
                acc[t] = __builtin_amdgcn_mfma_f32_16x16x32_bf16(afr[kc], bfr[t][kc], acc[t], 0, 0, 0);
#pragma unroll
        for (int t = 0; t < 4; t++)
#pragma unroll
            for (int r = 0; r < 4; r++) {
                int o = o0 + lg * 4 + r;
                float xv = x[((size_t)b * 128 + o) * NPIX + tile * 64 + t * 16 + lr];
                x2[tadr(b, 128, tile, o, t * 16 + lr)] = f2bf(xv + acc[t][r]);
            }
    }
}

// ---------------------------------------------------------------------------
// K8: out = x2 + pout[128,512] @ gated via MFMA; gated/x2 tiled, out planar f32.
// ---------------------------------------------------------------------------
__global__ __launch_bounds__(256) void gdfn_mfma(const ushort* __restrict__ gated,
                                                 const ushort* __restrict__ x2,
                                                 const ushort* __restrict__ pout_b,
                                                 float* __restrict__ out) {
    __shared__ ushort gs[64][72];

    const int blk = blockIdx.x;
    const int b = blk >> 8;
    const int tile = blk & 255;
    const int tid = threadIdx.x;
    const int wv = tid >> 6, lane = tid & 63;
    const int lr = lane & 15, lg = lane >> 4;

    const ushort* gb = gated + tadr(b, 512, tile, 0, 0);

    f32x4 acc[2][4];
#pragma unroll
    for (int mt = 0; mt < 2; mt++)
#pragma unroll
        for (int tt = 0; tt < 4; tt++) acc[mt][tt] = (f32x4){0.f, 0.f, 0.f, 0.f};

#pragma unroll 1
    for (int kb = 0; kb < 8; kb++) {
        __syncthreads();
        for (int i = tid; i < 512; i += 256) {
            int p = i & 63, kg = i >> 6;
            const ushort* src = gb + (kb * 64 + kg * 8) * 64 + p;
            ushort8v u;
#pragma unroll
            for (int j = 0; j < 8; j++) u[j] = src[j * 64];
            *(ushort8v*)&gs[p][kg * 8] = u;
        }
        __syncthreads();

        bf16x8 bfrg[4][2];
#pragma unroll
        for (int tt = 0; tt < 4; tt++)
#pragma unroll
            for (int kc = 0; kc < 2; kc++)
                bfrg[tt][kc] = __builtin_bit_cast(bf16x8, *(const ushort8v*)&gs[tt * 16 + lr][kc * 32 + lg * 8]);

#pragma unroll
        for (int mt = 0; mt < 2; mt++) {
            const int o0 = (wv * 2 + mt) * 16;
            bf16x8 afr[2];
#pragma unroll
            for (int kc = 0; kc < 2; kc++)
                afr[kc] = __builtin_bit_cast(bf16x8,
                    *(const ushort8v*)&pout_b[(size_t)(o0 + lr) * 512 + kb * 64 + kc * 32 + lg * 8]);
#pragma unroll
            for (int kc = 0; kc < 2; kc++)
#pragma unroll
                for (int tt = 0; tt < 4; tt++)
                    acc[mt][tt] = __builtin_amdgcn_mfma_f32_16x16x32_bf16(afr[kc], bfrg[tt][kc], acc[mt][tt], 0, 0, 0);
        }
    }

#pragma unroll
    for (int mt = 0; mt < 2; mt++)
#pragma unroll
        for (int tt = 0; tt < 4; tt++)
#pragma unroll
            for (int r = 0; r < 4; r++) {
                int o = (wv * 2 + mt) * 16 + lg * 4 + r;
                float xv = b2f(x2[tadr(b, 128, tile, o, tt * 16 + lr)]);
                out[((size_t)b * 128 + o) * NPIX + tile * 64 + tt * 16 + lr] = xv + acc[mt][tt][r];
            }
}

// ---------------------------------------------------------------------------
extern "C" void kernel_launch(void* const* d_in, const int* in_sizes, int n_in,
                              void* d_out, int out_size, void* d_ws, size_t ws_size,
                              hipStream_t stream) {
    const float* x = (const float*)d_in[0];
    const float* ln1_w = (const float*)d_in[1];
    const float* ln1_b = (const float*)d_in[2];
    const float* qkv_w = (const float*)d_in[3];
    const float* qkv_dw = (const float*)d_in[4];
    const float* temperature = (const float*)d_in[5];
    const float* attn_proj = (const float*)d_in[6];
    const float* ln2_w = (const float*)d_in[7];
    const float* ln2_b = (const float*)d_in[8];
    const float* pin_w = (const float*)d_in[9];
    const float* c1_w = (const float*)d_in[10];
    const float* c3_w = (const float*)d_in[11];
    const float* c5_w = (const float*)d_in[12];
    const float* pout_w = (const float*)d_in[13];
    float* out = (float*)d_out;

    char* ws = (char*)d_ws;
    ushort* qkv_pre = (ushort*)(ws + 0);            // 100,663,296 (dead after dwconv3)
    ushort* qkv     = (ushort*)(ws + 100663296);    // 100,663,296 (dead after mv_res)
    ushort* x2      = (ushort*)(ws + 201326592);    //  33,554,432 (lives to end)
    ushort* t       = (ushort*)(ws + 0);            //  67,108,864 (reuses qkv_pre)
    ushort* gated   = (ushort*)(ws + 67108864);     // 134,217,728 (reuses qkv region)
    ushort* Mb16    = (ushort*)(ws + 235151360);    //    262,144
    ushort* qkv_wb  = (ushort*)(ws + 235413504);    //     98,304
    ushort* pin_wb  = (ushort*)(ws + 235511808);    //     65,536
    ushort* pout_wb = (ushort*)(ws + 235577344);    //    131,072  (end ~235.7 MB)

    // K0: weight conversion (f32 -> bf16)
    wcvt<<<576, 256, 0, stream>>>(qkv_w, qkv_wb, 49152, pin_w, pin_wb, 32768, pout_w, pout_wb, 65536);
    // K1: qkv_pre = qkv_w @ LN1(x)   (x planar f32 -> qkv_pre tiled)
    ln_gemm_mfma<384, float><<<2048, 256, 0, stream>>>(x, qkv_wb, ln1_w, ln1_b, qkv_pre);
    // K2: qkv = dwconv3x3(qkv_pre), tiled->tiled
    dwconv3_lds<<<dim3(384, 8), 256, 0, stream>>>(qkv_pre, qkv_dw, qkv, 384);
    // K3: attention (norms + QK^T + softmax + attn_proj fold) in one kernel
    attn_M<<<64, 256, 0, stream>>>(qkv, temperature, attn_proj, Mb16);
    // K4: x2 = x + M_b @ v
    mv_res_mfma<<<2048, 256, 0, stream>>>(qkv, Mb16, x, x2);
    // K5: t = pin_w @ LN2(x2)
    ln_gemm_mfma<256, ushort><<<2048, 256, 0, stream>>>(x2, pin_wb, ln2_w, ln2_b, t);
    // K6/K7 fused + gating
    dw_gated<<<dim3(256, 8), 256, 0, stream>>>(t, c3_w, c5_w, c1_w, gated);
    // K8: out = x2 + pout @ gated
    gdfn_mfma<<<2048, 256, 0, stream>>>(gated, x2, pout_wb, out);
}

// Round 9
// 320.346 us; speedup vs baseline: 5.9178x; 1.0139x over previous
//
#include <hip/hip_runtime.h>
#include <type_traits>

typedef unsigned short ushort;
typedef unsigned int uint;
typedef __bf16 bf16x8 __attribute__((ext_vector_type(8)));
typedef unsigned short ushort8v __attribute__((ext_vector_type(8)));
typedef float f32x4 __attribute__((ext_vector_type(4)));

__device__ __forceinline__ float b2f(ushort u) {
    unsigned int x = ((unsigned int)u) << 16;
    float f;
    __builtin_memcpy(&f, &x, 4);
    return f;
}
__device__ __forceinline__ ushort f2bf(float f) {
    unsigned int x;
    __builtin_memcpy(&x, &f, 4);
    unsigned int r = x + 0x7fffu + ((x >> 16) & 1u);
    return (ushort)(r >> 16);
}
__device__ __forceinline__ float u2f_lo(uint u) {
    uint x = u << 16;
    float f;
    __builtin_memcpy(&f, &x, 4);
    return f;
}
__device__ __forceinline__ float u2f_hi(uint u) {
    uint x = u & 0xffff0000u;
    float f;
    __builtin_memcpy(&f, &x, 4);
    return f;
}
__device__ __forceinline__ uint packbf(float a, float b) {
    return (uint)f2bf(a) | ((uint)f2bf(b) << 16);
}

#define NPIX 16384  // H*W = 128*128
#define PSTRIDE 136 // padded plane row stride (ushorts); 68 uints

// Channel-major tiled layout: [b][tile(256)][ch(CH)][64 px]
__device__ __forceinline__ size_t tadr(int b, int CH, int tile, int ch, int off) {
    return (((size_t)b * 256 + tile) * CH + ch) * 64 + off;
}
// Pixel-major tiled layout for x2: [b][tile(256)][px(64)][ch(128)]
__device__ __forceinline__ size_t padr(int b, int tile, int p, int c) {
    return (((size_t)b * 256 + tile) * 64 + p) * 128 + c;
}

// ---------------------------------------------------------------------------
// stage one 128x128 plane (channel c of ch-major tiled tensor) into padded LDS.
// ---------------------------------------------------------------------------
__device__ __forceinline__ void stage_plane(ushort* pl, const ushort* __restrict__ src,
                                            int b, int c, int CH, int tid) {
    uint* plu = (uint*)pl;
    for (int i = tid; i < 784; i += 256) {
        int idx;
        if (i < 136) idx = i;                       // rows 0-1
        else if (i < 272) idx = 8840 + (i - 136);   // rows 130-131
        else {
            int j = i - 272;
            int r = (j >> 2) + 2;                   // rows 2..129
            int cs = j & 3;
            idx = r * 68 + (cs == 0 ? 0 : 64 + cs); // uint 0 (left pad), 65-67 (right pad)
        }
        plu[idx] = 0u;
    }
    for (int i = tid; i < 2048; i += 256) {
        int row = i >> 4, xg = (i & 15) << 3;
        int px0 = row * 128 + xg;
        uint4 v = *(const uint4*)&src[tadr(b, CH, px0 >> 6, c, px0 & 63)];
        uint* dst = (uint*)&pl[(row + 2) * PSTRIDE + xg + 2];
        dst[0] = v.x; dst[1] = v.y; dst[2] = v.z; dst[3] = v.w;
    }
    __syncthreads();
}

// unpack 12 consecutive bf16 at rowp (16B-aligned) into f32
__device__ __forceinline__ void unpack12(const ushort* rowp, float* cc) {
    const uint* rp = (const uint*)rowp;
    uint4 u = *(const uint4*)rp;
    uint2 v = *(const uint2*)(rp + 4);
    cc[0] = u2f_lo(u.x); cc[1] = u2f_hi(u.x);
    cc[2] = u2f_lo(u.y); cc[3] = u2f_hi(u.y);
    cc[4] = u2f_lo(u.z); cc[5] = u2f_hi(u.z);
    cc[6] = u2f_lo(u.w); cc[7] = u2f_hi(u.w);
    cc[8] = u2f_lo(v.x); cc[9] = u2f_hi(v.x);
    cc[10] = u2f_lo(v.y); cc[11] = u2f_hi(v.y);
}

// ---------------------------------------------------------------------------
// K0: convert fp32 weights to bf16 once (qkv_w, pin_w, pout_w).
// ---------------------------------------------------------------------------
__global__ __launch_bounds__(256) void wcvt(const float* __restrict__ s0, ushort* __restrict__ d0, int n0,
                                            const float* __restrict__ s1, ushort* __restrict__ d1, int n1,
                                            const float* __restrict__ s2, ushort* __restrict__ d2, int n2) {
    int i = blockIdx.x * 256 + threadIdx.x;
    if (i < n0) d0[i] = f2bf(s0[i]);
    else if (i < n0 + n1) d1[i - n0] = f2bf(s1[i - n0]);
    else if (i < n0 + n1 + n2) d2[i - n0 - n1] = f2bf(s2[i - n0 - n1]);
}

// ---------------------------------------------------------------------------
// K1: fused LayerNorm(C=128) + qkv 1x1 conv via MFMA. Planar f32 input.
// Output ch-major tiled [b][tile][384][64].
// ---------------------------------------------------------------------------
template <int O>
__global__ __launch_bounds__(256) void ln_gemm_mfma(const float* __restrict__ xin,
                                                    const ushort* __restrict__ Wb,
                                                    const float* __restrict__ gamma,
                                                    const float* __restrict__ beta,
                                                    ushort* __restrict__ out) {
    __shared__ ushort xs[64][136];
    __shared__ float red[2][4][64];
    __shared__ float mu[64], rs[64];
    __shared__ float gl[128], bl[128];

    const int blk = blockIdx.x;
    const int b = blk >> 8;
    const int tile = blk & 255;
    const int tid = threadIdx.x;

    const float* xb = xin + (size_t)b * 128 * NPIX + tile * 64;
    for (int i = tid; i < 1024; i += 256) {
        int p = i & 63, cg = i >> 6;
        const float* src = xb + (size_t)(cg * 8) * NPIX + p;
        ushort8v u;
#pragma unroll
        for (int j = 0; j < 8; j++) u[j] = f2bf(src[(size_t)j * NPIX]);
        *(ushort8v*)&xs[p][cg * 8] = u;
    }
    if (tid < 128) {
        gl[tid] = gamma[tid];
        bl[tid] = beta[tid];
    }
    __syncthreads();

    {
        const int p = tid & 63, part = tid >> 6;
        float s = 0.f, ss = 0.f;
#pragma unroll
        for (int q = 0; q < 4; q++) {
            ushort8v u = *(const ushort8v*)&xs[p][part * 32 + q * 8];
#pragma unroll
            for (int j = 0; j < 8; j++) {
                float v = b2f(u[j]);
                s += v;
                ss += v * v;
            }
        }
        red[0][part][p] = s;
        red[1][part][p] = ss;
    }
    __syncthreads();
    if (tid < 64) {
        float s = red[0][0][tid] + red[0][1][tid] + red[0][2][tid] + red[0][3][tid];
        float ss = red[1][0][tid] + red[1][1][tid] + red[1][2][tid] + red[1][3][tid];
        float m = s * (1.f / 128.f);
        float var = ss * (1.f / 128.f) - m * m;
        mu[tid] = m;
        rs[tid] = rsqrtf(var + 1e-5f);
    }
    __syncthreads();
    {
        const int p = tid & 63, part = tid >> 6;
        const float mp = mu[p], rp = rs[p];
#pragma unroll
        for (int q = 0; q < 4; q++) {
            int c0 = part * 32 + q * 8;
            ushort8v u = *(const ushort8v*)&xs[p][c0];
            ushort8v o;
#pragma unroll
            for (int j = 0; j < 8; j++) {
                float v = b2f(u[j]);
                o[j] = f2bf((v - mp) * rp * gl[c0 + j] + bl[c0 + j]);
            }
            *(ushort8v*)&xs[p][c0] = o;
        }
    }
    __syncthreads();

    const int wv = tid >> 6, lane = tid & 63;
    const int lr = lane & 15, lg = lane >> 4;

    bf16x8 bfr[4][4];
#pragma unroll
    for (int t = 0; t < 4; t++)
#pragma unroll
        for (int kc = 0; kc < 4; kc++)
            bfr[t][kc] = __builtin_bit_cast(bf16x8, *(const ushort8v*)&xs[t * 16 + lr][kc * 32 + lg * 8]);

    constexpr int MT = O / 64;
#pragma unroll 1
    for (int mt = 0; mt < MT; mt++) {
        const int o0 = (wv * MT + mt) * 16;
        bf16x8 afr[4];
#pragma unroll
        for (int kc = 0; kc < 4; kc++)
            afr[kc] = __builtin_bit_cast(bf16x8,
                *(const ushort8v*)&Wb[(size_t)(o0 + lr) * 128 + kc * 32 + lg * 8]);
        f32x4 acc[4] = {{0.f, 0.f, 0.f, 0.f}, {0.f, 0.f, 0.f, 0.f}, {0.f, 0.f, 0.f, 0.f}, {0.f, 0.f, 0.f, 0.f}};
#pragma unroll
        for (int kc = 0; kc < 4; kc++)
#pragma unroll
            for (int t = 0; t < 4; t++)
                acc[t] = __builtin_amdgcn_mfma_f32_16x16x32_bf16(afr[kc], bfr[t][kc], acc[t], 0, 0, 0);
#pragma unroll
        for (int t = 0; t < 4; t++)
#pragma unroll
            for (int r = 0; r < 4; r++) {
                int o = o0 + lg * 4 + r;
                out[tadr(b, O, tile, o, t * 16 + lr)] = f2bf(acc[t][r]);
            }
    }
}

// ---------------------------------------------------------------------------
// K2: 3x3 depthwise conv, one (b,c) plane per block; ch-major tiled in/out.
// ---------------------------------------------------------------------------
__global__ __launch_bounds__(256) void dwconv3_lds(const ushort* __restrict__ in,
                                                   const float* __restrict__ wdw,
                                                   ushort* __restrict__ out, int CH) {
    __shared__ ushort pl[132 * PSTRIDE];
    const int c = blockIdx.x;
    const int b = blockIdx.y;
    const int tid = threadIdx.x;

    float w[9];
#pragma unroll
    for (int j = 0; j < 9; j++) w[j] = wdw[c * 9 + j];

    stage_plane(pl, in, b, c, CH, tid);

    const int x = (tid & 15) * 8;
    const int ybase = tid >> 4;
#pragma unroll 1
    for (int k = 0; k < 8; k++) {
        const int y = k * 16 + ybase;
        float a[8];
#pragma unroll
        for (int p = 0; p < 8; p++) a[p] = 0.f;
#pragma unroll
        for (int ky = 0; ky < 3; ky++) {
            float cc[12];
            unpack12(&pl[(y + ky + 1) * PSTRIDE + x], cc);
#pragma unroll
            for (int kx = 0; kx < 3; kx++) {
                float wv = w[ky * 3 + kx];
#pragma unroll
                for (int p = 0; p < 8; p++) a[p] += cc[p + kx + 1] * wv;
            }
        }
        const int px0 = (y << 7) + x;
        uint4 o;
        o.x = packbf(a[0], a[1]);
        o.y = packbf(a[2], a[3]);
        o.z = packbf(a[4], a[5]);
        o.w = packbf(a[6], a[7]);
        *(uint4*)&out[tadr(b, CH, px0 >> 6, c, px0 & 63)] = o;
    }
}

// ---------------------------------------------------------------------------
// K6/K7/gating fused (unchanged): ch-major tiled in/out.
// ---------------------------------------------------------------------------
__global__ __launch_bounds__(256) void dw_gated(const ushort* __restrict__ t,
                                                const float* __restrict__ w3_,
                                                const float* __restrict__ w5_,
                                                const float* __restrict__ c1w,
                                                ushort* __restrict__ gated) {
    __shared__ ushort pl[132 * PSTRIDE];
    const int c = blockIdx.x;
    const int b = blockIdx.y;
    const int tid = threadIdx.x;

    float w3[9], w5[25];
#pragma unroll
    for (int j = 0; j < 9; j++) w3[j] = w3_[c * 9 + j];
#pragma unroll
    for (int j = 0; j < 25; j++) w5[j] = w5_[c * 25 + j];
    const float c1v = c1w[c];

    stage_plane(pl, t, b, c, 256, tid);

    const int x = (tid & 15) * 8;
    const int ybase = tid >> 4;
#pragma unroll 1
    for (int k = 0; k < 8; k++) {
        const int y = k * 16 + ybase;
        float a5[8], a3[8], tc[8];
#pragma unroll
        for (int p = 0; p < 8; p++) { a5[p] = 0.f; a3[p] = 0.f; }
#pragma unroll
        for (int ky = 0; ky < 5; ky++) {
            float cc[12];
            unpack12(&pl[(y + ky) * PSTRIDE + x], cc);
#pragma unroll
            for (int kx = 0; kx < 5; kx++) {
                float wv = w5[ky * 5 + kx];
#pragma unroll
                for (int p = 0; p < 8; p++) a5[p] += cc[p + kx] * wv;
            }
            if (ky >= 1 && ky <= 3) {
#pragma unroll
                for (int kx = 0; kx < 3; kx++) {
                    float wv = w3[(ky - 1) * 3 + kx];
#pragma unroll
                    for (int p = 0; p < 8; p++) a3[p] += cc[p + kx + 1] * wv;
                }
            }
            if (ky == 2) {
#pragma unroll
                for (int p = 0; p < 8; p++) tc[p] = cc[p + 2];
            }
        }
        const int px0 = (y << 7) + x;
        uint4 o3, o5;
        float g[8];
#pragma unroll
        for (int p = 0; p < 8; p++) {
            float x1 = tc[p] * c1v;
            g[p] = x1 * __builtin_amdgcn_rcpf(1.f + __expf(-1.702f * x1));
        }
        o3.x = packbf(g[0] * a3[0], g[1] * a3[1]);
        o3.y = packbf(g[2] * a3[2], g[3] * a3[3]);
        o3.z = packbf(g[4] * a3[4], g[5] * a3[5]);
        o3.w = packbf(g[6] * a3[6], g[7] * a3[7]);
        o5.x = packbf(g[0] * a5[0], g[1] * a5[1]);
        o5.y = packbf(g[2] * a5[2], g[3] * a5[3]);
        o5.z = packbf(g[4] * a5[4], g[5] * a5[5]);
        o5.w = packbf(g[6] * a5[6], g[7] * a5[7]);
        *(uint4*)&gated[tadr(b, 512, px0 >> 6, c, px0 & 63)] = o3;
        *(uint4*)&gated[tadr(b, 512, px0 >> 6, 256 + c, px0 & 63)] = o5;
    }
}

// ---------------------------------------------------------------------------
// K3: per (b,h): S = q k^T + row norms via MFMA, softmax, attn_proj fold -> M.
// (unchanged)
// ---------------------------------------------------------------------------
__global__ __launch_bounds__(256) void attn_M(const ushort* __restrict__ qkv,
                                              const float* __restrict__ temp,
                                              const float* __restrict__ attn_proj,
                                              ushort* __restrict__ M) {
    __shared__ float Sp[4][16][16];
    __shared__ float QSS[4][16], KSS[4][16];
    __shared__ float A[16][17];

    const int bh = blockIdx.x, b = bh >> 3, h = bh & 7;
    const int tid = threadIdx.x;
    const int w = tid >> 6, lane = tid & 63;
    const int lr = lane & 15, lg = lane >> 4;

    const size_t qbase = (((size_t)b * 256 + w * 64) * 384 + h * 16 + lr) * 64 + lg * 8;
    const size_t kbase = qbase + (size_t)128 * 64;

    f32x4 acc = {0.f, 0.f, 0.f, 0.f};
    f32x4 accq = {0.f, 0.f, 0.f, 0.f};
    f32x4 acck = {0.f, 0.f, 0.f, 0.f};
#pragma unroll 2
    for (int it = 0; it < 128; it++) {
        size_t off = (size_t)(it >> 1) * (384 * 64) + (it & 1) * 32;
        bf16x8 qf = __builtin_bit_cast(bf16x8, *(const ushort8v*)(qkv + qbase + off));
        bf16x8 kf = __builtin_bit_cast(bf16x8, *(const ushort8v*)(qkv + kbase + off));
        acc = __builtin_amdgcn_mfma_f32_16x16x32_bf16(qf, kf, acc, 0, 0, 0);
        accq = __builtin_amdgcn_mfma_f32_16x16x32_bf16(qf, qf, accq, 0, 0, 0);
        acck = __builtin_amdgcn_mfma_f32_16x16x32_bf16(kf, kf, acck, 0, 0, 0);
    }
#pragma unroll
    for (int r = 0; r < 4; r++) Sp[w][lg * 4 + r][lr] = acc[r];
    if (lg == (lr >> 2)) {
        QSS[w][lr] = accq[lr & 3];
        KSS[w][lr] = acck[lr & 3];
    }
    __syncthreads();

    const int d = tid >> 4, e = tid & 15;
    float S = Sp[0][d][e] + Sp[1][d][e] + Sp[2][d][e] + Sp[3][d][e];
    float nq = fmaxf(sqrtf(QSS[0][d] + QSS[1][d] + QSS[2][d] + QSS[3][d]), 1e-12f);
    float nk = fmaxf(sqrtf(KSS[0][e] + KSS[1][e] + KSS[2][e] + KSS[3][e]), 1e-12f);
    float logit = S / (nq * nk) * temp[h];
    float m = logit;
    for (int off = 8; off; off >>= 1) m = fmaxf(m, __shfl_xor(m, off, 64));
    float ex = expf(logit - m);
    float sum = ex;
    for (int off = 8; off; off >>= 1) sum += __shfl_xor(sum, off, 64);
    A[d][e] = ex / sum;
    __syncthreads();

    for (int i = tid; i < 2048; i += 256) {
        int o = i >> 4, ee = i & 15;
        float acc2 = 0.f;
#pragma unroll
        for (int dd = 0; dd < 16; dd++) acc2 += attn_proj[o * 128 + h * 16 + dd] * A[dd][ee];
        M[((size_t)b * 128 + o) * 128 + h * 16 + ee] = f2bf(acc2);
    }
}

// ---------------------------------------------------------------------------
// K4+K5 FUSED: x2 = x + M_b @ v, then t = pin @ LN2(x2), one 64-px tile/block.
// V staged via wide loads + LDS transpose (no scalar gathers). x2 out px-major.
// ---------------------------------------------------------------------------
__global__ __launch_bounds__(256) void mv_ln_mfma(const ushort* __restrict__ qkv,
                                                  const ushort* __restrict__ Mb16,
                                                  const float* __restrict__ x,
                                                  const ushort* __restrict__ pin_b,
                                                  const float* __restrict__ gamma,
                                                  const float* __restrict__ beta,
                                                  ushort* __restrict__ x2,
                                                  ushort* __restrict__ t_out) {
    __shared__ ushort vs[64][136];  // [px][ch] V tile
    __shared__ ushort xs[64][136];  // [px][ch] x2 tile
    __shared__ float red[2][4][64];
    __shared__ float mu[64], rs[64];
    __shared__ float gl[128], bl[128];

    const int blk = blockIdx.x;
    const int b = blk >> 8;
    const int tile = blk & 255;
    const int tid = threadIdx.x;
    const int wv = tid >> 6, lane = tid & 63;
    const int lr = lane & 15, lg = lane >> 4;

    // stage V: wide 16B loads (per-channel rows) + LDS transpose
    const ushort* vb = qkv + tadr(b, 384, tile, 256, 0);
#pragma unroll
    for (int k = 0; k < 4; k++) {
        int idx = tid + k * 256;           // 0..1023
        int c = idx & 127, pg = idx >> 7;  // pg 0..7
        ushort8v u = *(const ushort8v*)&vb[c * 64 + pg * 8];
#pragma unroll
        for (int j = 0; j < 8; j++) vs[pg * 8 + j][c] = u[j];
    }
    if (tid < 128) {
        gl[tid] = gamma[tid];
        bl[tid] = beta[tid];
    }
    __syncthreads();

    // MV GEMM
    bf16x8 bfr[4][4];
#pragma unroll
    for (int t = 0; t < 4; t++)
#pragma unroll
        for (int kc = 0; kc < 4; kc++)
            bfr[t][kc] = __builtin_bit_cast(bf16x8, *(const ushort8v*)&vs[t * 16 + lr][kc * 32 + lg * 8]);

    const ushort* Mb = Mb16 + (size_t)b * 128 * 128;
#pragma unroll 1
    for (int mt = 0; mt < 2; mt++) {
        const int o0 = (wv * 2 + mt) * 16;
        bf16x8 afr[4];
#pragma unroll
        for (int kc = 0; kc < 4; kc++)
            afr[kc] = __builtin_bit_cast(bf16x8,
                *(const ushort8v*)&Mb[(size_t)(o0 + lr) * 128 + kc * 32 + lg * 8]);
        f32x4 acc[4] = {{0.f, 0.f, 0.f, 0.f}, {0.f, 0.f, 0.f, 0.f}, {0.f, 0.f, 0.f, 0.f}, {0.f, 0.f, 0.f, 0.f}};
#pragma unroll
        for (int kc = 0; kc < 4; kc++)
#pragma unroll
            for (int t = 0; t < 4; t++)
                acc[t] = __builtin_amdgcn_mfma_f32_16x16x32_bf16(afr[kc], bfr[t][kc], acc[t], 0, 0, 0);
        // epilogue into xs[px][ch]: 4 consecutive ch per lane -> one 8B LDS write
#pragma unroll
        for (int t = 0; t < 4; t++) {
            int px = t * 16 + lr;
            const float* xp = &x[((size_t)b * 128 + o0 + lg * 4) * NPIX + tile * 64 + px];
            uint2 pk;
            pk.x = packbf(xp[0] + acc[t][0], xp[NPIX] + acc[t][1]);
            pk.y = packbf(xp[2 * NPIX] + acc[t][2], xp[3 * NPIX] + acc[t][3]);
            *(uint2*)&xs[px][o0 + lg * 4] = pk;
        }
    }
    __syncthreads();

    // copy xs -> x2 (px-major, fully coalesced) ; LN stats
#pragma unroll
    for (int k = 0; k < 4; k++) {
        int idx = tid + k * 256;            // 0..1023
        int p = idx >> 4, seg = idx & 15;   // 16 segs of 8 ch
        uint4 v = *(const uint4*)&xs[p][seg * 8];
        *(uint4*)&x2[padr(b, tile, p, seg * 8)] = v;
    }
    {
        const int p = tid & 63, part = tid >> 6;
        float s = 0.f, ss = 0.f;
#pragma unroll
        for (int q = 0; q < 4; q++) {
            ushort8v u = *(const ushort8v*)&xs[p][part * 32 + q * 8];
#pragma unroll
            for (int j = 0; j < 8; j++) {
                float v = b2f(u[j]);
                s += v;
                ss += v * v;
            }
        }
        red[0][part][p] = s;
        red[1][part][p] = ss;
    }
    __syncthreads();
    if (tid < 64) {
        float s = red[0][0][tid] + red[0][1][tid] + red[0][2][tid] + red[0][3][tid];
        float ss = red[1][0][tid] + red[1][1][tid] + red[1][2][tid] + red[1][3][tid];
        float m = s * (1.f / 128.f);
        float var = ss * (1.f / 128.f) - m * m;
        mu[tid] = m;
        rs[tid] = rsqrtf(var + 1e-5f);
    }
    __syncthreads();
    {
        const int p = tid & 63, part = tid >> 6;
        const float mp = mu[p], rp = rs[p];
#pragma unroll
        for (int q = 0; q < 4; q++) {
            int c0 = part * 32 + q * 8;
            ushort8v u = *(const ushort8v*)&xs[p][c0];
            ushort8v o;
#pragma unroll
            for (int j = 0; j < 8; j++) {
                float v = b2f(u[j]);
                o[j] = f2bf((v - mp) * rp * gl[c0 + j] + bl[c0 + j]);
            }
            *(ushort8v*)&xs[p][c0] = o;
        }
    }
    __syncthreads();

    // pin GEMM (O=256)
    bf16x8 bfr2[4][4];
#pragma unroll
    for (int t = 0; t < 4; t++)
#pragma unroll
        for (int kc = 0; kc < 4; kc++)
            bfr2[t][kc] = __builtin_bit_cast(bf16x8, *(const ushort8v*)&xs[t * 16 + lr][kc * 32 + lg * 8]);

#pragma unroll 1
    for (int mt = 0; mt < 4; mt++) {
        const int o0 = (wv * 4 + mt) * 16;
        bf16x8 afr[4];
#pragma unroll
        for (int kc = 0; kc < 4; kc++)
            afr[kc] = __builtin_bit_cast(bf16x8,
                *(const ushort8v*)&pin_b[(size_t)(o0 + lr) * 128 + kc * 32 + lg * 8]);
        f32x4 acc[4] = {{0.f, 0.f, 0.f, 0.f}, {0.f, 0.f, 0.f, 0.f}, {0.f, 0.f, 0.f, 0.f}, {0.f, 0.f, 0.f, 0.f}};
#pragma unroll
        for (int kc = 0; kc < 4; kc++)
#pragma unroll
            for (int t = 0; t < 4; t++)
                acc[t] = __builtin_amdgcn_mfma_f32_16x16x32_bf16(afr[kc], bfr2[t][kc], acc[t], 0, 0, 0);
#pragma unroll
        for (int t = 0; t < 4; t++)
#pragma unroll
            for (int r = 0; r < 4; r++) {
                int o = o0 + lg * 4 + r;
                t_out[tadr(b, 256, tile, o, t * 16 + lr)] = f2bf(acc[t][r]);
            }
    }
}

// ---------------------------------------------------------------------------
// K8: out = x2 + pout[128,512] @ gated via MFMA.
// Staging: wide 16B loads + LDS transpose, double-buffered (issue-early /
// ds_write-late so HBM latency hides under MFMA). x2 read px-major (8B/lane).
// ---------------------------------------------------------------------------
__global__ __launch_bounds__(256) void gdfn_mfma(const ushort* __restrict__ gated,
                                                 const ushort* __restrict__ x2,
                                                 const ushort* __restrict__ pout_b,
                                                 float* __restrict__ out) {
    __shared__ ushort gs[2][64][72];

    const int blk = blockIdx.x;
    const int b = blk >> 8;
    const int tile = blk & 255;
    const int tid = threadIdx.x;
    const int wv = tid >> 6, lane = tid & 63;
    const int lr = lane & 15, lg = lane >> 4;

    const ushort* gb = gated + tadr(b, 512, tile, 0, 0);
    const int c0 = tid & 63;              // channel within chunk
    const int pg0 = tid >> 6;             // px-group 0..3 (second: +4)

    f32x4 acc[2][4];
#pragma unroll
    for (int mt = 0; mt < 2; mt++)
#pragma unroll
        for (int tt = 0; tt < 4; tt++) acc[mt][tt] = (f32x4){0.f, 0.f, 0.f, 0.f};

    // prologue: chunk 0 -> buf 0
    ushort8v pre0 = *(const ushort8v*)&gb[c0 * 64 + pg0 * 8];
    ushort8v pre1 = *(const ushort8v*)&gb[c0 * 64 + (pg0 + 4) * 8];
#pragma unroll
    for (int j = 0; j < 8; j++) {
        gs[0][pg0 * 8 + j][c0] = pre0[j];
        gs[0][(pg0 + 4) * 8 + j][c0] = pre1[j];
    }
    __syncthreads();

#pragma unroll 1
    for (int kb = 0; kb < 8; kb++) {
        const int cur = kb & 1;
        // issue next chunk's global loads early
        if (kb < 7) {
            const ushort* nb = gb + (kb + 1) * 64 * 64;
            pre0 = *(const ushort8v*)&nb[c0 * 64 + pg0 * 8];
            pre1 = *(const ushort8v*)&nb[c0 * 64 + (pg0 + 4) * 8];
        }

        bf16x8 bfrg[4][2];
#pragma unroll
        for (int tt = 0; tt < 4; tt++)
#pragma unroll
            for (int kc = 0; kc < 2; kc++)
                bfrg[tt][kc] = __builtin_bit_cast(bf16x8, *(const ushort8v*)&gs[cur][tt * 16 + lr][kc * 32 + lg * 8]);

#pragma unroll
        for (int mt = 0; mt < 2; mt++) {
            const int o0 = (wv * 2 + mt) * 16;
            bf16x8 afr[2];
#pragma unroll
            for (int kc = 0; kc < 2; kc++)
                afr[kc] = __builtin_bit_cast(bf16x8,
                    *(const ushort8v*)&pout_b[(size_t)(o0 + lr) * 512 + kb * 64 + kc * 32 + lg * 8]);
#pragma unroll
            for (int kc = 0; kc < 2; kc++)
#pragma unroll
                for (int tt = 0; tt < 4; tt++)
                    acc[mt][tt] = __builtin_amdgcn_mfma_f32_16x16x32_bf16(afr[kc], bfrg[tt][kc], acc[mt][tt], 0, 0, 0);
        }

        if (kb < 7) {
            // write next chunk into the other buffer (readers are on `cur`)
#pragma unroll
            for (int j = 0; j < 8; j++) {
                gs[cur ^ 1][pg0 * 8 + j][c0] = pre0[j];
                gs[cur ^ 1][(pg0 + 4) * 8 + j][c0] = pre1[j];
            }
        }
        __syncthreads();
    }

#pragma unroll
    for (int mt = 0; mt < 2; mt++)
#pragma unroll
        for (int tt = 0; tt < 4; tt++) {
            int o0 = (wv * 2 + mt) * 16 + lg * 4;
            int px = tt * 16 + lr;
            uint2 xw = *(const uint2*)&x2[padr(b, tile, px, o0)];
            float xv0 = u2f_lo(xw.x), xv1 = u2f_hi(xw.x);
            float xv2 = u2f_lo(xw.y), xv3 = u2f_hi(xw.y);
            size_t obase = ((size_t)b * 128 + o0) * NPIX + tile * 64 + px;
            out[obase] = xv0 + acc[mt][tt][0];
            out[obase + NPIX] = xv1 + acc[mt][tt][1];
            out[obase + 2 * NPIX] = xv2 + acc[mt][tt][2];
            out[obase + 3 * NPIX] = xv3 + acc[mt][tt][3];
        }
}

// ---------------------------------------------------------------------------
extern "C" void kernel_launch(void* const* d_in, const int* in_sizes, int n_in,
                              void* d_out, int out_size, void* d_ws, size_t ws_size,
                              hipStream_t stream) {
    const float* x = (const float*)d_in[0];
    const float* ln1_w = (const float*)d_in[1];
    const float* ln1_b = (const float*)d_in[2];
    const float* qkv_w = (const float*)d_in[3];
    const float* qkv_dw = (const float*)d_in[4];
    const float* temperature = (const float*)d_in[5];
    const float* attn_proj = (const float*)d_in[6];
    const float* ln2_w = (const float*)d_in[7];
    const float* ln2_b = (const float*)d_in[8];
    const float* pin_w = (const float*)d_in[9];
    const float* c1_w = (const float*)d_in[10];
    const float* c3_w = (const float*)d_in[11];
    const float* c5_w = (const float*)d_in[12];
    const float* pout_w = (const float*)d_in[13];
    float* out = (float*)d_out;

    char* ws = (char*)d_ws;
    ushort* qkv_pre = (ushort*)(ws + 0);            // 100,663,296 (dead after dwconv3)
    ushort* qkv     = (ushort*)(ws + 100663296);    // 100,663,296 (dead after mv_ln)
    ushort* x2      = (ushort*)(ws + 201326592);    //  33,554,432 px-major (lives to end)
    ushort* t       = (ushort*)(ws + 0);            //  67,108,864 (reuses qkv_pre)
    ushort* gated   = (ushort*)(ws + 67108864);     // 134,217,728 (reuses qkv region)
    ushort* Mb16    = (ushort*)(ws + 235151360);    //    262,144
    ushort* qkv_wb  = (ushort*)(ws + 235413504);    //     98,304
    ushort* pin_wb  = (ushort*)(ws + 235511808);    //     65,536
    ushort* pout_wb = (ushort*)(ws + 235577344);    //    131,072  (end ~235.7 MB)

    // K0: weight conversion (f32 -> bf16)
    wcvt<<<576, 256, 0, stream>>>(qkv_w, qkv_wb, 49152, pin_w, pin_wb, 32768, pout_w, pout_wb, 65536);
    // K1: qkv_pre = qkv_w @ LN1(x)
    ln_gemm_mfma<384><<<2048, 256, 0, stream>>>(x, qkv_wb, ln1_w, ln1_b, qkv_pre);
    // K2: qkv = dwconv3x3(qkv_pre)
    dwconv3_lds<<<dim3(384, 8), 256, 0, stream>>>(qkv_pre, qkv_dw, qkv, 384);
    // K3: attention (norms + QK^T + softmax + attn_proj fold)
    attn_M<<<64, 256, 0, stream>>>(qkv, temperature, attn_proj, Mb16);
    // K4+K5 fused: x2 = x + M_b @ v ; t = pin @ LN2(x2)
    mv_ln_mfma<<<2048, 256, 0, stream>>>(qkv, Mb16, x, pin_wb, ln2_w, ln2_b, x2, t);
    // K6/K7 fused + gating
    dw_gated<<<dim3(256, 8), 256, 0, stream>>>(t, c3_w, c5_w, c1_w, gated);
    // K8: out = x2 + pout @ gated
    gdfn_mfma<<<2048, 256, 0, stream>>>(gated, x2, pout_wb, out);
}

// Round 10
// 317.682 us; speedup vs baseline: 5.9674x; 1.0084x over previous
//
#include <hip/hip_runtime.h>
#include <type_traits>

typedef unsigned short ushort;
typedef unsigned int uint;
typedef __bf16 bf16x8 __attribute__((ext_vector_type(8)));
typedef unsigned short ushort8v __attribute__((ext_vector_type(8)));
typedef float f32x4 __attribute__((ext_vector_type(4)));

__device__ __forceinline__ float b2f(ushort u) {
    unsigned int x = ((unsigned int)u) << 16;
    float f;
    __builtin_memcpy(&f, &x, 4);
    return f;
}
__device__ __forceinline__ ushort f2bf(float f) {
    unsigned int x;
    __builtin_memcpy(&x, &f, 4);
    unsigned int r = x + 0x7fffu + ((x >> 16) & 1u);
    return (ushort)(r >> 16);
}
__device__ __forceinline__ float u2f_lo(uint u) {
    uint x = u << 16;
    float f;
    __builtin_memcpy(&f, &x, 4);
    return f;
}
__device__ __forceinline__ float u2f_hi(uint u) {
    uint x = u & 0xffff0000u;
    float f;
    __builtin_memcpy(&f, &x, 4);
    return f;
}
__device__ __forceinline__ uint packbf(float a, float b) {
    return (uint)f2bf(a) | ((uint)f2bf(b) << 16);
}

#define NPIX 16384  // H*W = 128*128
#define PSTRIDE 136 // padded plane row stride (ushorts); 68 uints

// Channel-major tiled layout: [b][tile(256)][ch(CH)][64 px]
__device__ __forceinline__ size_t tadr(int b, int CH, int tile, int ch, int off) {
    return (((size_t)b * 256 + tile) * CH + ch) * 64 + off;
}
// Pixel-major tiled layout for x2: [b][tile(256)][px(64)][ch(128)]
__device__ __forceinline__ size_t padr(int b, int tile, int p, int c) {
    return (((size_t)b * 256 + tile) * 64 + p) * 128 + c;
}

// ---------------------------------------------------------------------------
// stage one 128x128 plane (channel c of ch-major tiled tensor) into padded LDS.
// ---------------------------------------------------------------------------
__device__ __forceinline__ void stage_plane(ushort* pl, const ushort* __restrict__ src,
                                            int b, int c, int CH, int tid) {
    uint* plu = (uint*)pl;
    for (int i = tid; i < 784; i += 256) {
        int idx;
        if (i < 136) idx = i;                       // rows 0-1
        else if (i < 272) idx = 8840 + (i - 136);   // rows 130-131
        else {
            int j = i - 272;
            int r = (j >> 2) + 2;                   // rows 2..129
            int cs = j & 3;
            idx = r * 68 + (cs == 0 ? 0 : 64 + cs); // uint 0 (left pad), 65-67 (right pad)
        }
        plu[idx] = 0u;
    }
    for (int i = tid; i < 2048; i += 256) {
        int row = i >> 4, xg = (i & 15) << 3;
        int px0 = row * 128 + xg;
        uint4 v = *(const uint4*)&src[tadr(b, CH, px0 >> 6, c, px0 & 63)];
        uint* dst = (uint*)&pl[(row + 2) * PSTRIDE + xg + 2];
        dst[0] = v.x; dst[1] = v.y; dst[2] = v.z; dst[3] = v.w;
    }
    __syncthreads();
}

// unpack 12 consecutive bf16 at rowp (16B-aligned) into f32
__device__ __forceinline__ void unpack12(const ushort* rowp, float* cc) {
    const uint* rp = (const uint*)rowp;
    uint4 u = *(const uint4*)rp;
    uint2 v = *(const uint2*)(rp + 4);
    cc[0] = u2f_lo(u.x); cc[1] = u2f_hi(u.x);
    cc[2] = u2f_lo(u.y); cc[3] = u2f_hi(u.y);
    cc[4] = u2f_lo(u.z); cc[5] = u2f_hi(u.z);
    cc[6] = u2f_lo(u.w); cc[7] = u2f_hi(u.w);
    cc[8] = u2f_lo(v.x); cc[9] = u2f_hi(v.x);
    cc[10] = u2f_lo(v.y); cc[11] = u2f_hi(v.y);
}

// ---------------------------------------------------------------------------
// K0: convert fp32 weights to bf16 once (qkv_w, pin_w, pout_w).
// ---------------------------------------------------------------------------
__global__ __launch_bounds__(256) void wcvt(const float* __restrict__ s0, ushort* __restrict__ d0, int n0,
                                            const float* __restrict__ s1, ushort* __restrict__ d1, int n1,
                                            const float* __restrict__ s2, ushort* __restrict__ d2, int n2) {
    int i = blockIdx.x * 256 + threadIdx.x;
    if (i < n0) d0[i] = f2bf(s0[i]);
    else if (i < n0 + n1) d1[i - n0] = f2bf(s1[i - n0]);
    else if (i < n0 + n1 + n2) d2[i - n0 - n1] = f2bf(s2[i - n0 - n1]);
}

// ---------------------------------------------------------------------------
// K1: fused LayerNorm(C=128) + qkv 1x1 conv via MFMA. Planar f32 input.
// Staging split into bulk-load (32 coalesced dwords in flight) then cvt+write.
// ---------------------------------------------------------------------------
template <int O>
__global__ __launch_bounds__(256) void ln_gemm_mfma(const float* __restrict__ xin,
                                                    const ushort* __restrict__ Wb,
                                                    const float* __restrict__ gamma,
                                                    const float* __restrict__ beta,
                                                    ushort* __restrict__ out) {
    __shared__ ushort xs[64][136];
    __shared__ float red[2][4][64];
    __shared__ float mu[64], rs[64];
    __shared__ float gl[128], bl[128];

    const int blk = blockIdx.x;
    const int b = blk >> 8;
    const int tile = blk & 255;
    const int tid = threadIdx.x;

    const float* xb = xin + (size_t)b * 128 * NPIX + tile * 64;
    float vx[4][8];
#pragma unroll
    for (int k = 0; k < 4; k++) {
        int i = tid + k * 256;
        int p = i & 63, cg = i >> 6;
        const float* src = xb + (size_t)(cg * 8) * NPIX + p;
#pragma unroll
        for (int j = 0; j < 8; j++) vx[k][j] = src[(size_t)j * NPIX];
    }
    if (tid < 128) {
        gl[tid] = gamma[tid];
        bl[tid] = beta[tid];
    }
#pragma unroll
    for (int k = 0; k < 4; k++) {
        int i = tid + k * 256;
        int p = i & 63, cg = i >> 6;
        ushort8v u;
#pragma unroll
        for (int j = 0; j < 8; j++) u[j] = f2bf(vx[k][j]);
        *(ushort8v*)&xs[p][cg * 8] = u;
    }
    __syncthreads();

    {
        const int p = tid & 63, part = tid >> 6;
        float s = 0.f, ss = 0.f;
#pragma unroll
        for (int q = 0; q < 4; q++) {
            ushort8v u = *(const ushort8v*)&xs[p][part * 32 + q * 8];
#pragma unroll
            for (int j = 0; j < 8; j++) {
                float v = b2f(u[j]);
                s += v;
                ss += v * v;
            }
        }
        red[0][part][p] = s;
        red[1][part][p] = ss;
    }
    __syncthreads();
    if (tid < 64) {
        float s = red[0][0][tid] + red[0][1][tid] + red[0][2][tid] + red[0][3][tid];
        float ss = red[1][0][tid] + red[1][1][tid] + red[1][2][tid] + red[1][3][tid];
        float m = s * (1.f / 128.f);
        float var = ss * (1.f / 128.f) - m * m;
        mu[tid] = m;
        rs[tid] = rsqrtf(var + 1e-5f);
    }
    __syncthreads();
    {
        const int p = tid & 63, part = tid >> 6;
        const float mp = mu[p], rp = rs[p];
#pragma unroll
        for (int q = 0; q < 4; q++) {
            int c0 = part * 32 + q * 8;
            ushort8v u = *(const ushort8v*)&xs[p][c0];
            ushort8v o;
#pragma unroll
            for (int j = 0; j < 8; j++) {
                float v = b2f(u[j]);
                o[j] = f2bf((v - mp) * rp * gl[c0 + j] + bl[c0 + j]);
            }
            *(ushort8v*)&xs[p][c0] = o;
        }
    }
    __syncthreads();

    const int wv = tid >> 6, lane = tid & 63;
    const int lr = lane & 15, lg = lane >> 4;

    bf16x8 bfr[4][4];
#pragma unroll
    for (int t = 0; t < 4; t++)
#pragma unroll
        for (int kc = 0; kc < 4; kc++)
            bfr[t][kc] = __builtin_bit_cast(bf16x8, *(const ushort8v*)&xs[t * 16 + lr][kc * 32 + lg * 8]);

    constexpr int MT = O / 64;
#pragma unroll 1
    for (int mt = 0; mt < MT; mt++) {
        const int o0 = (wv * MT + mt) * 16;
        bf16x8 afr[4];
#pragma unroll
        for (int kc = 0; kc < 4; kc++)
            afr[kc] = __builtin_bit_cast(bf16x8,
                *(const ushort8v*)&Wb[(size_t)(o0 + lr) * 128 + kc * 32 + lg * 8]);
        f32x4 acc[4] = {{0.f, 0.f, 0.f, 0.f}, {0.f, 0.f, 0.f, 0.f}, {0.f, 0.f, 0.f, 0.f}, {0.f, 0.f, 0.f, 0.f}};
#pragma unroll
        for (int kc = 0; kc < 4; kc++)
#pragma unroll
            for (int t = 0; t < 4; t++)
                acc[t] = __builtin_amdgcn_mfma_f32_16x16x32_bf16(afr[kc], bfr[t][kc], acc[t], 0, 0, 0);
#pragma unroll
        for (int t = 0; t < 4; t++)
#pragma unroll
            for (int r = 0; r < 4; r++) {
                int o = o0 + lg * 4 + r;
                out[tadr(b, O, tile, o, t * 16 + lr)] = f2bf(acc[t][r]);
            }
    }
}

// ---------------------------------------------------------------------------
// K2: 3x3 depthwise conv, one (b,c) plane per block; ch-major tiled in/out.
// ---------------------------------------------------------------------------
__global__ __launch_bounds__(256) void dwconv3_lds(const ushort* __restrict__ in,
                                                   const float* __restrict__ wdw,
                                                   ushort* __restrict__ out, int CH) {
    __shared__ ushort pl[132 * PSTRIDE];
    const int c = blockIdx.x;
    const int b = blockIdx.y;
    const int tid = threadIdx.x;

    float w[9];
#pragma unroll
    for (int j = 0; j < 9; j++) w[j] = wdw[c * 9 + j];

    stage_plane(pl, in, b, c, CH, tid);

    const int x = (tid & 15) * 8;
    const int ybase = tid >> 4;
#pragma unroll 1
    for (int k = 0; k < 8; k++) {
        const int y = k * 16 + ybase;
        float a[8];
#pragma unroll
        for (int p = 0; p < 8; p++) a[p] = 0.f;
#pragma unroll
        for (int ky = 0; ky < 3; ky++) {
            float cc[12];
            unpack12(&pl[(y + ky + 1) * PSTRIDE + x], cc);
#pragma unroll
            for (int kx = 0; kx < 3; kx++) {
                float wv = w[ky * 3 + kx];
#pragma unroll
                for (int p = 0; p < 8; p++) a[p] += cc[p + kx + 1] * wv;
            }
        }
        const int px0 = (y << 7) + x;
        uint4 o;
        o.x = packbf(a[0], a[1]);
        o.y = packbf(a[2], a[3]);
        o.z = packbf(a[4], a[5]);
        o.w = packbf(a[6], a[7]);
        *(uint4*)&out[tadr(b, CH, px0 >> 6, c, px0 & 63)] = o;
    }
}

// ---------------------------------------------------------------------------
// K6/K7/gating fused: ch-major tiled in/out (unchanged).
// ---------------------------------------------------------------------------
__global__ __launch_bounds__(256) void dw_gated(const ushort* __restrict__ t,
                                                const float* __restrict__ w3_,
                                                const float* __restrict__ w5_,
                                                const float* __restrict__ c1w,
                                                ushort* __restrict__ gated) {
    __shared__ ushort pl[132 * PSTRIDE];
    const int c = blockIdx.x;
    const int b = blockIdx.y;
    const int tid = threadIdx.x;

    float w3[9], w5[25];
#pragma unroll
    for (int j = 0; j < 9; j++) w3[j] = w3_[c * 9 + j];
#pragma unroll
    for (int j = 0; j < 25; j++) w5[j] = w5_[c * 25 + j];
    const float c1v = c1w[c];

    stage_plane(pl, t, b, c, 256, tid);

    const int x = (tid & 15) * 8;
    const int ybase = tid >> 4;
#pragma unroll 1
    for (int k = 0; k < 8; k++) {
        const int y = k * 16 + ybase;
        float a5[8], a3[8], tc[8];
#pragma unroll
        for (int p = 0; p < 8; p++) { a5[p] = 0.f; a3[p] = 0.f; }
#pragma unroll
        for (int ky = 0; ky < 5; ky++) {
            float cc[12];
            unpack12(&pl[(y + ky) * PSTRIDE + x], cc);
#pragma unroll
            for (int kx = 0; kx < 5; kx++) {
                float wv = w5[ky * 5 + kx];
#pragma unroll
                for (int p = 0; p < 8; p++) a5[p] += cc[p + kx] * wv;
            }
            if (ky >= 1 && ky <= 3) {
#pragma unroll
                for (int kx = 0; kx < 3; kx++) {
                    float wv = w3[(ky - 1) * 3 + kx];
#pragma unroll
                    for (int p = 0; p < 8; p++) a3[p] += cc[p + kx + 1] * wv;
                }
            }
            if (ky == 2) {
#pragma unroll
                for (int p = 0; p < 8; p++) tc[p] = cc[p + 2];
            }
        }
        const int px0 = (y << 7) + x;
        uint4 o3, o5;
        float g[8];
#pragma unroll
        for (int p = 0; p < 8; p++) {
            float x1 = tc[p] * c1v;
            g[p] = x1 * __builtin_amdgcn_rcpf(1.f + __expf(-1.702f * x1));
        }
        o3.x = packbf(g[0] * a3[0], g[1] * a3[1]);
        o3.y = packbf(g[2] * a3[2], g[3] * a3[3]);
        o3.z = packbf(g[4] * a3[4], g[5] * a3[5]);
        o3.w = packbf(g[6] * a3[6], g[7] * a3[7]);
        o5.x = packbf(g[0] * a5[0], g[1] * a5[1]);
        o5.y = packbf(g[2] * a5[2], g[3] * a5[3]);
        o5.z = packbf(g[4] * a5[4], g[5] * a5[5]);
        o5.w = packbf(g[6] * a5[6], g[7] * a5[7]);
        *(uint4*)&gated[tadr(b, 512, px0 >> 6, c, px0 & 63)] = o3;
        *(uint4*)&gated[tadr(b, 512, px0 >> 6, 256 + c, px0 & 63)] = o5;
    }
}

// ---------------------------------------------------------------------------
// K3: per (b,h): S = q k^T + row norms via MFMA, softmax, attn_proj fold -> M.
// ---------------------------------------------------------------------------
__global__ __launch_bounds__(256) void attn_M(const ushort* __restrict__ qkv,
                                              const float* __restrict__ temp,
                                              const float* __restrict__ attn_proj,
                                              ushort* __restrict__ M) {
    __shared__ float Sp[4][16][16];
    __shared__ float QSS[4][16], KSS[4][16];
    __shared__ float A[16][17];

    const int bh = blockIdx.x, b = bh >> 3, h = bh & 7;
    const int tid = threadIdx.x;
    const int w = tid >> 6, lane = tid & 63;
    const int lr = lane & 15, lg = lane >> 4;

    const size_t qbase = (((size_t)b * 256 + w * 64) * 384 + h * 16 + lr) * 64 + lg * 8;
    const size_t kbase = qbase + (size_t)128 * 64;

    f32x4 acc = {0.f, 0.f, 0.f, 0.f};
    f32x4 accq = {0.f, 0.f, 0.f, 0.f};
    f32x4 acck = {0.f, 0.f, 0.f, 0.f};
#pragma unroll 2
    for (int it = 0; it < 128; it++) {
        size_t off = (size_t)(it >> 1) * (384 * 64) + (it & 1) * 32;
        bf16x8 qf = __builtin_bit_cast(bf16x8, *(const ushort8v*)(qkv + qbase + off));
        bf16x8 kf = __builtin_bit_cast(bf16x8, *(const ushort8v*)(qkv + kbase + off));
        acc = __builtin_amdgcn_mfma_f32_16x16x32_bf16(qf, kf, acc, 0, 0, 0);
        accq = __builtin_amdgcn_mfma_f32_16x16x32_bf16(qf, qf, accq, 0, 0, 0);
        acck = __builtin_amdgcn_mfma_f32_16x16x32_bf16(kf, kf, acck, 0, 0, 0);
    }
#pragma unroll
    for (int r = 0; r < 4; r++) Sp[w][lg * 4 + r][lr] = acc[r];
    if (lg == (lr >> 2)) {
        QSS[w][lr] = accq[lr & 3];
        KSS[w][lr] = acck[lr & 3];
    }
    __syncthreads();

    const int d = tid >> 4, e = tid & 15;
    float S = Sp[0][d][e] + Sp[1][d][e] + Sp[2][d][e] + Sp[3][d][e];
    float nq = fmaxf(sqrtf(QSS[0][d] + QSS[1][d] + QSS[2][d] + QSS[3][d]), 1e-12f);
    float nk = fmaxf(sqrtf(KSS[0][e] + KSS[1][e] + KSS[2][e] + KSS[3][e]), 1e-12f);
    float logit = S / (nq * nk) * temp[h];
    float m = logit;
    for (int off = 8; off; off >>= 1) m = fmaxf(m, __shfl_xor(m, off, 64));
    float ex = expf(logit - m);
    float sum = ex;
    for (int off = 8; off; off >>= 1) sum += __shfl_xor(sum, off, 64);
    A[d][e] = ex / sum;
    __syncthreads();

    for (int i = tid; i < 2048; i += 256) {
        int o = i >> 4, ee = i & 15;
        float acc2 = 0.f;
#pragma unroll
        for (int dd = 0; dd < 16; dd++) acc2 += attn_proj[o * 128 + h * 16 + dd] * A[dd][ee];
        M[((size_t)b * 128 + o) * 128 + h * 16 + ee] = f2bf(acc2);
    }
}

// ---------------------------------------------------------------------------
// K4+K5 FUSED: x2 = x + M_b @ v, then t = pin @ LN2(x2). V stage: bulk loads
// then transpose-write (rule #20: all indices static).
// ---------------------------------------------------------------------------
__global__ __launch_bounds__(256) void mv_ln_mfma(const ushort* __restrict__ qkv,
                                                  const ushort* __restrict__ Mb16,
                                                  const float* __restrict__ x,
                                                  const ushort* __restrict__ pin_b,
                                                  const float* __restrict__ gamma,
                                                  const float* __restrict__ beta,
                                                  ushort* __restrict__ x2,
                                                  ushort* __restrict__ t_out) {
    __shared__ ushort vs[64][136];  // [px][ch] V tile
    __shared__ ushort xs[64][136];  // [px][ch] x2 tile
    __shared__ float red[2][4][64];
    __shared__ float mu[64], rs[64];
    __shared__ float gl[128], bl[128];

    const int blk = blockIdx.x;
    const int b = blk >> 8;
    const int tile = blk & 255;
    const int tid = threadIdx.x;
    const int wv = tid >> 6, lane = tid & 63;
    const int lr = lane & 15, lg = lane >> 4;

    // stage V: bulk 16B loads, then LDS transpose
    const ushort* vb = qkv + tadr(b, 384, tile, 256, 0);
    ushort8v vv[4];
#pragma unroll
    for (int k = 0; k < 4; k++) {
        int idx = tid + k * 256;
        int c = idx & 127, pg = idx >> 7;
        vv[k] = *(const ushort8v*)&vb[c * 64 + pg * 8];
    }
    if (tid < 128) {
        gl[tid] = gamma[tid];
        bl[tid] = beta[tid];
    }
#pragma unroll
    for (int k = 0; k < 4; k++) {
        int idx = tid + k * 256;
        int c = idx & 127, pg = idx >> 7;
#pragma unroll
        for (int j = 0; j < 8; j++) vs[pg * 8 + j][c] = vv[k][j];
    }
    __syncthreads();

    // MV GEMM
    bf16x8 bfr[4][4];
#pragma unroll
    for (int t = 0; t < 4; t++)
#pragma unroll
        for (int kc = 0; kc < 4; kc++)
            bfr[t][kc] = __builtin_bit_cast(bf16x8, *(const ushort8v*)&vs[t * 16 + lr][kc * 32 + lg * 8]);

    const ushort* Mb = Mb16 + (size_t)b * 128 * 128;
#pragma unroll 1
    for (int mt = 0; mt < 2; mt++) {
        const int o0 = (wv * 2 + mt) * 16;
        bf16x8 afr[4];
#pragma unroll
        for (int kc = 0; kc < 4; kc++)
            afr[kc] = __builtin_bit_cast(bf16x8,
                *(const ushort8v*)&Mb[(size_t)(o0 + lr) * 128 + kc * 32 + lg * 8]);
        f32x4 acc[4] = {{0.f, 0.f, 0.f, 0.f}, {0.f, 0.f, 0.f, 0.f}, {0.f, 0.f, 0.f, 0.f}, {0.f, 0.f, 0.f, 0.f}};
#pragma unroll
        for (int kc = 0; kc < 4; kc++)
#pragma unroll
            for (int t = 0; t < 4; t++)
                acc[t] = __builtin_amdgcn_mfma_f32_16x16x32_bf16(afr[kc], bfr[t][kc], acc[t], 0, 0, 0);
#pragma unroll
        for (int t = 0; t < 4; t++) {
            int px = t * 16 + lr;
            const float* xp = &x[((size_t)b * 128 + o0 + lg * 4) * NPIX + tile * 64 + px];
            uint2 pk;
            pk.x = packbf(xp[0] + acc[t][0], xp[NPIX] + acc[t][1]);
            pk.y = packbf(xp[2 * NPIX] + acc[t][2], xp[3 * NPIX] + acc[t][3]);
            *(uint2*)&xs[px][o0 + lg * 4] = pk;
        }
    }
    __syncthreads();

    // copy xs -> x2 (px-major, coalesced) ; LN stats
#pragma unroll
    for (int k = 0; k < 4; k++) {
        int idx = tid + k * 256;
        int p = idx >> 4, seg = idx & 15;
        uint4 v = *(const uint4*)&xs[p][seg * 8];
        *(uint4*)&x2[padr(b, tile, p, seg * 8)] = v;
    }
    {
        const int p = tid & 63, part = tid >> 6;
        float s = 0.f, ss = 0.f;
#pragma unroll
        for (int q = 0; q < 4; q++) {
            ushort8v u = *(const ushort8v*)&xs[p][part * 32 + q * 8];
#pragma unroll
            for (int j = 0; j < 8; j++) {
                float v = b2f(u[j]);
                s += v;
                ss += v * v;
            }
        }
        red[0][part][p] = s;
        red[1][part][p] = ss;
    }
    __syncthreads();
    if (tid < 64) {
        float s = red[0][0][tid] + red[0][1][tid] + red[0][2][tid] + red[0][3][tid];
        float ss = red[1][0][tid] + red[1][1][tid] + red[1][2][tid] + red[1][3][tid];
        float m = s * (1.f / 128.f);
        float var = ss * (1.f / 128.f) - m * m;
        mu[tid] = m;
        rs[tid] = rsqrtf(var + 1e-5f);
    }
    __syncthreads();
    {
        const int p = tid & 63, part = tid >> 6;
        const float mp = mu[p], rp = rs[p];
#pragma unroll
        for (int q = 0; q < 4; q++) {
            int c0 = part * 32 + q * 8;
            ushort8v u = *(const ushort8v*)&xs[p][c0];
            ushort8v o;
#pragma unroll
            for (int j = 0; j < 8; j++) {
                float v = b2f(u[j]);
                o[j] = f2bf((v - mp) * rp * gl[c0 + j] + bl[c0 + j]);
            }
            *(ushort8v*)&xs[p][c0] = o;
        }
    }
    __syncthreads();

    // pin GEMM (O=256)
    bf16x8 bfr2[4][4];
#pragma unroll
    for (int t = 0; t < 4; t++)
#pragma unroll
        for (int kc = 0; kc < 4; kc++)
            bfr2[t][kc] = __builtin_bit_cast(bf16x8, *(const ushort8v*)&xs[t * 16 + lr][kc * 32 + lg * 8]);

#pragma unroll 1
    for (int mt = 0; mt < 4; mt++) {
        const int o0 = (wv * 4 + mt) * 16;
        bf16x8 afr[4];
#pragma unroll
        for (int kc = 0; kc < 4; kc++)
            afr[kc] = __builtin_bit_cast(bf16x8,
                *(const ushort8v*)&pin_b[(size_t)(o0 + lr) * 128 + kc * 32 + lg * 8]);
        f32x4 acc[4] = {{0.f, 0.f, 0.f, 0.f}, {0.f, 0.f, 0.f, 0.f}, {0.f, 0.f, 0.f, 0.f}, {0.f, 0.f, 0.f, 0.f}};
#pragma unroll
        for (int kc = 0; kc < 4; kc++)
#pragma unroll
            for (int t = 0; t < 4; t++)
                acc[t] = __builtin_amdgcn_mfma_f32_16x16x32_bf16(afr[kc], bfr2[t][kc], acc[t], 0, 0, 0);
#pragma unroll
        for (int t = 0; t < 4; t++)
#pragma unroll
            for (int r = 0; r < 4; r++) {
                int o = o0 + lg * 4 + r;
                t_out[tadr(b, 256, tile, o, t * 16 + lr)] = f2bf(acc[t][r]);
            }
    }
}

// ---------------------------------------------------------------------------
// K8: out = x2 + pout[128,512] @ gated via MFMA.
// BULK PREFETCH: all 8 chunks' loads issued before the first barrier (256 B
// in flight per thread -> BW-saturating burst; the single vmcnt(0) drain at
// the first __syncthreads covers them all). MFMA phases then run from
// register->LDS ping-pong with no VMEM stalls. All prefetch indices static.
// ---------------------------------------------------------------------------
__global__ __launch_bounds__(256) void gdfn_mfma(const ushort* __restrict__ gated,
                                                 const ushort* __restrict__ x2,
                                                 const ushort* __restrict__ pout_b,
                                                 float* __restrict__ out) {
    __shared__ ushort gs[2][64][72];

    const int blk = blockIdx.x;
    const int b = blk >> 8;
    const int tile = blk & 255;
    const int tid = threadIdx.x;
    const int wv = tid >> 6, lane = tid & 63;
    const int lr = lane & 15, lg = lane >> 4;

    const ushort* gb = gated + tadr(b, 512, tile, 0, 0);
    const int c0 = tid & 63;   // channel within chunk
    const int pg0 = tid >> 6;  // px-group 0..3 (second half: +4)

    // bulk-issue all 8 chunks (16 x 16B loads per thread)
    ushort8v pa[8], pb[8];
#pragma unroll
    for (int k = 0; k < 8; k++) {
        const ushort* nb = gb + k * 4096;
        pa[k] = *(const ushort8v*)&nb[c0 * 64 + pg0 * 8];
        pb[k] = *(const ushort8v*)&nb[c0 * 64 + (pg0 + 4) * 8];
    }

    f32x4 acc[2][4];
#pragma unroll
    for (int mt = 0; mt < 2; mt++)
#pragma unroll
        for (int tt = 0; tt < 4; tt++) acc[mt][tt] = (f32x4){0.f, 0.f, 0.f, 0.f};

    // chunk 0 -> buf 0
#pragma unroll
    for (int j = 0; j < 8; j++) {
        gs[0][pg0 * 8 + j][c0] = pa[0][j];
        gs[0][(pg0 + 4) * 8 + j][c0] = pb[0][j];
    }
    __syncthreads();

#pragma unroll
    for (int kb = 0; kb < 8; kb++) {
        const int cur = kb & 1;

        bf16x8 bfrg[4][2];
#pragma unroll
        for (int tt = 0; tt < 4; tt++)
#pragma unroll
            for (int kc = 0; kc < 2; kc++)
                bfrg[tt][kc] = __builtin_bit_cast(bf16x8, *(const ushort8v*)&gs[cur][tt * 16 + lr][kc * 32 + lg * 8]);

#pragma unroll
        for (int mt = 0; mt < 2; mt++) {
            const int o0 = (wv * 2 + mt) * 16;
            bf16x8 afr[2];
#pragma unroll
            for (int kc = 0; kc < 2; kc++)
                afr[kc] = __builtin_bit_cast(bf16x8,
                    *(const ushort8v*)&pout_b[(size_t)(o0 + lr) * 512 + kb * 64 + kc * 32 + lg * 8]);
#pragma unroll
            for (int kc = 0; kc < 2; kc++)
#pragma unroll
                for (int tt = 0; tt < 4; tt++)
                    acc[mt][tt] = __builtin_amdgcn_mfma_f32_16x16x32_bf16(afr[kc], bfrg[tt][kc], acc[mt][tt], 0, 0, 0);
        }

        if (kb < 7) {
#pragma unroll
            for (int j = 0; j < 8; j++) {
                gs[cur ^ 1][pg0 * 8 + j][c0] = pa[kb + 1][j];
                gs[cur ^ 1][(pg0 + 4) * 8 + j][c0] = pb[kb + 1][j];
            }
        }
        __syncthreads();
    }

#pragma unroll
    for (int mt = 0; mt < 2; mt++)
#pragma unroll
        for (int tt = 0; tt < 4; tt++) {
            int o0 = (wv * 2 + mt) * 16 + lg * 4;
            int px = tt * 16 + lr;
            uint2 xw = *(const uint2*)&x2[padr(b, tile, px, o0)];
            float xv0 = u2f_lo(xw.x), xv1 = u2f_hi(xw.x);
            float xv2 = u2f_lo(xw.y), xv3 = u2f_hi(xw.y);
            size_t obase = ((size_t)b * 128 + o0) * NPIX + tile * 64 + px;
            out[obase] = xv0 + acc[mt][tt][0];
            out[obase + NPIX] = xv1 + acc[mt][tt][1];
            out[obase + 2 * NPIX] = xv2 + acc[mt][tt][2];
            out[obase + 3 * NPIX] = xv3 + acc[mt][tt][3];
        }
}

// ---------------------------------------------------------------------------
extern "C" void kernel_launch(void* const* d_in, const int* in_sizes, int n_in,
                              void* d_out, int out_size, void* d_ws, size_t ws_size,
                              hipStream_t stream) {
    const float* x = (const float*)d_in[0];
    const float* ln1_w = (const float*)d_in[1];
    const float* ln1_b = (const float*)d_in[2];
    const float* qkv_w = (const float*)d_in[3];
    const float* qkv_dw = (const float*)d_in[4];
    const float* temperature = (const float*)d_in[5];
    const float* attn_proj = (const float*)d_in[6];
    const float* ln2_w = (const float*)d_in[7];
    const float* ln2_b = (const float*)d_in[8];
    const float* pin_w = (const float*)d_in[9];
    const float* c1_w = (const float*)d_in[10];
    const float* c3_w = (const float*)d_in[11];
    const float* c5_w = (const float*)d_in[12];
    const float* pout_w = (const float*)d_in[13];
    float* out = (float*)d_out;

    char* ws = (char*)d_ws;
    ushort* qkv_pre = (ushort*)(ws + 0);            // 100,663,296 (dead after dwconv3)
    ushort* qkv     = (ushort*)(ws + 100663296);    // 100,663,296 (dead after mv_ln)
    ushort* x2      = (ushort*)(ws + 201326592);    //  33,554,432 px-major (lives to end)
    ushort* t       = (ushort*)(ws + 0);            //  67,108,864 (reuses qkv_pre)
    ushort* gated   = (ushort*)(ws + 67108864);     // 134,217,728 (reuses qkv region)
    ushort* Mb16    = (ushort*)(ws + 235151360);    //    262,144
    ushort* qkv_wb  = (ushort*)(ws + 235413504);    //     98,304
    ushort* pin_wb  = (ushort*)(ws + 235511808);    //     65,536
    ushort* pout_wb = (ushort*)(ws + 235577344);    //    131,072  (end ~235.7 MB)

    // K0: weight conversion (f32 -> bf16)
    wcvt<<<576, 256, 0, stream>>>(qkv_w, qkv_wb, 49152, pin_w, pin_wb, 32768, pout_w, pout_wb, 65536);
    // K1: qkv_pre = qkv_w @ LN1(x)
    ln_gemm_mfma<384><<<2048, 256, 0, stream>>>(x, qkv_wb, ln1_w, ln1_b, qkv_pre);
    // K2: qkv = dwconv3x3(qkv_pre)
    dwconv3_lds<<<dim3(384, 8), 256, 0, stream>>>(qkv_pre, qkv_dw, qkv, 384);
    // K3: attention (norms + QK^T + softmax + attn_proj fold)
    attn_M<<<64, 256, 0, stream>>>(qkv, temperature, attn_proj, Mb16);
    // K4+K5 fused: x2 = x + M_b @ v ; t = pin @ LN2(x2)
    mv_ln_mfma<<<2048, 256, 0, stream>>>(qkv, Mb16, x, pin_wb, ln2_w, ln2_b, x2, t);
    // K6/K7 fused + gating
    dw_gated<<<dim3(256, 8), 256, 0, stream>>>(t, c3_w, c5_w, c1_w, gated);
    // K8: out = x2 + pout @ gated
    gdfn_mfma<<<2048, 256, 0, stream>>>(gated, x2, pout_wb, out);
}

// Round 11
// 312.925 us; speedup vs baseline: 6.0581x; 1.0152x over previous
//
#include <hip/hip_runtime.h>
#include <type_traits>

typedef unsigned short ushort;
typedef unsigned int uint;
typedef __bf16 bf16x8 __attribute__((ext_vector_type(8)));
typedef unsigned short ushort8v __attribute__((ext_vector_type(8)));
typedef float f32x4 __attribute__((ext_vector_type(4)));

__device__ __forceinline__ float b2f(ushort u) {
    unsigned int x = ((unsigned int)u) << 16;
    float f;
    __builtin_memcpy(&f, &x, 4);
    return f;
}
__device__ __forceinline__ ushort f2bf(float f) {
    unsigned int x;
    __builtin_memcpy(&x, &f, 4);
    unsigned int r = x + 0x7fffu + ((x >> 16) & 1u);
    return (ushort)(r >> 16);
}
__device__ __forceinline__ float u2f_lo(uint u) {
    uint x = u << 16;
    float f;
    __builtin_memcpy(&f, &x, 4);
    return f;
}
__device__ __forceinline__ float u2f_hi(uint u) {
    uint x = u & 0xffff0000u;
    float f;
    __builtin_memcpy(&f, &x, 4);
    return f;
}
__device__ __forceinline__ uint packbf(float a, float b) {
    return (uint)f2bf(a) | ((uint)f2bf(b) << 16);
}

#define NPIX 16384  // H*W = 128*128
#define PSTRIDE 136 // padded plane row stride (ushorts); 68 uints

// Channel-major tiled layout: [b][tile(256)][ch(CH)][64 px]
__device__ __forceinline__ size_t tadr(int b, int CH, int tile, int ch, int off) {
    return (((size_t)b * 256 + tile) * CH + ch) * 64 + off;
}
// Pixel-major tiled layout for x2: [b][tile(256)][px(64)][ch(128)]
__device__ __forceinline__ size_t padr(int b, int tile, int p, int c) {
    return (((size_t)b * 256 + tile) * 64 + p) * 128 + c;
}

// ---------------------------------------------------------------------------
// stage one 128x128 plane (channel c of ch-major tiled tensor) into padded LDS.
// ---------------------------------------------------------------------------
__device__ __forceinline__ void stage_plane(ushort* pl, const ushort* __restrict__ src,
                                            int b, int c, int CH, int tid) {
    uint* plu = (uint*)pl;
    for (int i = tid; i < 784; i += 256) {
        int idx;
        if (i < 136) idx = i;                       // rows 0-1
        else if (i < 272) idx = 8840 + (i - 136);   // rows 130-131
        else {
            int j = i - 272;
            int r = (j >> 2) + 2;                   // rows 2..129
            int cs = j & 3;
            idx = r * 68 + (cs == 0 ? 0 : 64 + cs); // uint 0 (left pad), 65-67 (right pad)
        }
        plu[idx] = 0u;
    }
    for (int i = tid; i < 2048; i += 256) {
        int row = i >> 4, xg = (i & 15) << 3;
        int px0 = row * 128 + xg;
        uint4 v = *(const uint4*)&src[tadr(b, CH, px0 >> 6, c, px0 & 63)];
        uint* dst = (uint*)&pl[(row + 2) * PSTRIDE + xg + 2];
        dst[0] = v.x; dst[1] = v.y; dst[2] = v.z; dst[3] = v.w;
    }
    __syncthreads();
}

// unpack 12 consecutive bf16 at rowp (16B-aligned) into f32
__device__ __forceinline__ void unpack12(const ushort* rowp, float* cc) {
    const uint* rp = (const uint*)rowp;
    uint4 u = *(const uint4*)rp;
    uint2 v = *(const uint2*)(rp + 4);
    cc[0] = u2f_lo(u.x); cc[1] = u2f_hi(u.x);
    cc[2] = u2f_lo(u.y); cc[3] = u2f_hi(u.y);
    cc[4] = u2f_lo(u.z); cc[5] = u2f_hi(u.z);
    cc[6] = u2f_lo(u.w); cc[7] = u2f_hi(u.w);
    cc[8] = u2f_lo(v.x); cc[9] = u2f_hi(v.x);
    cc[10] = u2f_lo(v.y); cc[11] = u2f_hi(v.y);
}

// ---------------------------------------------------------------------------
// K0: convert fp32 weights to bf16 once (qkv_w, pin_w, pout_w).
// ---------------------------------------------------------------------------
__global__ __launch_bounds__(256) void wcvt(const float* __restrict__ s0, ushort* __restrict__ d0, int n0,
                                            const float* __restrict__ s1, ushort* __restrict__ d1, int n1,
                                            const float* __restrict__ s2, ushort* __restrict__ d2, int n2) {
    int i = blockIdx.x * 256 + threadIdx.x;
    if (i < n0) d0[i] = f2bf(s0[i]);
    else if (i < n0 + n1) d1[i - n0] = f2bf(s1[i - n0]);
    else if (i < n0 + n1 + n2) d2[i - n0 - n1] = f2bf(s2[i - n0 - n1]);
}

// ---------------------------------------------------------------------------
// K1: fused LayerNorm(C=128) + qkv 1x1 conv via MFMA. Planar f32 input.
// Weight fragments software-pipelined across the mt loop (prefetch mt+1
// during mt's MFMA burst so the L2 load latency hides under compute).
// ---------------------------------------------------------------------------
template <int O>
__global__ __launch_bounds__(256) void ln_gemm_mfma(const float* __restrict__ xin,
                                                    const ushort* __restrict__ Wb,
                                                    const float* __restrict__ gamma,
                                                    const float* __restrict__ beta,
                                                    ushort* __restrict__ out) {
    __shared__ ushort xs[64][136];
    __shared__ float red[2][4][64];
    __shared__ float mu[64], rs[64];
    __shared__ float gl[128], bl[128];

    const int blk = blockIdx.x;
    const int b = blk >> 8;
    const int tile = blk & 255;
    const int tid = threadIdx.x;

    const float* xb = xin + (size_t)b * 128 * NPIX + tile * 64;
    float vx[4][8];
#pragma unroll
    for (int k = 0; k < 4; k++) {
        int i = tid + k * 256;
        int p = i & 63, cg = i >> 6;
        const float* src = xb + (size_t)(cg * 8) * NPIX + p;
#pragma unroll
        for (int j = 0; j < 8; j++) vx[k][j] = src[(size_t)j * NPIX];
    }
    if (tid < 128) {
        gl[tid] = gamma[tid];
        bl[tid] = beta[tid];
    }
#pragma unroll
    for (int k = 0; k < 4; k++) {
        int i = tid + k * 256;
        int p = i & 63, cg = i >> 6;
        ushort8v u;
#pragma unroll
        for (int j = 0; j < 8; j++) u[j] = f2bf(vx[k][j]);
        *(ushort8v*)&xs[p][cg * 8] = u;
    }
    __syncthreads();

    {
        const int p = tid & 63, part = tid >> 6;
        float s = 0.f, ss = 0.f;
#pragma unroll
        for (int q = 0; q < 4; q++) {
            ushort8v u = *(const ushort8v*)&xs[p][part * 32 + q * 8];
#pragma unroll
            for (int j = 0; j < 8; j++) {
                float v = b2f(u[j]);
                s += v;
                ss += v * v;
            }
        }
        red[0][part][p] = s;
        red[1][part][p] = ss;
    }
    __syncthreads();
    if (tid < 64) {
        float s = red[0][0][tid] + red[0][1][tid] + red[0][2][tid] + red[0][3][tid];
        float ss = red[1][0][tid] + red[1][1][tid] + red[1][2][tid] + red[1][3][tid];
        float m = s * (1.f / 128.f);
        float var = ss * (1.f / 128.f) - m * m;
        mu[tid] = m;
        rs[tid] = rsqrtf(var + 1e-5f);
    }
    __syncthreads();
    {
        const int p = tid & 63, part = tid >> 6;
        const float mp = mu[p], rp = rs[p];
#pragma unroll
        for (int q = 0; q < 4; q++) {
            int c0 = part * 32 + q * 8;
            ushort8v u = *(const ushort8v*)&xs[p][c0];
            ushort8v o;
#pragma unroll
            for (int j = 0; j < 8; j++) {
                float v = b2f(u[j]);
                o[j] = f2bf((v - mp) * rp * gl[c0 + j] + bl[c0 + j]);
            }
            *(ushort8v*)&xs[p][c0] = o;
        }
    }
    __syncthreads();

    const int wv = tid >> 6, lane = tid & 63;
    const int lr = lane & 15, lg = lane >> 4;

    bf16x8 bfr[4][4];
#pragma unroll
    for (int t = 0; t < 4; t++)
#pragma unroll
        for (int kc = 0; kc < 4; kc++)
            bfr[t][kc] = __builtin_bit_cast(bf16x8, *(const ushort8v*)&xs[t * 16 + lr][kc * 32 + lg * 8]);

    constexpr int MT = O / 64;
    // pipelined weight fragments (ping-pong)
    bf16x8 afp[2][4];
    {
        const int o0 = (wv * MT) * 16;
#pragma unroll
        for (int kc = 0; kc < 4; kc++)
            afp[0][kc] = __builtin_bit_cast(bf16x8,
                *(const ushort8v*)&Wb[(size_t)(o0 + lr) * 128 + kc * 32 + lg * 8]);
    }
#pragma unroll
    for (int mt = 0; mt < MT; mt++) {
        if (mt + 1 < MT) {
            const int o0n = (wv * MT + mt + 1) * 16;
#pragma unroll
            for (int kc = 0; kc < 4; kc++)
                afp[(mt + 1) & 1][kc] = __builtin_bit_cast(bf16x8,
                    *(const ushort8v*)&Wb[(size_t)(o0n + lr) * 128 + kc * 32 + lg * 8]);
        }
        const int o0 = (wv * MT + mt) * 16;
        f32x4 acc[4] = {{0.f, 0.f, 0.f, 0.f}, {0.f, 0.f, 0.f, 0.f}, {0.f, 0.f, 0.f, 0.f}, {0.f, 0.f, 0.f, 0.f}};
#pragma unroll
        for (int kc = 0; kc < 4; kc++)
#pragma unroll
            for (int t = 0; t < 4; t++)
                acc[t] = __builtin_amdgcn_mfma_f32_16x16x32_bf16(afp[mt & 1][kc], bfr[t][kc], acc[t], 0, 0, 0);
#pragma unroll
        for (int t = 0; t < 4; t++)
#pragma unroll
            for (int r = 0; r < 4; r++) {
                int o = o0 + lg * 4 + r;
                out[tadr(b, O, tile, o, t * 16 + lr)] = f2bf(acc[t][r]);
            }
    }
}

// ---------------------------------------------------------------------------
// K2: 3x3 depthwise conv, one (b,c) plane per block; ch-major tiled in/out.
// ---------------------------------------------------------------------------
__global__ __launch_bounds__(256) void dwconv3_lds(const ushort* __restrict__ in,
                                                   const float* __restrict__ wdw,
                                                   ushort* __restrict__ out, int CH) {
    __shared__ ushort pl[132 * PSTRIDE];
    const int c = blockIdx.x;
    const int b = blockIdx.y;
    const int tid = threadIdx.x;

    float w[9];
#pragma unroll
    for (int j = 0; j < 9; j++) w[j] = wdw[c * 9 + j];

    stage_plane(pl, in, b, c, CH, tid);

    const int x = (tid & 15) * 8;
    const int ybase = tid >> 4;
#pragma unroll 1
    for (int k = 0; k < 8; k++) {
        const int y = k * 16 + ybase;
        float a[8];
#pragma unroll
        for (int p = 0; p < 8; p++) a[p] = 0.f;
#pragma unroll
        for (int ky = 0; ky < 3; ky++) {
            float cc[12];
            unpack12(&pl[(y + ky + 1) * PSTRIDE + x], cc);
#pragma unroll
            for (int kx = 0; kx < 3; kx++) {
                float wv = w[ky * 3 + kx];
#pragma unroll
                for (int p = 0; p < 8; p++) a[p] += cc[p + kx + 1] * wv;
            }
        }
        const int px0 = (y << 7) + x;
        uint4 o;
        o.x = packbf(a[0], a[1]);
        o.y = packbf(a[2], a[3]);
        o.z = packbf(a[4], a[5]);
        o.w = packbf(a[6], a[7]);
        *(uint4*)&out[tadr(b, CH, px0 >> 6, c, px0 & 63)] = o;
    }
}

// ---------------------------------------------------------------------------
// K6/K7/gating fused: ch-major tiled in/out (unchanged).
// ---------------------------------------------------------------------------
__global__ __launch_bounds__(256) void dw_gated(const ushort* __restrict__ t,
                                                const float* __restrict__ w3_,
                                                const float* __restrict__ w5_,
                                                const float* __restrict__ c1w,
                                                ushort* __restrict__ gated) {
    __shared__ ushort pl[132 * PSTRIDE];
    const int c = blockIdx.x;
    const int b = blockIdx.y;
    const int tid = threadIdx.x;

    float w3[9], w5[25];
#pragma unroll
    for (int j = 0; j < 9; j++) w3[j] = w3_[c * 9 + j];
#pragma unroll
    for (int j = 0; j < 25; j++) w5[j] = w5_[c * 25 + j];
    const float c1v = c1w[c];

    stage_plane(pl, t, b, c, 256, tid);

    const int x = (tid & 15) * 8;
    const int ybase = tid >> 4;
#pragma unroll 1
    for (int k = 0; k < 8; k++) {
        const int y = k * 16 + ybase;
        float a5[8], a3[8], tc[8];
#pragma unroll
        for (int p = 0; p < 8; p++) { a5[p] = 0.f; a3[p] = 0.f; }
#pragma unroll
        for (int ky = 0; ky < 5; ky++) {
            float cc[12];
            unpack12(&pl[(y + ky) * PSTRIDE + x], cc);
#pragma unroll
            for (int kx = 0; kx < 5; kx++) {
                float wv = w5[ky * 5 + kx];
#pragma unroll
                for (int p = 0; p < 8; p++) a5[p] += cc[p + kx] * wv;
            }
            if (ky >= 1 && ky <= 3) {
#pragma unroll
                for (int kx = 0; kx < 3; kx++) {
                    float wv = w3[(ky - 1) * 3 + kx];
#pragma unroll
                    for (int p = 0; p < 8; p++) a3[p] += cc[p + kx + 1] * wv;
                }
            }
            if (ky == 2) {
#pragma unroll
                for (int p = 0; p < 8; p++) tc[p] = cc[p + 2];
            }
        }
        const int px0 = (y << 7) + x;
        uint4 o3, o5;
        float g[8];
#pragma unroll
        for (int p = 0; p < 8; p++) {
            float x1 = tc[p] * c1v;
            g[p] = x1 * __builtin_amdgcn_rcpf(1.f + __expf(-1.702f * x1));
        }
        o3.x = packbf(g[0] * a3[0], g[1] * a3[1]);
        o3.y = packbf(g[2] * a3[2], g[3] * a3[3]);
        o3.z = packbf(g[4] * a3[4], g[5] * a3[5]);
        o3.w = packbf(g[6] * a3[6], g[7] * a3[7]);
        o5.x = packbf(g[0] * a5[0], g[1] * a5[1]);
        o5.y = packbf(g[2] * a5[2], g[3] * a5[3]);
        o5.z = packbf(g[4] * a5[4], g[5] * a5[5]);
        o5.w = packbf(g[6] * a5[6], g[7] * a5[7]);
        *(uint4*)&gated[tadr(b, 512, px0 >> 6, c, px0 & 63)] = o3;
        *(uint4*)&gated[tadr(b, 512, px0 >> 6, 256 + c, px0 & 63)] = o5;
    }
}

// ---------------------------------------------------------------------------
// K3: per (b,h): S = q k^T + row norms via MFMA, softmax, attn_proj fold -> M.
// ---------------------------------------------------------------------------
__global__ __launch_bounds__(256) void attn_M(const ushort* __restrict__ qkv,
                                              const float* __restrict__ temp,
                                              const float* __restrict__ attn_proj,
                                              ushort* __restrict__ M) {
    __shared__ float Sp[4][16][16];
    __shared__ float QSS[4][16], KSS[4][16];
    __shared__ float A[16][17];

    const int bh = blockIdx.x, b = bh >> 3, h = bh & 7;
    const int tid = threadIdx.x;
    const int w = tid >> 6, lane = tid & 63;
    const int lr = lane & 15, lg = lane >> 4;

    const size_t qbase = (((size_t)b * 256 + w * 64) * 384 + h * 16 + lr) * 64 + lg * 8;
    const size_t kbase = qbase + (size_t)128 * 64;

    f32x4 acc = {0.f, 0.f, 0.f, 0.f};
    f32x4 accq = {0.f, 0.f, 0.f, 0.f};
    f32x4 acck = {0.f, 0.f, 0.f, 0.f};
#pragma unroll 2
    for (int it = 0; it < 128; it++) {
        size_t off = (size_t)(it >> 1) * (384 * 64) + (it & 1) * 32;
        bf16x8 qf = __builtin_bit_cast(bf16x8, *(const ushort8v*)(qkv + qbase + off));
        bf16x8 kf = __builtin_bit_cast(bf16x8, *(const ushort8v*)(qkv + kbase + off));
        acc = __builtin_amdgcn_mfma_f32_16x16x32_bf16(qf, kf, acc, 0, 0, 0);
        accq = __builtin_amdgcn_mfma_f32_16x16x32_bf16(qf, qf, accq, 0, 0, 0);
        acck = __builtin_amdgcn_mfma_f32_16x16x32_bf16(kf, kf, acck, 0, 0, 0);
    }
#pragma unroll
    for (int r = 0; r < 4; r++) Sp[w][lg * 4 + r][lr] = acc[r];
    if (lg == (lr >> 2)) {
        QSS[w][lr] = accq[lr & 3];
        KSS[w][lr] = acck[lr & 3];
    }
    __syncthreads();

    const int d = tid >> 4, e = tid & 15;
    float S = Sp[0][d][e] + Sp[1][d][e] + Sp[2][d][e] + Sp[3][d][e];
    float nq = fmaxf(sqrtf(QSS[0][d] + QSS[1][d] + QSS[2][d] + QSS[3][d]), 1e-12f);
    float nk = fmaxf(sqrtf(KSS[0][e] + KSS[1][e] + KSS[2][e] + KSS[3][e]), 1e-12f);
    float logit = S / (nq * nk) * temp[h];
    float m = logit;
    for (int off = 8; off; off >>= 1) m = fmaxf(m, __shfl_xor(m, off, 64));
    float ex = expf(logit - m);
    float sum = ex;
    for (int off = 8; off; off >>= 1) sum += __shfl_xor(sum, off, 64);
    A[d][e] = ex / sum;
    __syncthreads();

    for (int i = tid; i < 2048; i += 256) {
        int o = i >> 4, ee = i & 15;
        float acc2 = 0.f;
#pragma unroll
        for (int dd = 0; dd < 16; dd++) acc2 += attn_proj[o * 128 + h * 16 + dd] * A[dd][ee];
        M[((size_t)b * 128 + o) * 128 + h * 16 + ee] = f2bf(acc2);
    }
}

// ---------------------------------------------------------------------------
// K4+K5 FUSED: x2 = x + M_b @ v, then t = pin @ LN2(x2).
// Mb fragments hoisted to kernel entry (latency hidden under V staging);
// pin fragments pipelined across the mt loop.
// ---------------------------------------------------------------------------
__global__ __launch_bounds__(256) void mv_ln_mfma(const ushort* __restrict__ qkv,
                                                  const ushort* __restrict__ Mb16,
                                                  const float* __restrict__ x,
                                                  const ushort* __restrict__ pin_b,
                                                  const float* __restrict__ gamma,
                                                  const float* __restrict__ beta,
                                                  ushort* __restrict__ x2,
                                                  ushort* __restrict__ t_out) {
    __shared__ ushort vs[64][136];  // [px][ch] V tile
    __shared__ ushort xs[64][136];  // [px][ch] x2 tile
    __shared__ float red[2][4][64];
    __shared__ float mu[64], rs[64];
    __shared__ float gl[128], bl[128];

    const int blk = blockIdx.x;
    const int b = blk >> 8;
    const int tile = blk & 255;
    const int tid = threadIdx.x;
    const int wv = tid >> 6, lane = tid & 63;
    const int lr = lane & 15, lg = lane >> 4;

    // hoisted M fragments (independent of staging; latency covered by it)
    const ushort* Mb = Mb16 + (size_t)b * 128 * 128;
    bf16x8 mfr[2][4];
#pragma unroll
    for (int mt = 0; mt < 2; mt++)
#pragma unroll
        for (int kc = 0; kc < 4; kc++)
            mfr[mt][kc] = __builtin_bit_cast(bf16x8,
                *(const ushort8v*)&Mb[(size_t)((wv * 2 + mt) * 16 + lr) * 128 + kc * 32 + lg * 8]);

    // stage V: bulk 16B loads, then LDS transpose
    const ushort* vb = qkv + tadr(b, 384, tile, 256, 0);
    ushort8v vv[4];
#pragma unroll
    for (int k = 0; k < 4; k++) {
        int idx = tid + k * 256;
        int c = idx & 127, pg = idx >> 7;
        vv[k] = *(const ushort8v*)&vb[c * 64 + pg * 8];
    }
    if (tid < 128) {
        gl[tid] = gamma[tid];
        bl[tid] = beta[tid];
    }
#pragma unroll
    for (int k = 0; k < 4; k++) {
        int idx = tid + k * 256;
        int c = idx & 127, pg = idx >> 7;
#pragma unroll
        for (int j = 0; j < 8; j++) vs[pg * 8 + j][c] = vv[k][j];
    }
    __syncthreads();

    // MV GEMM
    bf16x8 bfr[4][4];
#pragma unroll
    for (int t = 0; t < 4; t++)
#pragma unroll
        for (int kc = 0; kc < 4; kc++)
            bfr[t][kc] = __builtin_bit_cast(bf16x8, *(const ushort8v*)&vs[t * 16 + lr][kc * 32 + lg * 8]);

#pragma unroll
    for (int mt = 0; mt < 2; mt++) {
        const int o0 = (wv * 2 + mt) * 16;
        f32x4 acc[4] = {{0.f, 0.f, 0.f, 0.f}, {0.f, 0.f, 0.f, 0.f}, {0.f, 0.f, 0.f, 0.f}, {0.f, 0.f, 0.f, 0.f}};
#pragma unroll
        for (int kc = 0; kc < 4; kc++)
#pragma unroll
            for (int t = 0; t < 4; t++)
                acc[t] = __builtin_amdgcn_mfma_f32_16x16x32_bf16(mfr[mt][kc], bfr[t][kc], acc[t], 0, 0, 0);
#pragma unroll
        for (int t = 0; t < 4; t++) {
            int px = t * 16 + lr;
            const float* xp = &x[((size_t)b * 128 + o0 + lg * 4) * NPIX + tile * 64 + px];
            uint2 pk;
            pk.x = packbf(xp[0] + acc[t][0], xp[NPIX] + acc[t][1]);
            pk.y = packbf(xp[2 * NPIX] + acc[t][2], xp[3 * NPIX] + acc[t][3]);
            *(uint2*)&xs[px][o0 + lg * 4] = pk;
        }
    }

    // prefetch pin fragments for mt=0 (latency hidden under LN phase)
    bf16x8 pfp[2][4];
#pragma unroll
    for (int kc = 0; kc < 4; kc++)
        pfp[0][kc] = __builtin_bit_cast(bf16x8,
            *(const ushort8v*)&pin_b[(size_t)((wv * 4) * 16 + lr) * 128 + kc * 32 + lg * 8]);
    __syncthreads();

    // copy xs -> x2 (px-major, coalesced) ; LN stats
#pragma unroll
    for (int k = 0; k < 4; k++) {
        int idx = tid + k * 256;
        int p = idx >> 4, seg = idx & 15;
        uint4 v = *(const uint4*)&xs[p][seg * 8];
        *(uint4*)&x2[padr(b, tile, p, seg * 8)] = v;
    }
    {
        const int p = tid & 63, part = tid >> 6;
        float s = 0.f, ss = 0.f;
#pragma unroll
        for (int q = 0; q < 4; q++) {
            ushort8v u = *(const ushort8v*)&xs[p][part * 32 + q * 8];
#pragma unroll
            for (int j = 0; j < 8; j++) {
                float v = b2f(u[j]);
                s += v;
                ss += v * v;
            }
        }
        red[0][part][p] = s;
        red[1][part][p] = ss;
    }
    __syncthreads();
    if (tid < 64) {
        float s = red[0][0][tid] + red[0][1][tid] + red[0][2][tid] + red[0][3][tid];
        float ss = red[1][0][tid] + red[1][1][tid] + red[1][2][tid] + red[1][3][tid];
        float m = s * (1.f / 128.f);
        float var = ss * (1.f / 128.f) - m * m;
        mu[tid] = m;
        rs[tid] = rsqrtf(var + 1e-5f);
    }
    __syncthreads();
    {
        const int p = tid & 63, part = tid >> 6;
        const float mp = mu[p], rp = rs[p];
#pragma unroll
        for (int q = 0; q < 4; q++) {
            int c0 = part * 32 + q * 8;
            ushort8v u = *(const ushort8v*)&xs[p][c0];
            ushort8v o;
#pragma unroll
            for (int j = 0; j < 8; j++) {
                float v = b2f(u[j]);
                o[j] = f2bf((v - mp) * rp * gl[c0 + j] + bl[c0 + j]);
            }
            *(ushort8v*)&xs[p][c0] = o;
        }
    }
    __syncthreads();

    // pin GEMM (O=256), weight frags pipelined
    bf16x8 bfr2[4][4];
#pragma unroll
    for (int t = 0; t < 4; t++)
#pragma unroll
        for (int kc = 0; kc < 4; kc++)
            bfr2[t][kc] = __builtin_bit_cast(bf16x8, *(const ushort8v*)&xs[t * 16 + lr][kc * 32 + lg * 8]);

#pragma unroll
    for (int mt = 0; mt < 4; mt++) {
        if (mt + 1 < 4) {
            const int o0n = (wv * 4 + mt + 1) * 16;
#pragma unroll
            for (int kc = 0; kc < 4; kc++)
                pfp[(mt + 1) & 1][kc] = __builtin_bit_cast(bf16x8,
                    *(const ushort8v*)&pin_b[(size_t)(o0n + lr) * 128 + kc * 32 + lg * 8]);
        }
        const int o0 = (wv * 4 + mt) * 16;
        f32x4 acc[4] = {{0.f, 0.f, 0.f, 0.f}, {0.f, 0.f, 0.f, 0.f}, {0.f, 0.f, 0.f, 0.f}, {0.f, 0.f, 0.f, 0.f}};
#pragma unroll
        for (int kc = 0; kc < 4; kc++)
#pragma unroll
            for (int t = 0; t < 4; t++)
                acc[t] = __builtin_amdgcn_mfma_f32_16x16x32_bf16(pfp[mt & 1][kc], bfr2[t][kc], acc[t], 0, 0, 0);
#pragma unroll
        for (int t = 0; t < 4; t++)
#pragma unroll
            for (int r = 0; r < 4; r++) {
                int o = o0 + lg * 4 + r;
                t_out[tadr(b, 256, tile, o, t * 16 + lr)] = f2bf(acc[t][r]);
            }
    }
}

// ---------------------------------------------------------------------------
// K8: out = x2 + pout[128,512] @ gated via MFMA.
// R8-proven staging (scalar gathers + ushort8v LDS writes) restructured as
// T14: issue chunk kb+1's gathers BEFORE kb's MFMA, ds_write them AFTER it
// (the vmcnt wait lands post-MFMA, so gather latency hides under compute).
// ---------------------------------------------------------------------------
__global__ __launch_bounds__(256) void gdfn_mfma(const ushort* __restrict__ gated,
                                                 const ushort* __restrict__ x2,
                                                 const ushort* __restrict__ pout_b,
                                                 float* __restrict__ out) {
    __shared__ ushort gs[2][64][72];

    const int blk = blockIdx.x;
    const int b = blk >> 8;
    const int tile = blk & 255;
    const int tid = threadIdx.x;
    const int wv = tid >> 6, lane = tid & 63;
    const int lr = lane & 15, lg = lane >> 4;

    const ushort* gb = gated + tadr(b, 512, tile, 0, 0);
    const int p0 = tid & 63;   // pixel
    const int kga = tid >> 6;  // ch-group 0..3 (second slot: +4)

    f32x4 acc[2][4];
#pragma unroll
    for (int mt = 0; mt < 2; mt++)
#pragma unroll
        for (int tt = 0; tt < 4; tt++) acc[mt][tt] = (f32x4){0.f, 0.f, 0.f, 0.f};

    // prologue: gather chunk 0, write buf 0
    {
        ushort ca[8], cb[8];
#pragma unroll
        for (int j = 0; j < 8; j++) ca[j] = gb[(kga * 8 + j) * 64 + p0];
#pragma unroll
        for (int j = 0; j < 8; j++) cb[j] = gb[((kga + 4) * 8 + j) * 64 + p0];
        ushort8v ua, ub;
#pragma unroll
        for (int j = 0; j < 8; j++) { ua[j] = ca[j]; ub[j] = cb[j]; }
        *(ushort8v*)&gs[0][p0][kga * 8] = ua;
        *(ushort8v*)&gs[0][p0][(kga + 4) * 8] = ub;
    }
    __syncthreads();

#pragma unroll
    for (int kb = 0; kb < 8; kb++) {
        const int cur = kb & 1;

        // T14 issue-early: gather chunk kb+1 into registers (in flight)
        ushort na[8], nb[8];
        if (kb < 7) {
            const ushort* nbp = gb + (kb + 1) * 4096;
#pragma unroll
            for (int j = 0; j < 8; j++) na[j] = nbp[(kga * 8 + j) * 64 + p0];
#pragma unroll
            for (int j = 0; j < 8; j++) nb[j] = nbp[((kga + 4) * 8 + j) * 64 + p0];
        }

        // MFMA on chunk kb from buf[cur]
        bf16x8 bfrg[4][2];
#pragma unroll
        for (int tt = 0; tt < 4; tt++)
#pragma unroll
            for (int kc = 0; kc < 2; kc++)
                bfrg[tt][kc] = __builtin_bit_cast(bf16x8, *(const ushort8v*)&gs[cur][tt * 16 + lr][kc * 32 + lg * 8]);

#pragma unroll
        for (int mt = 0; mt < 2; mt++) {
            const int o0 = (wv * 2 + mt) * 16;
            bf16x8 afr[2];
#pragma unroll
            for (int kc = 0; kc < 2; kc++)
                afr[kc] = __builtin_bit_cast(bf16x8,
                    *(const ushort8v*)&pout_b[(size_t)(o0 + lr) * 512 + kb * 64 + kc * 32 + lg * 8]);
#pragma unroll
            for (int kc = 0; kc < 2; kc++)
#pragma unroll
                for (int tt = 0; tt < 4; tt++)
                    acc[mt][tt] = __builtin_amdgcn_mfma_f32_16x16x32_bf16(afr[kc], bfrg[tt][kc], acc[mt][tt], 0, 0, 0);
        }

        // T14 write-late: ds_write chunk kb+1 into the other buffer
        if (kb < 7) {
            ushort8v ua, ub;
#pragma unroll
            for (int j = 0; j < 8; j++) { ua[j] = na[j]; ub[j] = nb[j]; }
            *(ushort8v*)&gs[cur ^ 1][p0][kga * 8] = ua;
            *(ushort8v*)&gs[cur ^ 1][p0][(kga + 4) * 8] = ub;
        }
        __syncthreads();
    }

#pragma unroll
    for (int mt = 0; mt < 2; mt++)
#pragma unroll
        for (int tt = 0; tt < 4; tt++) {
            int o0 = (wv * 2 + mt) * 16 + lg * 4;
            int px = tt * 16 + lr;
            uint2 xw = *(const uint2*)&x2[padr(b, tile, px, o0)];
            float xv0 = u2f_lo(xw.x), xv1 = u2f_hi(xw.x);
            float xv2 = u2f_lo(xw.y), xv3 = u2f_hi(xw.y);
            size_t obase = ((size_t)b * 128 + o0) * NPIX + tile * 64 + px;
            out[obase] = xv0 + acc[mt][tt][0];
            out[obase + NPIX] = xv1 + acc[mt][tt][1];
            out[obase + 2 * NPIX] = xv2 + acc[mt][tt][2];
            out[obase + 3 * NPIX] = xv3 + acc[mt][tt][3];
        }
}

// ---------------------------------------------------------------------------
extern "C" void kernel_launch(void* const* d_in, const int* in_sizes, int n_in,
                              void* d_out, int out_size, void* d_ws, size_t ws_size,
                              hipStream_t stream) {
    const float* x = (const float*)d_in[0];
    const float* ln1_w = (const float*)d_in[1];
    const float* ln1_b = (const float*)d_in[2];
    const float* qkv_w = (const float*)d_in[3];
    const float* qkv_dw = (const float*)d_in[4];
    const float* temperature = (const float*)d_in[5];
    const float* attn_proj = (const float*)d_in[6];
    const float* ln2_w = (const float*)d_in[7];
    const float* ln2_b = (const float*)d_in[8];
    const float* pin_w = (const float*)d_in[9];
    const float* c1_w = (const float*)d_in[10];
    const float* c3_w = (const float*)d_in[11];
    const float* c5_w = (const float*)d_in[12];
    const float* pout_w = (const float*)d_in[13];
    float* out = (float*)d_out;

    char* ws = (char*)d_ws;
    ushort* qkv_pre = (ushort*)(ws + 0);            // 100,663,296 (dead after dwconv3)
    ushort* qkv     = (ushort*)(ws + 100663296);    // 100,663,296 (dead after mv_ln)
    ushort* x2      = (ushort*)(ws + 201326592);    //  33,554,432 px-major (lives to end)
    ushort* t       = (ushort*)(ws + 0);            //  67,108,864 (reuses qkv_pre)
    ushort* gated   = (ushort*)(ws + 67108864);     // 134,217,728 (reuses qkv region)
    ushort* Mb16    = (ushort*)(ws + 235151360);    //    262,144
    ushort* qkv_wb  = (ushort*)(ws + 235413504);    //     98,304
    ushort* pin_wb  = (ushort*)(ws + 235511808);    //     65,536
    ushort* pout_wb = (ushort*)(ws + 235577344);    //    131,072  (end ~235.7 MB)

    // K0: weight conversion (f32 -> bf16)
    wcvt<<<576, 256, 0, stream>>>(qkv_w, qkv_wb, 49152, pin_w, pin_wb, 32768, pout_w, pout_wb, 65536);
    // K1: qkv_pre = qkv_w @ LN1(x)
    ln_gemm_mfma<384><<<2048, 256, 0, stream>>>(x, qkv_wb, ln1_w, ln1_b, qkv_pre);
    // K2: qkv = dwconv3x3(qkv_pre)
    dwconv3_lds<<<dim3(384, 8), 256, 0, stream>>>(qkv_pre, qkv_dw, qkv, 384);
    // K3: attention (norms + QK^T + softmax + attn_proj fold)
    attn_M<<<64, 256, 0, stream>>>(qkv, temperature, attn_proj, Mb16);
    // K4+K5 fused: x2 = x + M_b @ v ; t = pin @ LN2(x2)
    mv_ln_mfma<<<2048, 256, 0, stream>>>(qkv, Mb16, x, pin_wb, ln2_w, ln2_b, x2, t);
    // K6/K7 fused + gating
    dw_gated<<<dim3(256, 8), 256, 0, stream>>>(t, c3_w, c5_w, c1_w, gated);
    // K8: out = x2 + pout @ gated
    gdfn_mfma<<<2048, 256, 0, stream>>>(gated, x2, pout_wb, out);
}

// Round 12
// 302.868 us; speedup vs baseline: 6.2593x; 1.0332x over previous
//
#include <hip/hip_runtime.h>
#include <type_traits>

typedef unsigned short ushort;
typedef unsigned int uint;
typedef __bf16 bf16x8 __attribute__((ext_vector_type(8)));
typedef unsigned short ushort8v __attribute__((ext_vector_type(8)));
typedef float f32x4 __attribute__((ext_vector_type(4)));

__device__ __forceinline__ float b2f(ushort u) {
    unsigned int x = ((unsigned int)u) << 16;
    float f;
    __builtin_memcpy(&f, &x, 4);
    return f;
}
__device__ __forceinline__ ushort f2bf(float f) {
    unsigned int x;
    __builtin_memcpy(&x, &f, 4);
    unsigned int r = x + 0x7fffu + ((x >> 16) & 1u);
    return (ushort)(r >> 16);
}
__device__ __forceinline__ float u2f_lo(uint u) {
    uint x = u << 16;
    float f;
    __builtin_memcpy(&f, &x, 4);
    return f;
}
__device__ __forceinline__ float u2f_hi(uint u) {
    uint x = u & 0xffff0000u;
    float f;
    __builtin_memcpy(&f, &x, 4);
    return f;
}
__device__ __forceinline__ uint packbf(float a, float b) {
    return (uint)f2bf(a) | ((uint)f2bf(b) << 16);
}

#define NPIX 16384  // H*W = 128*128
#define PSTRIDE 136 // padded plane row stride (ushorts); 68 uints

// Channel-major tiled layout: [b][tile(256)][ch(CH)][64 px]
__device__ __forceinline__ size_t tadr(int b, int CH, int tile, int ch, int off) {
    return (((size_t)b * 256 + tile) * CH + ch) * 64 + off;
}
// Pixel-major tiled layout for x2: [b][tile(256)][px(64)][ch(128)]
__device__ __forceinline__ size_t padr(int b, int tile, int p, int c) {
    return (((size_t)b * 256 + tile) * 64 + p) * 128 + c;
}

// ---------------------------------------------------------------------------
// stage one 128x128 plane (channel c of ch-major tiled tensor) into padded LDS.
// ---------------------------------------------------------------------------
__device__ __forceinline__ void stage_plane(ushort* pl, const ushort* __restrict__ src,
                                            int b, int c, int CH, int tid) {
    uint* plu = (uint*)pl;
    for (int i = tid; i < 784; i += 256) {
        int idx;
        if (i < 136) idx = i;                       // rows 0-1
        else if (i < 272) idx = 8840 + (i - 136);   // rows 130-131
        else {
            int j = i - 272;
            int r = (j >> 2) + 2;                   // rows 2..129
            int cs = j & 3;
            idx = r * 68 + (cs == 0 ? 0 : 64 + cs); // uint 0 (left pad), 65-67 (right pad)
        }
        plu[idx] = 0u;
    }
    for (int i = tid; i < 2048; i += 256) {
        int row = i >> 4, xg = (i & 15) << 3;
        int px0 = row * 128 + xg;
        uint4 v = *(const uint4*)&src[tadr(b, CH, px0 >> 6, c, px0 & 63)];
        uint* dst = (uint*)&pl[(row + 2) * PSTRIDE + xg + 2];
        dst[0] = v.x; dst[1] = v.y; dst[2] = v.z; dst[3] = v.w;
    }
    __syncthreads();
}

// unpack 12 consecutive bf16 at rowp (16B-aligned) into f32
__device__ __forceinline__ void unpack12(const ushort* rowp, float* cc) {
    const uint* rp = (const uint*)rowp;
    uint4 u = *(const uint4*)rp;
    uint2 v = *(const uint2*)(rp + 4);
    cc[0] = u2f_lo(u.x); cc[1] = u2f_hi(u.x);
    cc[2] = u2f_lo(u.y); cc[3] = u2f_hi(u.y);
    cc[4] = u2f_lo(u.z); cc[5] = u2f_hi(u.z);
    cc[6] = u2f_lo(u.w); cc[7] = u2f_hi(u.w);
    cc[8] = u2f_lo(v.x); cc[9] = u2f_hi(v.x);
    cc[10] = u2f_lo(v.y); cc[11] = u2f_hi(v.y);
}

// ---------------------------------------------------------------------------
// K0: convert fp32 weights to bf16 once (qkv_w, pin_w, pout_w).
// ---------------------------------------------------------------------------
__global__ __launch_bounds__(256) void wcvt(const float* __restrict__ s0, ushort* __restrict__ d0, int n0,
                                            const float* __restrict__ s1, ushort* __restrict__ d1, int n1,
                                            const float* __restrict__ s2, ushort* __restrict__ d2, int n2) {
    int i = blockIdx.x * 256 + threadIdx.x;
    if (i < n0) d0[i] = f2bf(s0[i]);
    else if (i < n0 + n1) d1[i - n0] = f2bf(s1[i - n0]);
    else if (i < n0 + n1 + n2) d2[i - n0 - n1] = f2bf(s2[i - n0 - n1]);
}

// ---------------------------------------------------------------------------
// K1: fused LayerNorm(C=128) + qkv 1x1 conv via MFMA. Planar f32 input.
// Wave->channel map o0=(mt*4+wv)*16 so each mt-pair covers a contiguous
// 128-ch chunk; epilogue repacks acc via LDS [px][ch] into 16B stores
// (consecutive lanes -> consecutive px: 128B segments).
// ---------------------------------------------------------------------------
template <int O>
__global__ __launch_bounds__(256) void ln_gemm_mfma(const float* __restrict__ xin,
                                                    const ushort* __restrict__ Wb,
                                                    const float* __restrict__ gamma,
                                                    const float* __restrict__ beta,
                                                    ushort* __restrict__ out) {
    __shared__ ushort xs[64][136];
    __shared__ float red[2][4][64];
    __shared__ float mu[64], rs[64];
    __shared__ float gl[128], bl[128];

    const int blk = blockIdx.x;
    const int b = blk >> 8;
    const int tile = blk & 255;
    const int tid = threadIdx.x;

    const float* xb = xin + (size_t)b * 128 * NPIX + tile * 64;
    float vx[4][8];
#pragma unroll
    for (int k = 0; k < 4; k++) {
        int i = tid + k * 256;
        int p = i & 63, cg = i >> 6;
        const float* src = xb + (size_t)(cg * 8) * NPIX + p;
#pragma unroll
        for (int j = 0; j < 8; j++) vx[k][j] = src[(size_t)j * NPIX];
    }
    if (tid < 128) {
        gl[tid] = gamma[tid];
        bl[tid] = beta[tid];
    }
#pragma unroll
    for (int k = 0; k < 4; k++) {
        int i = tid + k * 256;
        int p = i & 63, cg = i >> 6;
        ushort8v u;
#pragma unroll
        for (int j = 0; j < 8; j++) u[j] = f2bf(vx[k][j]);
        *(ushort8v*)&xs[p][cg * 8] = u;
    }
    __syncthreads();

    {
        const int p = tid & 63, part = tid >> 6;
        float s = 0.f, ss = 0.f;
#pragma unroll
        for (int q = 0; q < 4; q++) {
            ushort8v u = *(const ushort8v*)&xs[p][part * 32 + q * 8];
#pragma unroll
            for (int j = 0; j < 8; j++) {
                float v = b2f(u[j]);
                s += v;
                ss += v * v;
            }
        }
        red[0][part][p] = s;
        red[1][part][p] = ss;
    }
    __syncthreads();
    if (tid < 64) {
        float s = red[0][0][tid] + red[0][1][tid] + red[0][2][tid] + red[0][3][tid];
        float ss = red[1][0][tid] + red[1][1][tid] + red[1][2][tid] + red[1][3][tid];
        float m = s * (1.f / 128.f);
        float var = ss * (1.f / 128.f) - m * m;
        mu[tid] = m;
        rs[tid] = rsqrtf(var + 1e-5f);
    }
    __syncthreads();
    {
        const int p = tid & 63, part = tid >> 6;
        const float mp = mu[p], rp = rs[p];
#pragma unroll
        for (int q = 0; q < 4; q++) {
            int c0 = part * 32 + q * 8;
            ushort8v u = *(const ushort8v*)&xs[p][c0];
            ushort8v o;
#pragma unroll
            for (int j = 0; j < 8; j++) {
                float v = b2f(u[j]);
                o[j] = f2bf((v - mp) * rp * gl[c0 + j] + bl[c0 + j]);
            }
            *(ushort8v*)&xs[p][c0] = o;
        }
    }
    __syncthreads();

    const int wv = tid >> 6, lane = tid & 63;
    const int lr = lane & 15, lg = lane >> 4;

    bf16x8 bfr[4][4];
#pragma unroll
    for (int t = 0; t < 4; t++)
#pragma unroll
        for (int kc = 0; kc < 4; kc++)
            bfr[t][kc] = __builtin_bit_cast(bf16x8, *(const ushort8v*)&xs[t * 16 + lr][kc * 32 + lg * 8]);

    constexpr int MT = O / 64;
    // pipelined weight fragments (ping-pong); o0 = (mt*4+wv)*16
    bf16x8 afp[2][4];
#pragma unroll
    for (int kc = 0; kc < 4; kc++)
        afp[0][kc] = __builtin_bit_cast(bf16x8,
            *(const ushort8v*)&Wb[(size_t)(wv * 16 + lr) * 128 + kc * 32 + lg * 8]);

    f32x4 accPair[2][4];
    const int rc = tid & 127, rhalf = tid >> 7;  // repack-store mapping helpers
    const int px8 = tid & 7, cb = tid >> 3;      // (cb 0..31)
    ushort* outp = out + tadr(b, O, tile, 0, 0);

#pragma unroll
    for (int mt = 0; mt < MT; mt++) {
        if (mt + 1 < MT) {
            const int o0n = ((mt + 1) * 4 + wv) * 16;
#pragma unroll
            for (int kc = 0; kc < 4; kc++)
                afp[(mt + 1) & 1][kc] = __builtin_bit_cast(bf16x8,
                    *(const ushort8v*)&Wb[(size_t)(o0n + lr) * 128 + kc * 32 + lg * 8]);
        }
        f32x4* acc = accPair[mt & 1];
#pragma unroll
        for (int t = 0; t < 4; t++) acc[t] = (f32x4){0.f, 0.f, 0.f, 0.f};
#pragma unroll
        for (int kc = 0; kc < 4; kc++)
#pragma unroll
            for (int t = 0; t < 4; t++)
                acc[t] = __builtin_amdgcn_mfma_f32_16x16x32_bf16(afp[mt & 1][kc], bfr[t][kc], acc[t], 0, 0, 0);

        if (mt & 1) {
            // repack pair (channels [(mt>>1)*128, +128)) via LDS [px][ch]
            __syncthreads();  // xs free (B-frags in regs; prior chunk's reads done)
#pragma unroll
            for (int h = 0; h < 2; h++) {
                const int lc = h * 64 + wv * 16 + lg * 4;  // local channel base
#pragma unroll
                for (int t = 0; t < 4; t++) {
                    int px = t * 16 + lr;
                    uint2 pk;
                    pk.x = packbf(accPair[h][t][0], accPair[h][t][1]);
                    pk.y = packbf(accPair[h][t][2], accPair[h][t][3]);
                    *(uint2*)&xs[px][lc] = pk;
                }
            }
            __syncthreads();
            const int pairbase = (mt >> 1) * 128;
#pragma unroll
            for (int cc = 0; cc < 4; cc++) {
                int c = cb + cc * 32;
                ushort8v u;
#pragma unroll
                for (int j = 0; j < 8; j++) u[j] = xs[px8 * 8 + j][c];
                *(ushort8v*)&outp[(size_t)(pairbase + c) * 64 + px8 * 8] = u;
            }
        }
    }
    (void)rc; (void)rhalf;
}

// ---------------------------------------------------------------------------
// K2: 3x3 depthwise conv, one (b,c) plane per block; ch-major tiled in/out.
// ---------------------------------------------------------------------------
__global__ __launch_bounds__(256) void dwconv3_lds(const ushort* __restrict__ in,
                                                   const float* __restrict__ wdw,
                                                   ushort* __restrict__ out, int CH) {
    __shared__ ushort pl[132 * PSTRIDE];
    const int c = blockIdx.x;
    const int b = blockIdx.y;
    const int tid = threadIdx.x;

    float w[9];
#pragma unroll
    for (int j = 0; j < 9; j++) w[j] = wdw[c * 9 + j];

    stage_plane(pl, in, b, c, CH, tid);

    const int x = (tid & 15) * 8;
    const int ybase = tid >> 4;
#pragma unroll 1
    for (int k = 0; k < 8; k++) {
        const int y = k * 16 + ybase;
        float a[8];
#pragma unroll
        for (int p = 0; p < 8; p++) a[p] = 0.f;
#pragma unroll
        for (int ky = 0; ky < 3; ky++) {
            float cc[12];
            unpack12(&pl[(y + ky + 1) * PSTRIDE + x], cc);
#pragma unroll
            for (int kx = 0; kx < 3; kx++) {
                float wv = w[ky * 3 + kx];
#pragma unroll
                for (int p = 0; p < 8; p++) a[p] += cc[p + kx + 1] * wv;
            }
        }
        const int px0 = (y << 7) + x;
        uint4 o;
        o.x = packbf(a[0], a[1]);
        o.y = packbf(a[2], a[3]);
        o.z = packbf(a[4], a[5]);
        o.w = packbf(a[6], a[7]);
        *(uint4*)&out[tadr(b, CH, px0 >> 6, c, px0 & 63)] = o;
    }
}

// ---------------------------------------------------------------------------
// K6/K7/gating fused: ch-major tiled in/out (unchanged).
// ---------------------------------------------------------------------------
__global__ __launch_bounds__(256) void dw_gated(const ushort* __restrict__ t,
                                                const float* __restrict__ w3_,
                                                const float* __restrict__ w5_,
                                                const float* __restrict__ c1w,
                                                ushort* __restrict__ gated) {
    __shared__ ushort pl[132 * PSTRIDE];
    const int c = blockIdx.x;
    const int b = blockIdx.y;
    const int tid = threadIdx.x;

    float w3[9], w5[25];
#pragma unroll
    for (int j = 0; j < 9; j++) w3[j] = w3_[c * 9 + j];
#pragma unroll
    for (int j = 0; j < 25; j++) w5[j] = w5_[c * 25 + j];
    const float c1v = c1w[c];

    stage_plane(pl, t, b, c, 256, tid);

    const int x = (tid & 15) * 8;
    const int ybase = tid >> 4;
#pragma unroll 1
    for (int k = 0; k < 8; k++) {
        const int y = k * 16 + ybase;
        float a5[8], a3[8], tc[8];
#pragma unroll
        for (int p = 0; p < 8; p++) { a5[p] = 0.f; a3[p] = 0.f; }
#pragma unroll
        for (int ky = 0; ky < 5; ky++) {
            float cc[12];
            unpack12(&pl[(y + ky) * PSTRIDE + x], cc);
#pragma unroll
            for (int kx = 0; kx < 5; kx++) {
                float wv = w5[ky * 5 + kx];
#pragma unroll
                for (int p = 0; p < 8; p++) a5[p] += cc[p + kx] * wv;
            }
            if (ky >= 1 && ky <= 3) {
#pragma unroll
                for (int kx = 0; kx < 3; kx++) {
                    float wv = w3[(ky - 1) * 3 + kx];
#pragma unroll
                    for (int p = 0; p < 8; p++) a3[p] += cc[p + kx + 1] * wv;
                }
            }
            if (ky == 2) {
#pragma unroll
                for (int p = 0; p < 8; p++) tc[p] = cc[p + 2];
            }
        }
        const int px0 = (y << 7) + x;
        uint4 o3, o5;
        float g[8];
#pragma unroll
        for (int p = 0; p < 8; p++) {
            float x1 = tc[p] * c1v;
            g[p] = x1 * __builtin_amdgcn_rcpf(1.f + __expf(-1.702f * x1));
        }
        o3.x = packbf(g[0] * a3[0], g[1] * a3[1]);
        o3.y = packbf(g[2] * a3[2], g[3] * a3[3]);
        o3.z = packbf(g[4] * a3[4], g[5] * a3[5]);
        o3.w = packbf(g[6] * a3[6], g[7] * a3[7]);
        o5.x = packbf(g[0] * a5[0], g[1] * a5[1]);
        o5.y = packbf(g[2] * a5[2], g[3] * a5[3]);
        o5.z = packbf(g[4] * a5[4], g[5] * a5[5]);
        o5.w = packbf(g[6] * a5[6], g[7] * a5[7]);
        *(uint4*)&gated[tadr(b, 512, px0 >> 6, c, px0 & 63)] = o3;
        *(uint4*)&gated[tadr(b, 512, px0 >> 6, 256 + c, px0 & 63)] = o5;
    }
}

// ---------------------------------------------------------------------------
// K3: per (b,h): S = q k^T + row norms via MFMA, softmax, attn_proj fold -> M.
// ---------------------------------------------------------------------------
__global__ __launch_bounds__(256) void attn_M(const ushort* __restrict__ qkv,
                                              const float* __restrict__ temp,
                                              const float* __restrict__ attn_proj,
                                              ushort* __restrict__ M) {
    __shared__ float Sp[4][16][16];
    __shared__ float QSS[4][16], KSS[4][16];
    __shared__ float A[16][17];

    const int bh = blockIdx.x, b = bh >> 3, h = bh & 7;
    const int tid = threadIdx.x;
    const int w = tid >> 6, lane = tid & 63;
    const int lr = lane & 15, lg = lane >> 4;

    const size_t qbase = (((size_t)b * 256 + w * 64) * 384 + h * 16 + lr) * 64 + lg * 8;
    const size_t kbase = qbase + (size_t)128 * 64;

    f32x4 acc = {0.f, 0.f, 0.f, 0.f};
    f32x4 accq = {0.f, 0.f, 0.f, 0.f};
    f32x4 acck = {0.f, 0.f, 0.f, 0.f};
#pragma unroll 2
    for (int it = 0; it < 128; it++) {
        size_t off = (size_t)(it >> 1) * (384 * 64) + (it & 1) * 32;
        bf16x8 qf = __builtin_bit_cast(bf16x8, *(const ushort8v*)(qkv + qbase + off));
        bf16x8 kf = __builtin_bit_cast(bf16x8, *(const ushort8v*)(qkv + kbase + off));
        acc = __builtin_amdgcn_mfma_f32_16x16x32_bf16(qf, kf, acc, 0, 0, 0);
        accq = __builtin_amdgcn_mfma_f32_16x16x32_bf16(qf, qf, accq, 0, 0, 0);
        acck = __builtin_amdgcn_mfma_f32_16x16x32_bf16(kf, kf, acck, 0, 0, 0);
    }
#pragma unroll
    for (int r = 0; r < 4; r++) Sp[w][lg * 4 + r][lr] = acc[r];
    if (lg == (lr >> 2)) {
        QSS[w][lr] = accq[lr & 3];
        KSS[w][lr] = acck[lr & 3];
    }
    __syncthreads();

    const int d = tid >> 4, e = tid & 15;
    float S = Sp[0][d][e] + Sp[1][d][e] + Sp[2][d][e] + Sp[3][d][e];
    float nq = fmaxf(sqrtf(QSS[0][d] + QSS[1][d] + QSS[2][d] + QSS[3][d]), 1e-12f);
    float nk = fmaxf(sqrtf(KSS[0][e] + KSS[1][e] + KSS[2][e] + KSS[3][e]), 1e-12f);
    float logit = S / (nq * nk) * temp[h];
    float m = logit;
    for (int off = 8; off; off >>= 1) m = fmaxf(m, __shfl_xor(m, off, 64));
    float ex = expf(logit - m);
    float sum = ex;
    for (int off = 8; off; off >>= 1) sum += __shfl_xor(sum, off, 64);
    A[d][e] = ex / sum;
    __syncthreads();

    for (int i = tid; i < 2048; i += 256) {
        int o = i >> 4, ee = i & 15;
        float acc2 = 0.f;
#pragma unroll
        for (int dd = 0; dd < 16; dd++) acc2 += attn_proj[o * 128 + h * 16 + dd] * A[dd][ee];
        M[((size_t)b * 128 + o) * 128 + h * 16 + ee] = f2bf(acc2);
    }
}

// ---------------------------------------------------------------------------
// K4+K5 FUSED: x2 = x + M_b @ v, then t = pin @ LN2(x2).
// pin GEMM uses o0=(mt*4+wv)*16 mapping + LDS repack epilogue (vs reused).
// ---------------------------------------------------------------------------
__global__ __launch_bounds__(256) void mv_ln_mfma(const ushort* __restrict__ qkv,
                                                  const ushort* __restrict__ Mb16,
                                                  const float* __restrict__ x,
                                                  const ushort* __restrict__ pin_b,
                                                  const float* __restrict__ gamma,
                                                  const float* __restrict__ beta,
                                                  ushort* __restrict__ x2,
                                                  ushort* __restrict__ t_out) {
    __shared__ ushort vs[64][136];  // [px][ch] V tile; reused as repack buffer
    __shared__ ushort xs[64][136];  // [px][ch] x2 tile
    __shared__ float red[2][4][64];
    __shared__ float mu[64], rs[64];
    __shared__ float gl[128], bl[128];

    const int blk = blockIdx.x;
    const int b = blk >> 8;
    const int tile = blk & 255;
    const int tid = threadIdx.x;
    const int wv = tid >> 6, lane = tid & 63;
    const int lr = lane & 15, lg = lane >> 4;

    // hoisted M fragments (latency covered by V staging)
    const ushort* Mb = Mb16 + (size_t)b * 128 * 128;
    bf16x8 mfr[2][4];
#pragma unroll
    for (int mt = 0; mt < 2; mt++)
#pragma unroll
        for (int kc = 0; kc < 4; kc++)
            mfr[mt][kc] = __builtin_bit_cast(bf16x8,
                *(const ushort8v*)&Mb[(size_t)((wv * 2 + mt) * 16 + lr) * 128 + kc * 32 + lg * 8]);

    // stage V: bulk 16B loads, then LDS transpose
    const ushort* vb = qkv + tadr(b, 384, tile, 256, 0);
    ushort8v vv[4];
#pragma unroll
    for (int k = 0; k < 4; k++) {
        int idx = tid + k * 256;
        int c = idx & 127, pg = idx >> 7;
        vv[k] = *(const ushort8v*)&vb[c * 64 + pg * 8];
    }
    if (tid < 128) {
        gl[tid] = gamma[tid];
        bl[tid] = beta[tid];
    }
#pragma unroll
    for (int k = 0; k < 4; k++) {
        int idx = tid + k * 256;
        int c = idx & 127, pg = idx >> 7;
#pragma unroll
        for (int j = 0; j < 8; j++) vs[pg * 8 + j][c] = vv[k][j];
    }
    __syncthreads();

    // MV GEMM
    bf16x8 bfr[4][4];
#pragma unroll
    for (int t = 0; t < 4; t++)
#pragma unroll
        for (int kc = 0; kc < 4; kc++)
            bfr[t][kc] = __builtin_bit_cast(bf16x8, *(const ushort8v*)&vs[t * 16 + lr][kc * 32 + lg * 8]);

#pragma unroll
    for (int mt = 0; mt < 2; mt++) {
        const int o0 = (wv * 2 + mt) * 16;
        f32x4 acc[4] = {{0.f, 0.f, 0.f, 0.f}, {0.f, 0.f, 0.f, 0.f}, {0.f, 0.f, 0.f, 0.f}, {0.f, 0.f, 0.f, 0.f}};
#pragma unroll
        for (int kc = 0; kc < 4; kc++)
#pragma unroll
            for (int t = 0; t < 4; t++)
                acc[t] = __builtin_amdgcn_mfma_f32_16x16x32_bf16(mfr[mt][kc], bfr[t][kc], acc[t], 0, 0, 0);
#pragma unroll
        for (int t = 0; t < 4; t++) {
            int px = t * 16 + lr;
            const float* xp = &x[((size_t)b * 128 + o0 + lg * 4) * NPIX + tile * 64 + px];
            uint2 pk;
            pk.x = packbf(xp[0] + acc[t][0], xp[NPIX] + acc[t][1]);
            pk.y = packbf(xp[2 * NPIX] + acc[t][2], xp[3 * NPIX] + acc[t][3]);
            *(uint2*)&xs[px][o0 + lg * 4] = pk;
        }
    }

    // prefetch pin fragments for mt=0 (o0 = wv*16; latency hidden under LN)
    bf16x8 pfp[2][4];
#pragma unroll
    for (int kc = 0; kc < 4; kc++)
        pfp[0][kc] = __builtin_bit_cast(bf16x8,
            *(const ushort8v*)&pin_b[(size_t)(wv * 16 + lr) * 128 + kc * 32 + lg * 8]);
    __syncthreads();

    // copy xs -> x2 (px-major, coalesced) ; LN stats
#pragma unroll
    for (int k = 0; k < 4; k++) {
        int idx = tid + k * 256;
        int p = idx >> 4, seg = idx & 15;
        uint4 v = *(const uint4*)&xs[p][seg * 8];
        *(uint4*)&x2[padr(b, tile, p, seg * 8)] = v;
    }
    {
        const int p = tid & 63, part = tid >> 6;
        float s = 0.f, ss = 0.f;
#pragma unroll
        for (int q = 0; q < 4; q++) {
            ushort8v u = *(const ushort8v*)&xs[p][part * 32 + q * 8];
#pragma unroll
            for (int j = 0; j < 8; j++) {
                float v = b2f(u[j]);
                s += v;
                ss += v * v;
            }
        }
        red[0][part][p] = s;
        red[1][part][p] = ss;
    }
    __syncthreads();
    if (tid < 64) {
        float s = red[0][0][tid] + red[0][1][tid] + red[0][2][tid] + red[0][3][tid];
        float ss = red[1][0][tid] + red[1][1][tid] + red[1][2][tid] + red[1][3][tid];
        float m = s * (1.f / 128.f);
        float var = ss * (1.f / 128.f) - m * m;
        mu[tid] = m;
        rs[tid] = rsqrtf(var + 1e-5f);
    }
    __syncthreads();
    {
        const int p = tid & 63, part = tid >> 6;
        const float mp = mu[p], rp = rs[p];
#pragma unroll
        for (int q = 0; q < 4; q++) {
            int c0 = part * 32 + q * 8;
            ushort8v u = *(const ushort8v*)&xs[p][c0];
            ushort8v o;
#pragma unroll
            for (int j = 0; j < 8; j++) {
                float v = b2f(u[j]);
                o[j] = f2bf((v - mp) * rp * gl[c0 + j] + bl[c0 + j]);
            }
            *(ushort8v*)&xs[p][c0] = o;
        }
    }
    __syncthreads();

    // pin GEMM (O=256): o0=(mt*4+wv)*16, LDS repack epilogue into vs
    bf16x8 bfr2[4][4];
#pragma unroll
    for (int t = 0; t < 4; t++)
#pragma unroll
        for (int kc = 0; kc < 4; kc++)
            bfr2[t][kc] = __builtin_bit_cast(bf16x8, *(const ushort8v*)&xs[t * 16 + lr][kc * 32 + lg * 8]);

    f32x4 accPair[2][4];
    const int px8 = tid & 7, cb = tid >> 3;
    ushort* toutp = t_out + tadr(b, 256, tile, 0, 0);

#pragma unroll
    for (int mt = 0; mt < 4; mt++) {
        if (mt + 1 < 4) {
            const int o0n = ((mt + 1) * 4 + wv) * 16;
#pragma unroll
            for (int kc = 0; kc < 4; kc++)
                pfp[(mt + 1) & 1][kc] = __builtin_bit_cast(bf16x8,
                    *(const ushort8v*)&pin_b[(size_t)(o0n + lr) * 128 + kc * 32 + lg * 8]);
        }
        f32x4* acc = accPair[mt & 1];
#pragma unroll
        for (int t = 0; t < 4; t++) acc[t] = (f32x4){0.f, 0.f, 0.f, 0.f};
#pragma unroll
        for (int kc = 0; kc < 4; kc++)
#pragma unroll
            for (int t = 0; t < 4; t++)
                acc[t] = __builtin_amdgcn_mfma_f32_16x16x32_bf16(pfp[mt & 1][kc], bfr2[t][kc], acc[t], 0, 0, 0);

        if (mt & 1) {
            __syncthreads();  // vs free (V-frags consumed long ago)
#pragma unroll
            for (int h = 0; h < 2; h++) {
                const int lc = h * 64 + wv * 16 + lg * 4;
#pragma unroll
                for (int t = 0; t < 4; t++) {
                    int px = t * 16 + lr;
                    uint2 pk;
                    pk.x = packbf(accPair[h][t][0], accPair[h][t][1]);
                    pk.y = packbf(accPair[h][t][2], accPair[h][t][3]);
                    *(uint2*)&vs[px][lc] = pk;
                }
            }
            __syncthreads();
            const int pairbase = (mt >> 1) * 128;
#pragma unroll
            for (int cc = 0; cc < 4; cc++) {
                int c = cb + cc * 32;
                ushort8v u;
#pragma unroll
                for (int j = 0; j < 8; j++) u[j] = vs[px8 * 8 + j][c];
                *(ushort8v*)&toutp[(size_t)(pairbase + c) * 64 + px8 * 8] = u;
            }
        }
    }
}

// ---------------------------------------------------------------------------
// K8: out = x2 + pout[128,512] @ gated via MFMA.
// T14 dbuf staging (R11). Epilogue now repacks f32 out via LDS (unioned with
// gs): float4 stores with consecutive lanes on consecutive px (256B segments).
// ---------------------------------------------------------------------------
__global__ __launch_bounds__(256) void gdfn_mfma(const ushort* __restrict__ gated,
                                                 const ushort* __restrict__ x2,
                                                 const ushort* __restrict__ pout_b,
                                                 float* __restrict__ out) {
    __shared__ float smem[64 * 129];  // 33 KB; aliases gs[2][64][72] (18.4 KB)
    ushort (*gs)[64][72] = (ushort(*)[64][72])smem;
    float (*xf)[129] = (float(*)[129])smem;

    const int blk = blockIdx.x;
    const int b = blk >> 8;
    const int tile = blk & 255;
    const int tid = threadIdx.x;
    const int wv = tid >> 6, lane = tid & 63;
    const int lr = lane & 15, lg = lane >> 4;

    const ushort* gb = gated + tadr(b, 512, tile, 0, 0);
    const int p0 = tid & 63;   // pixel
    const int kga = tid >> 6;  // ch-group 0..3 (second slot: +4)

    f32x4 acc[2][4];
#pragma unroll
    for (int mt = 0; mt < 2; mt++)
#pragma unroll
        for (int tt = 0; tt < 4; tt++) acc[mt][tt] = (f32x4){0.f, 0.f, 0.f, 0.f};

    // prologue: gather chunk 0, write buf 0
    {
        ushort ca[8], cbv[8];
#pragma unroll
        for (int j = 0; j < 8; j++) ca[j] = gb[(kga * 8 + j) * 64 + p0];
#pragma unroll
        for (int j = 0; j < 8; j++) cbv[j] = gb[((kga + 4) * 8 + j) * 64 + p0];
        ushort8v ua, ub;
#pragma unroll
        for (int j = 0; j < 8; j++) { ua[j] = ca[j]; ub[j] = cbv[j]; }
        *(ushort8v*)&gs[0][p0][kga * 8] = ua;
        *(ushort8v*)&gs[0][p0][(kga + 4) * 8] = ub;
    }
    __syncthreads();

#pragma unroll
    for (int kb = 0; kb < 8; kb++) {
        const int cur = kb & 1;

        // T14 issue-early: gather chunk kb+1 into registers
        ushort na[8], nb[8];
        if (kb < 7) {
            const ushort* nbp = gb + (kb + 1) * 4096;
#pragma unroll
            for (int j = 0; j < 8; j++) na[j] = nbp[(kga * 8 + j) * 64 + p0];
#pragma unroll
            for (int j = 0; j < 8; j++) nb[j] = nbp[((kga + 4) * 8 + j) * 64 + p0];
        }

        bf16x8 bfrg[4][2];
#pragma unroll
        for (int tt = 0; tt < 4; tt++)
#pragma unroll
            for (int kc = 0; kc < 2; kc++)
                bfrg[tt][kc] = __builtin_bit_cast(bf16x8, *(const ushort8v*)&gs[cur][tt * 16 + lr][kc * 32 + lg * 8]);

#pragma unroll
        for (int mt = 0; mt < 2; mt++) {
            const int o0 = (wv * 2 + mt) * 16;
            bf16x8 afr[2];
#pragma unroll
            for (int kc = 0; kc < 2; kc++)
                afr[kc] = __builtin_bit_cast(bf16x8,
                    *(const ushort8v*)&pout_b[(size_t)(o0 + lr) * 512 + kb * 64 + kc * 32 + lg * 8]);
#pragma unroll
            for (int kc = 0; kc < 2; kc++)
#pragma unroll
                for (int tt = 0; tt < 4; tt++)
                    acc[mt][tt] = __builtin_amdgcn_mfma_f32_16x16x32_bf16(afr[kc], bfrg[tt][kc], acc[mt][tt], 0, 0, 0);
        }

        if (kb < 7) {
            ushort8v ua, ub;
#pragma unroll
            for (int j = 0; j < 8; j++) { ua[j] = na[j]; ub[j] = nb[j]; }
            *(ushort8v*)&gs[cur ^ 1][p0][kga * 8] = ua;
            *(ushort8v*)&gs[cur ^ 1][p0][(kga + 4) * 8] = ub;
        }
        __syncthreads();
    }

    // epilogue: add x2, repack via LDS f32 [px][129], 16B stores (256B segments)
#pragma unroll
    for (int mt = 0; mt < 2; mt++)
#pragma unroll
        for (int tt = 0; tt < 4; tt++) {
            int o0 = (wv * 2 + mt) * 16 + lg * 4;
            int px = tt * 16 + lr;
            uint2 xw = *(const uint2*)&x2[padr(b, tile, px, o0)];
            xf[px][o0 + 0] = u2f_lo(xw.x) + acc[mt][tt][0];
            xf[px][o0 + 1] = u2f_hi(xw.x) + acc[mt][tt][1];
            xf[px][o0 + 2] = u2f_lo(xw.y) + acc[mt][tt][2];
            xf[px][o0 + 3] = u2f_hi(xw.y) + acc[mt][tt][3];
        }
    __syncthreads();
    {
        const int qx = tid & 15;       // px quad
        const int cbase = tid >> 4;    // 0..15
#pragma unroll
        for (int cc = 0; cc < 8; cc++) {
            int c = cbase + cc * 16;
            float4 v;
            v.x = xf[qx * 4 + 0][c];
            v.y = xf[qx * 4 + 1][c];
            v.z = xf[qx * 4 + 2][c];
            v.w = xf[qx * 4 + 3][c];
            *(float4*)&out[((size_t)b * 128 + c) * NPIX + tile * 64 + qx * 4] = v;
        }
    }
}

// ---------------------------------------------------------------------------
extern "C" void kernel_launch(void* const* d_in, const int* in_sizes, int n_in,
                              void* d_out, int out_size, void* d_ws, size_t ws_size,
                              hipStream_t stream) {
    const float* x = (const float*)d_in[0];
    const float* ln1_w = (const float*)d_in[1];
    const float* ln1_b = (const float*)d_in[2];
    const float* qkv_w = (const float*)d_in[3];
    const float* qkv_dw = (const float*)d_in[4];
    const float* temperature = (const float*)d_in[5];
    const float* attn_proj = (const float*)d_in[6];
    const float* ln2_w = (const float*)d_in[7];
    const float* ln2_b = (const float*)d_in[8];
    const float* pin_w = (const float*)d_in[9];
    const float* c1_w = (const float*)d_in[10];
    const float* c3_w = (const float*)d_in[11];
    const float* c5_w = (const float*)d_in[12];
    const float* pout_w = (const float*)d_in[13];
    float* out = (float*)d_out;

    char* ws = (char*)d_ws;
    ushort* qkv_pre = (ushort*)(ws + 0);            // 100,663,296 (dead after dwconv3)
    ushort* qkv     = (ushort*)(ws + 100663296);    // 100,663,296 (dead after mv_ln)
    ushort* x2      = (ushort*)(ws + 201326592);    //  33,554,432 px-major (lives to end)
    ushort* t       = (ushort*)(ws + 0);            //  67,108,864 (reuses qkv_pre)
    ushort* gated   = (ushort*)(ws + 67108864);     // 134,217,728 (reuses qkv region)
    ushort* Mb16    = (ushort*)(ws + 235151360);    //    262,144
    ushort* qkv_wb  = (ushort*)(ws + 235413504);    //     98,304
    ushort* pin_wb  = (ushort*)(ws + 235511808);    //     65,536
    ushort* pout_wb = (ushort*)(ws + 235577344);    //    131,072  (end ~235.7 MB)

    // K0: weight conversion (f32 -> bf16)
    wcvt<<<576, 256, 0, stream>>>(qkv_w, qkv_wb, 49152, pin_w, pin_wb, 32768, pout_w, pout_wb, 65536);
    // K1: qkv_pre = qkv_w @ LN1(x)
    ln_gemm_mfma<384><<<2048, 256, 0, stream>>>(x, qkv_wb, ln1_w, ln1_b, qkv_pre);
    // K2: qkv = dwconv3x3(qkv_pre)
    dwconv3_lds<<<dim3(384, 8), 256, 0, stream>>>(qkv_pre, qkv_dw, qkv, 384);
    // K3: attention (norms + QK^T + softmax + attn_proj fold)
    attn_M<<<64, 256, 0, stream>>>(qkv, temperature, attn_proj, Mb16);
    // K4+K5 fused: x2 = x + M_b @ v ; t = pin @ LN2(x2)
    mv_ln_mfma<<<2048, 256, 0, stream>>>(qkv, Mb16, x, pin_wb, ln2_w, ln2_b, x2, t);
    // K6/K7 fused + gating
    dw_gated<<<dim3(256, 8), 256, 0, stream>>>(t, c3_w, c5_w, c1_w, gated);
    // K8: out = x2 + pout @ gated
    gdfn_mfma<<<2048, 256, 0, stream>>>(gated, x2, pout_wb, out);
}

// Round 13
// 301.691 us; speedup vs baseline: 6.2837x; 1.0039x over previous
//
#include <hip/hip_runtime.h>
#include <type_traits>

typedef unsigned short ushort;
typedef unsigned int uint;
typedef __bf16 bf16x8 __attribute__((ext_vector_type(8)));
typedef unsigned short ushort8v __attribute__((ext_vector_type(8)));
typedef float f32x4 __attribute__((ext_vector_type(4)));

__device__ __forceinline__ float b2f(ushort u) {
    unsigned int x = ((unsigned int)u) << 16;
    float f;
    __builtin_memcpy(&f, &x, 4);
    return f;
}
__device__ __forceinline__ ushort f2bf(float f) {
    unsigned int x;
    __builtin_memcpy(&x, &f, 4);
    unsigned int r = x + 0x7fffu + ((x >> 16) & 1u);
    return (ushort)(r >> 16);
}
__device__ __forceinline__ float u2f_lo(uint u) {
    uint x = u << 16;
    float f;
    __builtin_memcpy(&f, &x, 4);
    return f;
}
__device__ __forceinline__ float u2f_hi(uint u) {
    uint x = u & 0xffff0000u;
    float f;
    __builtin_memcpy(&f, &x, 4);
    return f;
}
__device__ __forceinline__ uint packbf(float a, float b) {
    return (uint)f2bf(a) | ((uint)f2bf(b) << 16);
}

#define NPIX 16384  // H*W = 128*128
#define PSTRIDE 136 // padded plane row stride (ushorts); 68 uints

// Channel-major tiled layout: [b][tile(256)][ch(CH)][64 px]
__device__ __forceinline__ size_t tadr(int b, int CH, int tile, int ch, int off) {
    return (((size_t)b * 256 + tile) * CH + ch) * 64 + off;
}
// Pixel-major tiled layout for x2: [b][tile(256)][px(64)][ch(128)]
__device__ __forceinline__ size_t padr(int b, int tile, int p, int c) {
    return (((size_t)b * 256 + tile) * 64 + p) * 128 + c;
}

// ---------------------------------------------------------------------------
// stage one 128x128 plane (channel c of ch-major tiled tensor) into padded LDS.
// ---------------------------------------------------------------------------
__device__ __forceinline__ void stage_plane(ushort* pl, const ushort* __restrict__ src,
                                            int b, int c, int CH, int tid) {
    uint* plu = (uint*)pl;
    for (int i = tid; i < 784; i += 256) {
        int idx;
        if (i < 136) idx = i;                       // rows 0-1
        else if (i < 272) idx = 8840 + (i - 136);   // rows 130-131
        else {
            int j = i - 272;
            int r = (j >> 2) + 2;                   // rows 2..129
            int cs = j & 3;
            idx = r * 68 + (cs == 0 ? 0 : 64 + cs); // uint 0 (left pad), 65-67 (right pad)
        }
        plu[idx] = 0u;
    }
    for (int i = tid; i < 2048; i += 256) {
        int row = i >> 4, xg = (i & 15) << 3;
        int px0 = row * 128 + xg;
        uint4 v = *(const uint4*)&src[tadr(b, CH, px0 >> 6, c, px0 & 63)];
        uint* dst = (uint*)&pl[(row + 2) * PSTRIDE + xg + 2];
        dst[0] = v.x; dst[1] = v.y; dst[2] = v.z; dst[3] = v.w;
    }
    __syncthreads();
}

// unpack 12 consecutive bf16 at rowp (16B-aligned) into f32
__device__ __forceinline__ void unpack12(const ushort* rowp, float* cc) {
    const uint* rp = (const uint*)rowp;
    uint4 u = *(const uint4*)rp;
    uint2 v = *(const uint2*)(rp + 4);
    cc[0] = u2f_lo(u.x); cc[1] = u2f_hi(u.x);
    cc[2] = u2f_lo(u.y); cc[3] = u2f_hi(u.y);
    cc[4] = u2f_lo(u.z); cc[5] = u2f_hi(u.z);
    cc[6] = u2f_lo(u.w); cc[7] = u2f_hi(u.w);
    cc[8] = u2f_lo(v.x); cc[9] = u2f_hi(v.x);
    cc[10] = u2f_lo(v.y); cc[11] = u2f_hi(v.y);
}

// ---------------------------------------------------------------------------
// K0: convert fp32 weights to bf16 once (qkv_w, pin_w, pout_w).
// ---------------------------------------------------------------------------
__global__ __launch_bounds__(256) void wcvt(const float* __restrict__ s0, ushort* __restrict__ d0, int n0,
                                            const float* __restrict__ s1, ushort* __restrict__ d1, int n1,
                                            const float* __restrict__ s2, ushort* __restrict__ d2, int n2) {
    int i = blockIdx.x * 256 + threadIdx.x;
    if (i < n0) d0[i] = f2bf(s0[i]);
    else if (i < n0 + n1) d1[i - n0] = f2bf(s1[i - n0]);
    else if (i < n0 + n1 + n2) d2[i - n0 - n1] = f2bf(s2[i - n0 - n1]);
}

// ---------------------------------------------------------------------------
// K1: fused LayerNorm(C=128) + qkv 1x1 conv via MFMA (R12 structure).
// ---------------------------------------------------------------------------
template <int O>
__global__ __launch_bounds__(256) void ln_gemm_mfma(const float* __restrict__ xin,
                                                    const ushort* __restrict__ Wb,
                                                    const float* __restrict__ gamma,
                                                    const float* __restrict__ beta,
                                                    ushort* __restrict__ out) {
    __shared__ ushort xs[64][136];
    __shared__ float red[2][4][64];
    __shared__ float mu[64], rs[64];
    __shared__ float gl[128], bl[128];

    const int blk = blockIdx.x;
    const int b = blk >> 8;
    const int tile = blk & 255;
    const int tid = threadIdx.x;

    const float* xb = xin + (size_t)b * 128 * NPIX + tile * 64;
    float vx[4][8];
#pragma unroll
    for (int k = 0; k < 4; k++) {
        int i = tid + k * 256;
        int p = i & 63, cg = i >> 6;
        const float* src = xb + (size_t)(cg * 8) * NPIX + p;
#pragma unroll
        for (int j = 0; j < 8; j++) vx[k][j] = src[(size_t)j * NPIX];
    }
    if (tid < 128) {
        gl[tid] = gamma[tid];
        bl[tid] = beta[tid];
    }
#pragma unroll
    for (int k = 0; k < 4; k++) {
        int i = tid + k * 256;
        int p = i & 63, cg = i >> 6;
        ushort8v u;
#pragma unroll
        for (int j = 0; j < 8; j++) u[j] = f2bf(vx[k][j]);
        *(ushort8v*)&xs[p][cg * 8] = u;
    }
    __syncthreads();

    {
        const int p = tid & 63, part = tid >> 6;
        float s = 0.f, ss = 0.f;
#pragma unroll
        for (int q = 0; q < 4; q++) {
            ushort8v u = *(const ushort8v*)&xs[p][part * 32 + q * 8];
#pragma unroll
            for (int j = 0; j < 8; j++) {
                float v = b2f(u[j]);
                s += v;
                ss += v * v;
            }
        }
        red[0][part][p] = s;
        red[1][part][p] = ss;
    }
    __syncthreads();
    if (tid < 64) {
        float s = red[0][0][tid] + red[0][1][tid] + red[0][2][tid] + red[0][3][tid];
        float ss = red[1][0][tid] + red[1][1][tid] + red[1][2][tid] + red[1][3][tid];
        float m = s * (1.f / 128.f);
        float var = ss * (1.f / 128.f) - m * m;
        mu[tid] = m;
        rs[tid] = rsqrtf(var + 1e-5f);
    }
    __syncthreads();
    {
        const int p = tid & 63, part = tid >> 6;
        const float mp = mu[p], rp = rs[p];
#pragma unroll
        for (int q = 0; q < 4; q++) {
            int c0 = part * 32 + q * 8;
            ushort8v u = *(const ushort8v*)&xs[p][c0];
            ushort8v o;
#pragma unroll
            for (int j = 0; j < 8; j++) {
                float v = b2f(u[j]);
                o[j] = f2bf((v - mp) * rp * gl[c0 + j] + bl[c0 + j]);
            }
            *(ushort8v*)&xs[p][c0] = o;
        }
    }
    __syncthreads();

    const int wv = tid >> 6, lane = tid & 63;
    const int lr = lane & 15, lg = lane >> 4;

    bf16x8 bfr[4][4];
#pragma unroll
    for (int t = 0; t < 4; t++)
#pragma unroll
        for (int kc = 0; kc < 4; kc++)
            bfr[t][kc] = __builtin_bit_cast(bf16x8, *(const ushort8v*)&xs[t * 16 + lr][kc * 32 + lg * 8]);

    constexpr int MT = O / 64;
    bf16x8 afp[2][4];
#pragma unroll
    for (int kc = 0; kc < 4; kc++)
        afp[0][kc] = __builtin_bit_cast(bf16x8,
            *(const ushort8v*)&Wb[(size_t)(wv * 16 + lr) * 128 + kc * 32 + lg * 8]);

    f32x4 accPair[2][4];
    const int px8 = tid & 7, cb = tid >> 3;
    ushort* outp = out + tadr(b, O, tile, 0, 0);

#pragma unroll
    for (int mt = 0; mt < MT; mt++) {
        if (mt + 1 < MT) {
            const int o0n = ((mt + 1) * 4 + wv) * 16;
#pragma unroll
            for (int kc = 0; kc < 4; kc++)
                afp[(mt + 1) & 1][kc] = __builtin_bit_cast(bf16x8,
                    *(const ushort8v*)&Wb[(size_t)(o0n + lr) * 128 + kc * 32 + lg * 8]);
        }
        f32x4* acc = accPair[mt & 1];
#pragma unroll
        for (int t = 0; t < 4; t++) acc[t] = (f32x4){0.f, 0.f, 0.f, 0.f};
#pragma unroll
        for (int kc = 0; kc < 4; kc++)
#pragma unroll
            for (int t = 0; t < 4; t++)
                acc[t] = __builtin_amdgcn_mfma_f32_16x16x32_bf16(afp[mt & 1][kc], bfr[t][kc], acc[t], 0, 0, 0);

        if (mt & 1) {
            __syncthreads();
#pragma unroll
            for (int h = 0; h < 2; h++) {
                const int lc = h * 64 + wv * 16 + lg * 4;
#pragma unroll
                for (int t = 0; t < 4; t++) {
                    int px = t * 16 + lr;
                    uint2 pk;
                    pk.x = packbf(accPair[h][t][0], accPair[h][t][1]);
                    pk.y = packbf(accPair[h][t][2], accPair[h][t][3]);
                    *(uint2*)&xs[px][lc] = pk;
                }
            }
            __syncthreads();
            const int pairbase = (mt >> 1) * 128;
#pragma unroll
            for (int cc = 0; cc < 4; cc++) {
                int c = cb + cc * 32;
                ushort8v u;
#pragma unroll
                for (int j = 0; j < 8; j++) u[j] = xs[px8 * 8 + j][c];
                *(ushort8v*)&outp[(size_t)(pairbase + c) * 64 + px8 * 8] = u;
            }
        }
    }
}

// ---------------------------------------------------------------------------
// K2: 3x3 depthwise conv, one (b,c) plane per block; ch-major tiled in/out.
// ---------------------------------------------------------------------------
__global__ __launch_bounds__(256) void dwconv3_lds(const ushort* __restrict__ in,
                                                   const float* __restrict__ wdw,
                                                   ushort* __restrict__ out, int CH) {
    __shared__ ushort pl[132 * PSTRIDE];
    const int c = blockIdx.x;
    const int b = blockIdx.y;
    const int tid = threadIdx.x;

    float w[9];
#pragma unroll
    for (int j = 0; j < 9; j++) w[j] = wdw[c * 9 + j];

    stage_plane(pl, in, b, c, CH, tid);

    const int x = (tid & 15) * 8;
    const int ybase = tid >> 4;
#pragma unroll 1
    for (int k = 0; k < 8; k++) {
        const int y = k * 16 + ybase;
        float a[8];
#pragma unroll
        for (int p = 0; p < 8; p++) a[p] = 0.f;
#pragma unroll
        for (int ky = 0; ky < 3; ky++) {
            float cc[12];
            unpack12(&pl[(y + ky + 1) * PSTRIDE + x], cc);
#pragma unroll
            for (int kx = 0; kx < 3; kx++) {
                float wv = w[ky * 3 + kx];
#pragma unroll
                for (int p = 0; p < 8; p++) a[p] += cc[p + kx + 1] * wv;
            }
        }
        const int px0 = (y << 7) + x;
        uint4 o;
        o.x = packbf(a[0], a[1]);
        o.y = packbf(a[2], a[3]);
        o.z = packbf(a[4], a[5]);
        o.w = packbf(a[6], a[7]);
        *(uint4*)&out[tadr(b, CH, px0 >> 6, c, px0 & 63)] = o;
    }
}

// ---------------------------------------------------------------------------
// K6/K7/gating fused: ch-major tiled in/out (unchanged).
// ---------------------------------------------------------------------------
__global__ __launch_bounds__(256) void dw_gated(const ushort* __restrict__ t,
                                                const float* __restrict__ w3_,
                                                const float* __restrict__ w5_,
                                                const float* __restrict__ c1w,
                                                ushort* __restrict__ gated) {
    __shared__ ushort pl[132 * PSTRIDE];
    const int c = blockIdx.x;
    const int b = blockIdx.y;
    const int tid = threadIdx.x;

    float w3[9], w5[25];
#pragma unroll
    for (int j = 0; j < 9; j++) w3[j] = w3_[c * 9 + j];
#pragma unroll
    for (int j = 0; j < 25; j++) w5[j] = w5_[c * 25 + j];
    const float c1v = c1w[c];

    stage_plane(pl, t, b, c, 256, tid);

    const int x = (tid & 15) * 8;
    const int ybase = tid >> 4;
#pragma unroll 1
    for (int k = 0; k < 8; k++) {
        const int y = k * 16 + ybase;
        float a5[8], a3[8], tc[8];
#pragma unroll
        for (int p = 0; p < 8; p++) { a5[p] = 0.f; a3[p] = 0.f; }
#pragma unroll
        for (int ky = 0; ky < 5; ky++) {
            float cc[12];
            unpack12(&pl[(y + ky) * PSTRIDE + x], cc);
#pragma unroll
            for (int kx = 0; kx < 5; kx++) {
                float wv = w5[ky * 5 + kx];
#pragma unroll
                for (int p = 0; p < 8; p++) a5[p] += cc[p + kx] * wv;
            }
            if (ky >= 1 && ky <= 3) {
#pragma unroll
                for (int kx = 0; kx < 3; kx++) {
                    float wv = w3[(ky - 1) * 3 + kx];
#pragma unroll
                    for (int p = 0; p < 8; p++) a3[p] += cc[p + kx + 1] * wv;
                }
            }
            if (ky == 2) {
#pragma unroll
                for (int p = 0; p < 8; p++) tc[p] = cc[p + 2];
            }
        }
        const int px0 = (y << 7) + x;
        uint4 o3, o5;
        float g[8];
#pragma unroll
        for (int p = 0; p < 8; p++) {
            float x1 = tc[p] * c1v;
            g[p] = x1 * __builtin_amdgcn_rcpf(1.f + __expf(-1.702f * x1));
        }
        o3.x = packbf(g[0] * a3[0], g[1] * a3[1]);
        o3.y = packbf(g[2] * a3[2], g[3] * a3[3]);
        o3.z = packbf(g[4] * a3[4], g[5] * a3[5]);
        o3.w = packbf(g[6] * a3[6], g[7] * a3[7]);
        o5.x = packbf(g[0] * a5[0], g[1] * a5[1]);
        o5.y = packbf(g[2] * a5[2], g[3] * a5[3]);
        o5.z = packbf(g[4] * a5[4], g[5] * a5[5]);
        o5.w = packbf(g[6] * a5[6], g[7] * a5[7]);
        *(uint4*)&gated[tadr(b, 512, px0 >> 6, c, px0 & 63)] = o3;
        *(uint4*)&gated[tadr(b, 512, px0 >> 6, 256 + c, px0 & 63)] = o5;
    }
}

// ---------------------------------------------------------------------------
// K3: per (b,h) attention -> M. Now 512 threads / 8 wave-segments (2048 px
// per wave) to double per-CU wave residency and halve the MFMA chain.
// ---------------------------------------------------------------------------
__global__ __launch_bounds__(512) void attn_M(const ushort* __restrict__ qkv,
                                              const float* __restrict__ temp,
                                              const float* __restrict__ attn_proj,
                                              ushort* __restrict__ M) {
    __shared__ float Sp[8][16][16];
    __shared__ float QSS[8][16], KSS[8][16];
    __shared__ float A[16][17];

    const int bh = blockIdx.x, b = bh >> 3, h = bh & 7;
    const int tid = threadIdx.x;
    const int w = tid >> 6, lane = tid & 63;
    const int lr = lane & 15, lg = lane >> 4;

    const size_t qbase = (((size_t)b * 256 + w * 32) * 384 + h * 16 + lr) * 64 + lg * 8;
    const size_t kbase = qbase + (size_t)128 * 64;

    f32x4 acc = {0.f, 0.f, 0.f, 0.f};
    f32x4 accq = {0.f, 0.f, 0.f, 0.f};
    f32x4 acck = {0.f, 0.f, 0.f, 0.f};
#pragma unroll 2
    for (int it = 0; it < 64; it++) {
        size_t off = (size_t)(it >> 1) * (384 * 64) + (it & 1) * 32;
        bf16x8 qf = __builtin_bit_cast(bf16x8, *(const ushort8v*)(qkv + qbase + off));
        bf16x8 kf = __builtin_bit_cast(bf16x8, *(const ushort8v*)(qkv + kbase + off));
        acc = __builtin_amdgcn_mfma_f32_16x16x32_bf16(qf, kf, acc, 0, 0, 0);
        accq = __builtin_amdgcn_mfma_f32_16x16x32_bf16(qf, qf, accq, 0, 0, 0);
        acck = __builtin_amdgcn_mfma_f32_16x16x32_bf16(kf, kf, acck, 0, 0, 0);
    }
#pragma unroll
    for (int r = 0; r < 4; r++) Sp[w][lg * 4 + r][lr] = acc[r];
    if (lg == (lr >> 2)) {
        QSS[w][lr] = accq[lr & 3];
        KSS[w][lr] = acck[lr & 3];
    }
    __syncthreads();

    if (tid < 256) {
        const int d = tid >> 4, e = tid & 15;
        float S = 0.f, q2 = 0.f, k2 = 0.f;
#pragma unroll
        for (int s = 0; s < 8; s++) {
            S += Sp[s][d][e];
            q2 += QSS[s][d];
            k2 += KSS[s][e];
        }
        float nq = fmaxf(sqrtf(q2), 1e-12f);
        float nk = fmaxf(sqrtf(k2), 1e-12f);
        float logit = S / (nq * nk) * temp[h];
        float m = logit;
        for (int off = 8; off; off >>= 1) m = fmaxf(m, __shfl_xor(m, off, 64));
        float ex = expf(logit - m);
        float sum = ex;
        for (int off = 8; off; off >>= 1) sum += __shfl_xor(sum, off, 64);
        A[d][e] = ex / sum;
    }
    __syncthreads();

    for (int i = tid; i < 2048; i += 512) {
        int o = i >> 4, ee = i & 15;
        float acc2 = 0.f;
#pragma unroll
        for (int dd = 0; dd < 16; dd++) acc2 += attn_proj[o * 128 + h * 16 + dd] * A[dd][ee];
        M[((size_t)b * 128 + o) * 128 + h * 16 + ee] = f2bf(acc2);
    }
}

// ---------------------------------------------------------------------------
// K4+K5 FUSED: x2 = x + M_b @ v, then t = pin @ LN2(x2).
// SINGLE LDS tile ts[] (V tile reused as x2 tile after B-frags are in regs,
// then as repack buffer): LDS 39 -> 21 KB => ~7 blocks/CU.
// ---------------------------------------------------------------------------
__global__ __launch_bounds__(256) void mv_ln_mfma(const ushort* __restrict__ qkv,
                                                  const ushort* __restrict__ Mb16,
                                                  const float* __restrict__ x,
                                                  const ushort* __restrict__ pin_b,
                                                  const float* __restrict__ gamma,
                                                  const float* __restrict__ beta,
                                                  ushort* __restrict__ x2,
                                                  ushort* __restrict__ t_out) {
    __shared__ ushort ts[64][136];  // V tile -> x2 tile -> repack buffer
    __shared__ float red[2][4][64];
    __shared__ float mu[64], rs[64];
    __shared__ float gl[128], bl[128];

    const int blk = blockIdx.x;
    const int b = blk >> 8;
    const int tile = blk & 255;
    const int tid = threadIdx.x;
    const int wv = tid >> 6, lane = tid & 63;
    const int lr = lane & 15, lg = lane >> 4;

    // hoisted M fragments (latency covered by V staging)
    const ushort* Mb = Mb16 + (size_t)b * 128 * 128;
    bf16x8 mfr[2][4];
#pragma unroll
    for (int mt = 0; mt < 2; mt++)
#pragma unroll
        for (int kc = 0; kc < 4; kc++)
            mfr[mt][kc] = __builtin_bit_cast(bf16x8,
                *(const ushort8v*)&Mb[(size_t)((wv * 2 + mt) * 16 + lr) * 128 + kc * 32 + lg * 8]);

    // stage V: bulk 16B loads, then LDS transpose into ts
    const ushort* vb = qkv + tadr(b, 384, tile, 256, 0);
    ushort8v vv[4];
#pragma unroll
    for (int k = 0; k < 4; k++) {
        int idx = tid + k * 256;
        int c = idx & 127, pg = idx >> 7;
        vv[k] = *(const ushort8v*)&vb[c * 64 + pg * 8];
    }
    if (tid < 128) {
        gl[tid] = gamma[tid];
        bl[tid] = beta[tid];
    }
#pragma unroll
    for (int k = 0; k < 4; k++) {
        int idx = tid + k * 256;
        int c = idx & 127, pg = idx >> 7;
#pragma unroll
        for (int j = 0; j < 8; j++) ts[pg * 8 + j][c] = vv[k][j];
    }
    __syncthreads();

    // read all V B-frags into registers, then barrier (ts becomes reusable)
    bf16x8 bfr[4][4];
#pragma unroll
    for (int t = 0; t < 4; t++)
#pragma unroll
        for (int kc = 0; kc < 4; kc++)
            bfr[t][kc] = __builtin_bit_cast(bf16x8, *(const ushort8v*)&ts[t * 16 + lr][kc * 32 + lg * 8]);
    __syncthreads();

    // MV GEMM; write x2-tile into ts[px][ch]
#pragma unroll
    for (int mt = 0; mt < 2; mt++) {
        const int o0 = (wv * 2 + mt) * 16;
        f32x4 acc[4] = {{0.f, 0.f, 0.f, 0.f}, {0.f, 0.f, 0.f, 0.f}, {0.f, 0.f, 0.f, 0.f}, {0.f, 0.f, 0.f, 0.f}};
#pragma unroll
        for (int kc = 0; kc < 4; kc++)
#pragma unroll
            for (int t = 0; t < 4; t++)
                acc[t] = __builtin_amdgcn_mfma_f32_16x16x32_bf16(mfr[mt][kc], bfr[t][kc], acc[t], 0, 0, 0);
#pragma unroll
        for (int t = 0; t < 4; t++) {
            int px = t * 16 + lr;
            const float* xp = &x[((size_t)b * 128 + o0 + lg * 4) * NPIX + tile * 64 + px];
            uint2 pk;
            pk.x = packbf(xp[0] + acc[t][0], xp[NPIX] + acc[t][1]);
            pk.y = packbf(xp[2 * NPIX] + acc[t][2], xp[3 * NPIX] + acc[t][3]);
            *(uint2*)&ts[px][o0 + lg * 4] = pk;
        }
    }

    // prefetch pin fragments for mt=0 (latency hidden under LN phase)
    bf16x8 pfp[2][4];
#pragma unroll
    for (int kc = 0; kc < 4; kc++)
        pfp[0][kc] = __builtin_bit_cast(bf16x8,
            *(const ushort8v*)&pin_b[(size_t)(wv * 16 + lr) * 128 + kc * 32 + lg * 8]);
    __syncthreads();

    // copy ts -> x2 (px-major, coalesced) ; LN stats
#pragma unroll
    for (int k = 0; k < 4; k++) {
        int idx = tid + k * 256;
        int p = idx >> 4, seg = idx & 15;
        uint4 v = *(const uint4*)&ts[p][seg * 8];
        *(uint4*)&x2[padr(b, tile, p, seg * 8)] = v;
    }
    {
        const int p = tid & 63, part = tid >> 6;
        float s = 0.f, ss = 0.f;
#pragma unroll
        for (int q = 0; q < 4; q++) {
            ushort8v u = *(const ushort8v*)&ts[p][part * 32 + q * 8];
#pragma unroll
            for (int j = 0; j < 8; j++) {
                float v = b2f(u[j]);
                s += v;
                ss += v * v;
            }
        }
        red[0][part][p] = s;
        red[1][part][p] = ss;
    }
    __syncthreads();
    if (tid < 64) {
        float s = red[0][0][tid] + red[0][1][tid] + red[0][2][tid] + red[0][3][tid];
        float ss = red[1][0][tid] + red[1][1][tid] + red[1][2][tid] + red[1][3][tid];
        float m = s * (1.f / 128.f);
        float var = ss * (1.f / 128.f) - m * m;
        mu[tid] = m;
        rs[tid] = rsqrtf(var + 1e-5f);
    }
    __syncthreads();
    {
        const int p = tid & 63, part = tid >> 6;
        const float mp = mu[p], rp = rs[p];
#pragma unroll
        for (int q = 0; q < 4; q++) {
            int c0 = part * 32 + q * 8;
            ushort8v u = *(const ushort8v*)&ts[p][c0];
            ushort8v o;
#pragma unroll
            for (int j = 0; j < 8; j++) {
                float v = b2f(u[j]);
                o[j] = f2bf((v - mp) * rp * gl[c0 + j] + bl[c0 + j]);
            }
            *(ushort8v*)&ts[p][c0] = o;
        }
    }
    __syncthreads();

    // pin GEMM (O=256): o0=(mt*4+wv)*16, LDS repack epilogue reusing ts
    bf16x8 bfr2[4][4];
#pragma unroll
    for (int t = 0; t < 4; t++)
#pragma unroll
        for (int kc = 0; kc < 4; kc++)
            bfr2[t][kc] = __builtin_bit_cast(bf16x8, *(const ushort8v*)&ts[t * 16 + lr][kc * 32 + lg * 8]);

    f32x4 accPair[2][4];
    const int px8 = tid & 7, cb = tid >> 3;
    ushort* toutp = t_out + tadr(b, 256, tile, 0, 0);

#pragma unroll
    for (int mt = 0; mt < 4; mt++) {
        if (mt + 1 < 4) {
            const int o0n = ((mt + 1) * 4 + wv) * 16;
#pragma unroll
            for (int kc = 0; kc < 4; kc++)
                pfp[(mt + 1) & 1][kc] = __builtin_bit_cast(bf16x8,
                    *(const ushort8v*)&pin_b[(size_t)(o0n + lr) * 128 + kc * 32 + lg * 8]);
        }
        f32x4* acc = accPair[mt & 1];
#pragma unroll
        for (int t = 0; t < 4; t++) acc[t] = (f32x4){0.f, 0.f, 0.f, 0.f};
#pragma unroll
        for (int kc = 0; kc < 4; kc++)
#pragma unroll
            for (int t = 0; t < 4; t++)
                acc[t] = __builtin_amdgcn_mfma_f32_16x16x32_bf16(pfp[mt & 1][kc], bfr2[t][kc], acc[t], 0, 0, 0);

        if (mt & 1) {
            __syncthreads();  // bfr2 reads done; ts reusable as repack buffer
#pragma unroll
            for (int h = 0; h < 2; h++) {
                const int lc = h * 64 + wv * 16 + lg * 4;
#pragma unroll
                for (int t = 0; t < 4; t++) {
                    int px = t * 16 + lr;
                    uint2 pk;
                    pk.x = packbf(accPair[h][t][0], accPair[h][t][1]);
                    pk.y = packbf(accPair[h][t][2], accPair[h][t][3]);
                    *(uint2*)&ts[px][lc] = pk;
                }
            }
            __syncthreads();
            const int pairbase = (mt >> 1) * 128;
#pragma unroll
            for (int cc = 0; cc < 4; cc++) {
                int c = cb + cc * 32;
                ushort8v u;
#pragma unroll
                for (int j = 0; j < 8; j++) u[j] = ts[px8 * 8 + j][c];
                *(ushort8v*)&toutp[(size_t)(pairbase + c) * 64 + px8 * 8] = u;
            }
        }
    }
}

// ---------------------------------------------------------------------------
// K8: out = x2 + pout[128,512] @ gated via MFMA.
// T14 dbuf staging. f32 repack epilogue now in TWO 32-px halves so the
// repack buffer xf[32][129] (16.5KB) fits inside gs (18.4KB): LDS 33->18.4KB
// => ~8 blocks/CU resident (occupancy is the latency fix).
// ---------------------------------------------------------------------------
__global__ __launch_bounds__(256) void gdfn_mfma(const ushort* __restrict__ gated,
                                                 const ushort* __restrict__ x2,
                                                 const ushort* __restrict__ pout_b,
                                                 float* __restrict__ out) {
    __shared__ ushort gs[2][64][72];           // 18432 B
    float (*xf)[129] = (float(*)[129])gs;      // alias: 32*129*4 = 16512 B

    const int blk = blockIdx.x;
    const int b = blk >> 8;
    const int tile = blk & 255;
    const int tid = threadIdx.x;
    const int wv = tid >> 6, lane = tid & 63;
    const int lr = lane & 15, lg = lane >> 4;

    const ushort* gb = gated + tadr(b, 512, tile, 0, 0);
    const int p0 = tid & 63;   // pixel
    const int kga = tid >> 6;  // ch-group 0..3 (second slot: +4)

    f32x4 acc[2][4];
#pragma unroll
    for (int mt = 0; mt < 2; mt++)
#pragma unroll
        for (int tt = 0; tt < 4; tt++) acc[mt][tt] = (f32x4){0.f, 0.f, 0.f, 0.f};

    // prologue: gather chunk 0, write buf 0
    {
        ushort ca[8], cbv[8];
#pragma unroll
        for (int j = 0; j < 8; j++) ca[j] = gb[(kga * 8 + j) * 64 + p0];
#pragma unroll
        for (int j = 0; j < 8; j++) cbv[j] = gb[((kga + 4) * 8 + j) * 64 + p0];
        ushort8v ua, ub;
#pragma unroll
        for (int j = 0; j < 8; j++) { ua[j] = ca[j]; ub[j] = cbv[j]; }
        *(ushort8v*)&gs[0][p0][kga * 8] = ua;
        *(ushort8v*)&gs[0][p0][(kga + 4) * 8] = ub;
    }
    __syncthreads();

#pragma unroll
    for (int kb = 0; kb < 8; kb++) {
        const int cur = kb & 1;

        // T14 issue-early: gather chunk kb+1 into registers
        ushort na[8], nb[8];
        if (kb < 7) {
            const ushort* nbp = gb + (kb + 1) * 4096;
#pragma unroll
            for (int j = 0; j < 8; j++) na[j] = nbp[(kga * 8 + j) * 64 + p0];
#pragma unroll
            for (int j = 0; j < 8; j++) nb[j] = nbp[((kga + 4) * 8 + j) * 64 + p0];
        }

        bf16x8 bfrg[4][2];
#pragma unroll
        for (int tt = 0; tt < 4; tt++)
#pragma unroll
            for (int kc = 0; kc < 2; kc++)
                bfrg[tt][kc] = __builtin_bit_cast(bf16x8, *(const ushort8v*)&gs[cur][tt * 16 + lr][kc * 32 + lg * 8]);

#pragma unroll
        for (int mt = 0; mt < 2; mt++) {
            const int o0 = (wv * 2 + mt) * 16;
            bf16x8 afr[2];
#pragma unroll
            for (int kc = 0; kc < 2; kc++)
                afr[kc] = __builtin_bit_cast(bf16x8,
                    *(const ushort8v*)&pout_b[(size_t)(o0 + lr) * 512 + kb * 64 + kc * 32 + lg * 8]);
#pragma unroll
            for (int kc = 0; kc < 2; kc++)
#pragma unroll
                for (int tt = 0; tt < 4; tt++)
                    acc[mt][tt] = __builtin_amdgcn_mfma_f32_16x16x32_bf16(afr[kc], bfrg[tt][kc], acc[mt][tt], 0, 0, 0);
        }

        if (kb < 7) {
            ushort8v ua, ub;
#pragma unroll
            for (int j = 0; j < 8; j++) { ua[j] = na[j]; ub[j] = nb[j]; }
            *(ushort8v*)&gs[cur ^ 1][p0][kga * 8] = ua;
            *(ushort8v*)&gs[cur ^ 1][p0][(kga + 4) * 8] = ub;
        }
        __syncthreads();
    }

    // epilogue: add x2, repack via xf[32][129] in two 32-px halves
#pragma unroll
    for (int h = 0; h < 2; h++) {
#pragma unroll
        for (int mt = 0; mt < 2; mt++)
#pragma unroll
            for (int t2 = 0; t2 < 2; t2++) {
                const int tt = h * 2 + t2;
                int o0 = (wv * 2 + mt) * 16 + lg * 4;
                int px = tt * 16 + lr;
                uint2 xw = *(const uint2*)&x2[padr(b, tile, px, o0)];
                xf[px - h * 32][o0 + 0] = u2f_lo(xw.x) + acc[mt][tt][0];
                xf[px - h * 32][o0 + 1] = u2f_hi(xw.x) + acc[mt][tt][1];
                xf[px - h * 32][o0 + 2] = u2f_lo(xw.y) + acc[mt][tt][2];
                xf[px - h * 32][o0 + 3] = u2f_hi(xw.y) + acc[mt][tt][3];
            }
        __syncthreads();
        {
            const int qx = tid & 7;       // px quad within half
            const int cbase = tid >> 3;   // 0..31
#pragma unroll
            for (int cc = 0; cc < 4; cc++) {
                int c = cbase + cc * 32;
                float4 v;
                v.x = xf[qx * 4 + 0][c];
                v.y = xf[qx * 4 + 1][c];
                v.z = xf[qx * 4 + 2][c];
                v.w = xf[qx * 4 + 3][c];
                *(float4*)&out[((size_t)b * 128 + c) * NPIX + tile * 64 + h * 32 + qx * 4] = v;
            }
        }
        __syncthreads();
    }
}

// ---------------------------------------------------------------------------
extern "C" void kernel_launch(void* const* d_in, const int* in_sizes, int n_in,
                              void* d_out, int out_size, void* d_ws, size_t ws_size,
                              hipStream_t stream) {
    const float* x = (const float*)d_in[0];
    const float* ln1_w = (const float*)d_in[1];
    const float* ln1_b = (const float*)d_in[2];
    const float* qkv_w = (const float*)d_in[3];
    const float* qkv_dw = (const float*)d_in[4];
    const float* temperature = (const float*)d_in[5];
    const float* attn_proj = (const float*)d_in[6];
    const float* ln2_w = (const float*)d_in[7];
    const float* ln2_b = (const float*)d_in[8];
    const float* pin_w = (const float*)d_in[9];
    const float* c1_w = (const float*)d_in[10];
    const float* c3_w = (const float*)d_in[11];
    const float* c5_w = (const float*)d_in[12];
    const float* pout_w = (const float*)d_in[13];
    float* out = (float*)d_out;

    char* ws = (char*)d_ws;
    ushort* qkv_pre = (ushort*)(ws + 0);            // 100,663,296 (dead after dwconv3)
    ushort* qkv     = (ushort*)(ws + 100663296);    // 100,663,296 (dead after mv_ln)
    ushort* x2      = (ushort*)(ws + 201326592);    //  33,554,432 px-major (lives to end)
    ushort* t       = (ushort*)(ws + 0);            //  67,108,864 (reuses qkv_pre)
    ushort* gated   = (ushort*)(ws + 67108864);     // 134,217,728 (reuses qkv region)
    ushort* Mb16    = (ushort*)(ws + 235151360);    //    262,144
    ushort* qkv_wb  = (ushort*)(ws + 235413504);    //     98,304
    ushort* pin_wb  = (ushort*)(ws + 235511808);    //     65,536
    ushort* pout_wb = (ushort*)(ws + 235577344);    //    131,072  (end ~235.7 MB)

    // K0: weight conversion (f32 -> bf16)
    wcvt<<<576, 256, 0, stream>>>(qkv_w, qkv_wb, 49152, pin_w, pin_wb, 32768, pout_w, pout_wb, 65536);
    // K1: qkv_pre = qkv_w @ LN1(x)
    ln_gemm_mfma<384><<<2048, 256, 0, stream>>>(x, qkv_wb, ln1_w, ln1_b, qkv_pre);
    // K2: qkv = dwconv3x3(qkv_pre)
    dwconv3_lds<<<dim3(384, 8), 256, 0, stream>>>(qkv_pre, qkv_dw, qkv, 384);
    // K3: attention (norms + QK^T + softmax + attn_proj fold)
    attn_M<<<64, 512, 0, stream>>>(qkv, temperature, attn_proj, Mb16);
    // K4+K5 fused: x2 = x + M_b @ v ; t = pin @ LN2(x2)
    mv_ln_mfma<<<2048, 256, 0, stream>>>(qkv, Mb16, x, pin_wb, ln2_w, ln2_b, x2, t);
    // K6/K7 fused + gating
    dw_gated<<<dim3(256, 8), 256, 0, stream>>>(t, c3_w, c5_w, c1_w, gated);
    // K8: out = x2 + pout @ gated
    gdfn_mfma<<<2048, 256, 0, stream>>>(gated, x2, pout_wb, out);
}